// Round 17
// baseline (399.629 us; speedup 1.0000x reference)
//
#include <hip/hip_runtime.h>
#include <hip/hip_bf16.h>
#include <stdint.h>

#define T_TOK 1024
#define HDIM 2048
#define DDIM 2048
#define NE 8

typedef unsigned int uint;
typedef unsigned short ushort;

typedef _Float16 f16x8 __attribute__((ext_vector_type(8)));
typedef float f32x4 __attribute__((ext_vector_type(4)));

typedef __attribute__((address_space(1))) const void v_g;
typedef __attribute__((address_space(3))) void v_l;

__device__ __forceinline__ ushort f2h(float f) {
  _Float16 h = (_Float16)f;           // v_cvt_f16_f32, RTNE
  return *(ushort*)&h;
}

// e2m1 nibble * 2^(sc-127) -> fp16 bits (exact; subnormals handled; <2^-24 -> 0)
__device__ __forceinline__ uint dqh(uint nib, int sc) {
  uint m = nib & 7u;
  int e = (int)(m >> 1);
  int e16 = sc - 113 + e;                       // fp16 biased exponent
  uint mant = ((m & 1u) && m >= 2u) ? 0x200u : 0u;
  uint bits;
  if (m == 0u || e16 <= -10) bits = 0u;
  else if (e16 >= 1) bits = ((uint)e16 << 10) | mant;
  else bits = (0x400u | mant) >> (1 - e16);     // subnormal (exact for these values)
  return bits | ((nib & 8u) << 12);
}
__device__ __forceinline__ uint dq2h(uint b, int sc) {
  return dqh(b & 15u, sc) | (dqh((b >> 4) & 15u, sc) << 16);
}

// Pipeline sync primitives (counted vmcnt across raw barriers, T3+T4)
__device__ __forceinline__ void waitv4() {
  asm volatile("s_waitcnt vmcnt(4)" ::: "memory");
  __builtin_amdgcn_sched_barrier(0);
}
__device__ __forceinline__ void waitv0() {
  asm volatile("s_waitcnt vmcnt(0)" ::: "memory");
  __builtin_amdgcn_sched_barrier(0);
}
__device__ __forceinline__ void barrier_raw() {
  asm volatile("" ::: "memory");
  __builtin_amdgcn_s_barrier();
  asm volatile("" ::: "memory");
}

// --- router body (RMSNorm + f32 logits + top-4 softmax + residual out=x) -----
__device__ __forceinline__ void router_body(
    int t, const float* __restrict__ x, const float* __restrict__ nw,
    const float* __restrict__ rw, const float* __restrict__ rb,
    ushort* __restrict__ tbuf, float* __restrict__ scores,
    float* __restrict__ outp)
{
  const int tid = threadIdx.x;
  const float4* xr = (const float4*)(x + (size_t)t * HDIM);
  float4 v0 = xr[tid * 2], v1 = xr[tid * 2 + 1];
  // residual: out = x (replaces the D2D memcpy; dn's atomics come later in-stream)
  float4* orow = (float4*)(outp + (size_t)t * HDIM);
  orow[tid * 2] = v0;
  orow[tid * 2 + 1] = v1;
  float ss = v0.x*v0.x + v0.y*v0.y + v0.z*v0.z + v0.w*v0.w
           + v1.x*v1.x + v1.y*v1.y + v1.z*v1.z + v1.w*v1.w;
  __shared__ float red[256];
  red[tid] = ss;
  __syncthreads();
  for (int s = 128; s > 0; s >>= 1) {
    if (tid < s) red[tid] += red[tid + s];
    __syncthreads();
  }
  const float rstd = rsqrtf(red[0] * (1.0f / HDIM) + 1e-5f);
  float xv[8] = {v0.x, v0.y, v0.z, v0.w, v1.x, v1.y, v1.z, v1.w};
  float lp[NE];
#pragma unroll
  for (int e = 0; e < NE; ++e) lp[e] = 0.f;
  union { ushort us[8]; uint4 v; } pkh;
  const int h0 = tid * 8;
#pragma unroll
  for (int j = 0; j < 8; ++j) {
    int h = h0 + j;
    float tn = xv[j] * rstd * nw[h];
    pkh.us[j] = f2h(tn);
#pragma unroll
    for (int e = 0; e < NE; ++e) lp[e] += tn * rw[h * NE + e];
  }
  *(uint4*)(tbuf + (size_t)t * HDIM + h0) = pkh.v;
#pragma unroll
  for (int e = 0; e < NE; ++e)
#pragma unroll
    for (int off = 32; off > 0; off >>= 1) lp[e] += __shfl_down(lp[e], off);
  __shared__ float wred[4][NE];
  if ((tid & 63) == 0) {
#pragma unroll
    for (int e = 0; e < NE; ++e) wred[tid >> 6][e] = lp[e];
  }
  __syncthreads();
  if (tid == 0) {
    float lg[NE];
#pragma unroll
    for (int e = 0; e < NE; ++e)
      lg[e] = wred[0][e] + wred[1][e] + wred[2][e] + wred[3][e] + rb[e];
    bool used[NE] = {false, false, false, false, false, false, false, false};
    float tv[4]; int ti[4];
    for (int s = 0; s < 4; ++s) {          // ties: lowest index first (strict >)
      float best = -3.4e38f; int bi = 0;
      for (int e = 0; e < NE; ++e)
        if (!used[e] && lg[e] > best) { best = lg[e]; bi = e; }
      used[bi] = true; tv[s] = best; ti[s] = bi;
    }
    float den = 0.f, ev[4];
    for (int s = 0; s < 4; ++s) { ev[s] = expf(tv[s] - tv[0]); den += ev[s]; }
    float so[NE] = {0, 0, 0, 0, 0, 0, 0, 0};
    for (int s = 0; s < 4; ++s) so[ti[s]] = ev[s] / den;
#pragma unroll
    for (int e = 0; e < NE; ++e) scores[t * NE + e] = so[e];
  }
}

__global__ __launch_bounds__(256) void router_kernel(
    const float* __restrict__ x, const float* __restrict__ nw,
    const float* __restrict__ rw, const float* __restrict__ rb,
    ushort* __restrict__ tbuf, float* __restrict__ scores,
    float* __restrict__ outp)
{
  router_body(blockIdx.x, x, nw, rw, rb, tbuf, scores, outp);
}

// ---- fused prep: dequant (blocks 0..NDQB-1) + router (rest) — independent ----
#define NDQB ((NE * 4096 * 64 + NE * 2048 * 64) / 256)
__global__ __launch_bounds__(256) void prep_kernel(
    const float* __restrict__ x, const float* __restrict__ nw,
    const float* __restrict__ rw, const float* __restrict__ rb,
    const int* __restrict__ gub, const int* __restrict__ gus,
    const int* __restrict__ dnb, const int* __restrict__ dns,
    ushort* __restrict__ tbuf, float* __restrict__ scores,
    ushort* __restrict__ wgu, ushort* __restrict__ wdn,
    float* __restrict__ outp)
{
  if (blockIdx.x >= NDQB) {
    router_body(blockIdx.x - NDQB, x, nw, rw, rb, tbuf, scores, outp);
    return;
  }
  const int NG = NE * 4096 * 64;
  int tidg = blockIdx.x * 256 + threadIdx.x;
  const int* qb; const int* qs; ushort* dst; int bi;
  if (tidg < NG) { bi = tidg; qb = gub; qs = gus; dst = wgu; }
  else           { bi = tidg - NG; qb = dnb; qs = dns; dst = wdn; }
  int sc = qs[bi];
  const int4* bp = (const int4*)(qb + (size_t)bi * 16);
  int4 q0 = bp[0], q1 = bp[1], q2 = bp[2], q3 = bp[3];
  uint w[16];
  w[0]=dq2h(q0.x,sc);  w[1]=dq2h(q0.y,sc);  w[2]=dq2h(q0.z,sc);  w[3]=dq2h(q0.w,sc);
  w[4]=dq2h(q1.x,sc);  w[5]=dq2h(q1.y,sc);  w[6]=dq2h(q1.z,sc);  w[7]=dq2h(q1.w,sc);
  w[8]=dq2h(q2.x,sc);  w[9]=dq2h(q2.y,sc);  w[10]=dq2h(q2.z,sc); w[11]=dq2h(q2.w,sc);
  w[12]=dq2h(q3.x,sc); w[13]=dq2h(q3.y,sc); w[14]=dq2h(q3.z,sc); w[15]=dq2h(q3.w,sc);
  uint4* o = (uint4*)(dst + (size_t)bi * 32);
  o[0] = make_uint4(w[0], w[1], w[2], w[3]);
  o[1] = make_uint4(w[4], w[5], w[6], w[7]);
  o[2] = make_uint4(w[8], w[9], w[10], w[11]);
  o[3] = make_uint4(w[12], w[13], w[14], w[15]);
}

// ------------- per-expert token compaction (deterministic prefix scan) --------
__global__ __launch_bounds__(256) void scan_kernel(
    const float* __restrict__ scores, int* __restrict__ cnts, int* __restrict__ idx)
{
  const int e = blockIdx.x, tid = threadIdx.x;
  int loc[4], c = 0;
#pragma unroll
  for (int j = 0; j < 4; ++j) {
    int t = tid * 4 + j;
    loc[j] = (scores[t * NE + e] != 0.f) ? 1 : 0;
    c += loc[j];
  }
  __shared__ int sc[256];
  sc[tid] = c;
  __syncthreads();
  for (int off = 1; off < 256; off <<= 1) {
    int v = (tid >= off) ? sc[tid - off] : 0;
    __syncthreads();
    sc[tid] += v;
    __syncthreads();
  }
  int base = sc[tid] - c;
#pragma unroll
  for (int j = 0; j < 4; ++j)
    if (loc[j]) idx[e * T_TOK + base++] = tid * 4 + j;
  if (tid == 255) cnts[e] = sc[255];
}

// ---- pipelined fp16 GEMM: 128x128 tile, BK=32, 2-deep counted-vmcnt (T3+T4) --
// R16-exact + T5 s_setprio around the MFMA cluster.
// MODE 0: gate_up+GLU -> mid; MODE 1: down+scatter.
template<int MODE>
__global__ __launch_bounds__(256) void mx_gemm_p(
    const ushort* __restrict__ Abase,
    const ushort* __restrict__ Bw,
    const float* __restrict__ bias,
    const float* __restrict__ scores,
    const int* __restrict__ cnts,
    const int* __restrict__ tokidx,
    ushort* __restrict__ midH,
    float* __restrict__ outp)
{
  constexpr int NTOT = (MODE == 0) ? 2 * DDIM : HDIM;
  constexpr int K    = (MODE == 0) ? HDIM : DDIM;
  constexpr int NKT  = K / 32;
  const int nt = blockIdx.x, mt = blockIdx.y, e = blockIdx.z;
  const int cnt = cnts[e];
  const int m0 = mt * 128, n0 = nt * 128;
  if (m0 >= cnt) return;
  const ushort* A = Abase + (MODE == 0 ? (size_t)0 : (size_t)e * T_TOK * DDIM);

  __shared__ __align__(16) ushort As[2][128 * 32];   // 2 x 8 KB
  __shared__ __align__(16) ushort Bs[2][128 * 32];   // 2 x 8 KB
  __shared__ int tok_s[128];

  const int tid = threadIdx.x;
  const int lane = tid & 63;
  const int wv = tid >> 6;
  const int wm = wv >> 1, wn = wv & 1;
  const int fr = lane & 15, kg = lane >> 4;

  if (tid < 128) {
    int sl = m0 + tid;
    tok_s[tid] = (sl < cnt) ? tokidx[e * T_TOK + sl] : 0;
  }
  __syncthreads();

  int arow[2];
#pragma unroll
  for (int j = 0; j < 2; ++j) {
    int row = (tid + 256 * j) >> 2;
    arow[j] = (MODE == 0) ? tok_s[row] : (m0 + row);
  }

  f32x4 acc[4][4];
#pragma unroll
  for (int i = 0; i < 4; ++i)
#pragma unroll
    for (int j = 0; j < 4; ++j) acc[i][j] = f32x4{0.f, 0.f, 0.f, 0.f};

  // stage one K-tile (4 global_load_lds per thread: 2 A + 2 B), swizzled source
  auto do_stage = [&](int buf, int kt) {
#pragma unroll
    for (int j = 0; j < 2; ++j) {
      int cidx = tid + 256 * j;
      int row = cidx >> 2, ck = cidx & 3;
      int gck = ck ^ ((row >> 1) & 3);
      size_t go = (size_t)arow[j] * K + kt * 32 + gck * 8;
      __builtin_amdgcn_global_load_lds((v_g*)(A + go),
          (v_l*)((char*)&As[buf][0] + cidx * 16), 16, 0, 0);
    }
#pragma unroll
    for (int j = 0; j < 2; ++j) {
      int cidx = tid + 256 * j;
      int row = cidx >> 2, ck = cidx & 3;
      int gck = ck ^ ((row >> 1) & 3);
      const ushort* g = Bw + ((size_t)e * NTOT + n0 + row) * K + kt * 32 + gck * 8;
      __builtin_amdgcn_global_load_lds((v_g*)g,
          (v_l*)((char*)&Bs[buf][0] + cidx * 16), 16, 0, 0);
    }
  };

  auto do_compute = [&](int buf) {
    f16x8 aF[4], bF[4];
#pragma unroll
    for (int mi = 0; mi < 4; ++mi) {
      int r = wm * 64 + mi * 16 + fr;
      int ck = kg ^ ((r >> 1) & 3);
      aF[mi] = *(const f16x8*)(&As[buf][r * 32 + ck * 8]);
    }
#pragma unroll
    for (int ni = 0; ni < 4; ++ni) {
      int r = wn * 64 + ni * 16 + fr;
      int ck = kg ^ ((r >> 1) & 3);
      bF[ni] = *(const f16x8*)(&Bs[buf][r * 32 + ck * 8]);
    }
    __builtin_amdgcn_s_setprio(1);          // T5: favor MFMA-issuing wave
#pragma unroll
    for (int mi = 0; mi < 4; ++mi)
#pragma unroll
      for (int ni = 0; ni < 4; ++ni)
        acc[mi][ni] = __builtin_amdgcn_mfma_f32_16x16x32_f16(aF[mi], bF[ni], acc[mi][ni], 0, 0, 0);
    __builtin_amdgcn_s_setprio(0);
  };

  // prologue: 2-deep prefetch
  do_stage(0, 0);
  do_stage(1, 1);
  waitv4();                         // tile0's 4 loads landed
  barrier_raw();                    // all waves' tile0 loads landed
#pragma unroll 2
  for (int kt = 0; kt < NKT; ++kt) {
    do_compute(kt & 1);             // tile kt
    if (kt == NKT - 1) break;
    barrier_raw();                  // all waves done READING buf kt&1
    if (kt + 2 < NKT) {
      do_stage(kt & 1, kt + 2);     // overwrite freed buffer; 8 outstanding
      waitv4();                     // tile kt+1's loads landed
    } else {
      waitv0();                     // tail drain
    }
    barrier_raw();                  // all waves have tile kt+1 ready
  }

  const int c = lane & 15, rg = lane >> 4;
  const int sbase = m0 + wm * 64, nbase = n0 + wn * 64;
  if constexpr (MODE == 0) {
#pragma unroll
    for (int mi = 0; mi < 4; ++mi)
#pragma unroll
      for (int ni = 0; ni < 4; ++ni) {
        int n = nbase + ni * 16 + c;
        float bv = bias[(size_t)e * NTOT + n];
#pragma unroll
        for (int r = 0; r < 4; ++r) {
          int slot = sbase + mi * 16 + rg * 4 + r;
          float val = acc[mi][ni][r] + bv;
          float other = __shfl_xor(val, 1);
          if (!(c & 1) && slot < cnt) {
            int tok = tok_s[slot - m0];
            float g = fminf(val, 7.0f);
            float u = fminf(fmaxf(other, -7.0f), 7.0f);
            float glu = g / (1.0f + expf(-1.702f * g));
            float mv = (u + 1.0f) * glu;
            float s = scores[tok * NE + e];
            midH[((size_t)e * T_TOK + slot) * DDIM + ((uint)n >> 1)] = f2h(mv * s);
          }
        }
      }
  } else {
#pragma unroll
    for (int mi = 0; mi < 4; ++mi)
#pragma unroll
      for (int ni = 0; ni < 4; ++ni) {
        int n = nbase + ni * 16 + c;
        float dbv = bias[(size_t)e * NTOT + n];
#pragma unroll
        for (int r = 0; r < 4; ++r) {
          int slot = sbase + mi * 16 + rg * 4 + r;
          if (slot < cnt) {
            int tok = tok_s[slot - m0];
            float s = scores[tok * NE + e];
            atomicAdd(outp + (size_t)tok * HDIM + n, acc[mi][ni][r] + s * dbv);
          }
        }
      }
  }
}

// ---- fallback kernels (inline fp16 dequant, simple 1-phase; ws-too-small) ----
__global__ __launch_bounds__(256) void gu_gemm_q(
    const ushort* __restrict__ At,
    const int* __restrict__ qblocks,
    const int* __restrict__ qscales,
    const float* __restrict__ bias,
    const float* __restrict__ scores,
    const int* __restrict__ cnts,
    const int* __restrict__ tokidx,
    ushort* __restrict__ midH)
{
  constexpr int NTOT = 2 * DDIM;
  constexpr int K = HDIM;
  const int nt = blockIdx.x, mt = blockIdx.y, e = blockIdx.z;
  const int cnt = cnts[e];
  const int m0 = mt * 128, n0 = nt * 128;
  if (m0 >= cnt) return;

  __shared__ __align__(16) ushort As[128 * 64];
  __shared__ __align__(16) ushort Bs[128 * 64];
  __shared__ int tok_s[128];

  const int tid = threadIdx.x;
  const int lane = tid & 63;
  const int wv = tid >> 6;
  const int wm = wv >> 1, wn = wv & 1;
  const int fr = lane & 15, kg = lane >> 4;

  if (tid < 128) {
    int sl = m0 + tid;
    tok_s[tid] = (sl < cnt) ? tokidx[e * T_TOK + sl] : 0;
  }
  __syncthreads();
  int arow[4];
#pragma unroll
  for (int j = 0; j < 4; ++j) arow[j] = tok_s[(tid + 256 * j) >> 3];

  f32x4 acc[4][4];
#pragma unroll
  for (int i = 0; i < 4; ++i)
#pragma unroll
    for (int j = 0; j < 4; ++j) acc[i][j] = f32x4{0.f, 0.f, 0.f, 0.f};

  for (int kt = 0; kt < K / 64; ++kt) {
#pragma unroll
    for (int j = 0; j < 4; ++j) {
      int cidx = tid + 256 * j;
      int row = cidx >> 3, ck = cidx & 7;
      int sck = ck ^ (row & 7);
      size_t go = (size_t)arow[j] * K + kt * 64 + sck * 8;
      __builtin_amdgcn_global_load_lds((v_g*)(At + go), (v_l*)((char*)As + cidx * 16), 16, 0, 0);
    }
    {
      const int brow = tid >> 1, bblk = tid & 1;
      int kb = kt * 2 + bblk;
      size_t bi = ((size_t)e * NTOT + n0 + brow) * (K / 32) + kb;
      int sc = qscales[bi];
      const int4* bp = (const int4*)(qblocks + bi * 16);
      int4 q0 = bp[0], q1 = bp[1], q2 = bp[2], q3 = bp[3];
      uint w[16];
      w[0]=dq2h(q0.x,sc);  w[1]=dq2h(q0.y,sc);  w[2]=dq2h(q0.z,sc);  w[3]=dq2h(q0.w,sc);
      w[4]=dq2h(q1.x,sc);  w[5]=dq2h(q1.y,sc);  w[6]=dq2h(q1.z,sc);  w[7]=dq2h(q1.w,sc);
      w[8]=dq2h(q2.x,sc);  w[9]=dq2h(q2.y,sc);  w[10]=dq2h(q2.z,sc); w[11]=dq2h(q2.w,sc);
      w[12]=dq2h(q3.x,sc); w[13]=dq2h(q3.y,sc); w[14]=dq2h(q3.z,sc); w[15]=dq2h(q3.w,sc);
#pragma unroll
      for (int q = 0; q < 4; ++q) {
        int ck = bblk * 4 + q;
        int sk = ck ^ (brow & 7);
        *(uint4*)((char*)Bs + brow * 128 + sk * 16) =
            make_uint4(w[4*q], w[4*q+1], w[4*q+2], w[4*q+3]);
      }
    }
    __syncthreads();
#pragma unroll
    for (int kh = 0; kh < 2; ++kh) {
      f16x8 aF[4], bF[4];
#pragma unroll
      for (int mi = 0; mi < 4; ++mi) {
        int r = wm * 64 + mi * 16 + fr;
        int ck = (kh * 4 + kg) ^ (r & 7);
        aF[mi] = *(const f16x8*)((const char*)As + r * 128 + ck * 16);
      }
#pragma unroll
      for (int ni = 0; ni < 4; ++ni) {
        int r = wn * 64 + ni * 16 + fr;
        int ck = (kh * 4 + kg) ^ (r & 7);
        bF[ni] = *(const f16x8*)((const char*)Bs + r * 128 + ck * 16);
      }
#pragma unroll
      for (int mi = 0; mi < 4; ++mi)
#pragma unroll
        for (int ni = 0; ni < 4; ++ni)
          acc[mi][ni] = __builtin_amdgcn_mfma_f32_16x16x32_f16(aF[mi], bF[ni], acc[mi][ni], 0, 0, 0);
    }
    __syncthreads();
  }

  const int c = lane & 15, rg = lane >> 4;
  const int sbase = m0 + wm * 64, nbase = n0 + wn * 64;
#pragma unroll
  for (int mi = 0; mi < 4; ++mi)
#pragma unroll
    for (int ni = 0; ni < 4; ++ni) {
      int n = nbase + ni * 16 + c;
      float bv = bias[(size_t)e * NTOT + n];
#pragma unroll
      for (int r = 0; r < 4; ++r) {
        int slot = sbase + mi * 16 + rg * 4 + r;
        float val = acc[mi][ni][r] + bv;
        float other = __shfl_xor(val, 1);
        if (!(c & 1) && slot < cnt) {
          int tok = tok_s[slot - m0];
          float g = fminf(val, 7.0f);
          float u = fminf(fmaxf(other, -7.0f), 7.0f);
          float glu = g / (1.0f + expf(-1.702f * g));
          float mv = (u + 1.0f) * glu;
          float s = scores[tok * NE + e];
          midH[((size_t)e * T_TOK + slot) * DDIM + ((uint)n >> 1)] = f2h(mv * s);
        }
      }
    }
}

__global__ __launch_bounds__(256) void dn_gemm_q(
    const ushort* __restrict__ Abase,
    const int* __restrict__ qblocks,
    const int* __restrict__ qscales,
    const float* __restrict__ bias,
    const float* __restrict__ scores,
    const int* __restrict__ cnts,
    const int* __restrict__ tokidx,
    float* __restrict__ outp)
{
  constexpr int NTOT = HDIM;
  constexpr int K    = DDIM;
  const int nt = blockIdx.x, mt = blockIdx.y, e = blockIdx.z;
  const int cnt = cnts[e];
  const int m0 = mt * 128, n0 = nt * 128;
  if (m0 >= cnt) return;
  const ushort* A = Abase + (size_t)e * T_TOK * DDIM;

  __shared__ __align__(16) ushort As[128 * 64];
  __shared__ __align__(16) ushort Bs[128 * 64];
  __shared__ int tok_s[128];

  const int tid = threadIdx.x;
  const int lane = tid & 63;
  const int wv = tid >> 6;
  const int wm = wv >> 1, wn = wv & 1;
  const int fr = lane & 15, kg = lane >> 4;

  if (tid < 128) {
    int sl = m0 + tid;
    tok_s[tid] = (sl < cnt) ? tokidx[e * T_TOK + sl] : 0;
  }
  __syncthreads();

  f32x4 acc[4][4];
#pragma unroll
  for (int i = 0; i < 4; ++i)
#pragma unroll
    for (int j = 0; j < 4; ++j) acc[i][j] = f32x4{0.f, 0.f, 0.f, 0.f};

  for (int kt = 0; kt < K / 64; ++kt) {
#pragma unroll
    for (int j = 0; j < 4; ++j) {
      int cidx = tid + 256 * j;
      int row = cidx >> 3, ck = cidx & 7;
      int sck = ck ^ (row & 7);
      size_t go = (size_t)(m0 + row) * K + kt * 64 + sck * 8;
      __builtin_amdgcn_global_load_lds((v_g*)(A + go), (v_l*)((char*)As + cidx * 16), 16, 0, 0);
    }
    {
      const int brow = tid >> 1, bblk = tid & 1;
      int kb = kt * 2 + bblk;
      size_t bi = ((size_t)e * NTOT + n0 + brow) * (K / 32) + kb;
      int sc = qscales[bi];
      const int4* bp = (const int4*)(qblocks + bi * 16);
      int4 q0 = bp[0], q1 = bp[1], q2 = bp[2], q3 = bp[3];
      uint w[16];
      w[0]=dq2h(q0.x,sc);  w[1]=dq2h(q0.y,sc);  w[2]=dq2h(q0.z,sc);  w[3]=dq2h(q0.w,sc);
      w[4]=dq2h(q1.x,sc);  w[5]=dq2h(q1.y,sc);  w[6]=dq2h(q1.z,sc);  w[7]=dq2h(q1.w,sc);
      w[8]=dq2h(q2.x,sc);  w[9]=dq2h(q2.y,sc);  w[10]=dq2h(q2.z,sc); w[11]=dq2h(q2.w,sc);
      w[12]=dq2h(q3.x,sc); w[13]=dq2h(q3.y,sc); w[14]=dq2h(q3.z,sc); w[15]=dq2h(q3.w,sc);
#pragma unroll
      for (int q = 0; q < 4; ++q) {
        int ck = bblk * 4 + q;
        int sk = ck ^ (brow & 7);
        *(uint4*)((char*)Bs + brow * 128 + sk * 16) =
            make_uint4(w[4*q], w[4*q+1], w[4*q+2], w[4*q+3]);
      }
    }
    __syncthreads();
#pragma unroll
    for (int kh = 0; kh < 2; ++kh) {
      f16x8 aF[4], bF[4];
#pragma unroll
      for (int mi = 0; mi < 4; ++mi) {
        int r = wm * 64 + mi * 16 + fr;
        int ck = (kh * 4 + kg) ^ (r & 7);
        aF[mi] = *(const f16x8*)((const char*)As + r * 128 + ck * 16);
      }
#pragma unroll
      for (int ni = 0; ni < 4; ++ni) {
        int r = wn * 64 + ni * 16 + fr;
        int ck = (kh * 4 + kg) ^ (r & 7);
        bF[ni] = *(const f16x8*)((const char*)Bs + r * 128 + ck * 16);
      }
#pragma unroll
      for (int mi = 0; mi < 4; ++mi)
#pragma unroll
        for (int ni = 0; ni < 4; ++ni)
          acc[mi][ni] = __builtin_amdgcn_mfma_f32_16x16x32_f16(aF[mi], bF[ni], acc[mi][ni], 0, 0, 0);
    }
    __syncthreads();
  }

  const int c = lane & 15, rg = lane >> 4;
  const int sbase = m0 + wm * 64, nbase = n0 + wn * 64;
#pragma unroll
  for (int mi = 0; mi < 4; ++mi)
#pragma unroll
    for (int ni = 0; ni < 4; ++ni) {
      int n = nbase + ni * 16 + c;
      float dbv = bias[(size_t)e * NTOT + n];
#pragma unroll
      for (int r = 0; r < 4; ++r) {
        int slot = sbase + mi * 16 + rg * 4 + r;
        if (slot < cnt) {
          int tok = tok_s[slot - m0];
          float s = scores[tok * NE + e];
          atomicAdd(outp + (size_t)tok * HDIM + n, acc[mi][ni][r] + s * dbv);
        }
      }
    }
}

extern "C" void kernel_launch(void* const* d_in, const int* in_sizes, int n_in,
                              void* d_out, int out_size, void* d_ws, size_t ws_size,
                              hipStream_t stream)
{
  const float* x      = (const float*)d_in[0];
  const float* nw     = (const float*)d_in[1];
  const float* rw     = (const float*)d_in[2];
  const float* rb     = (const float*)d_in[3];
  const int*   gus    = (const int*)d_in[4];
  const int*   gub    = (const int*)d_in[5];
  const float* gubias = (const float*)d_in[6];
  const int*   dns    = (const int*)d_in[7];
  const int*   dnb    = (const int*)d_in[8];
  const float* dnbias = (const float*)d_in[9];

  char* ws = (char*)d_ws;
  const size_t SZ_WGU = (size_t)NE * 4096 * 2048 * 2;   // 134 MB
  const size_t SZ_WDN = (size_t)NE * 2048 * 2048 * 2;   //  67 MB
  const size_t SZ_T   = (size_t)T_TOK * HDIM * 2;       //   4 MB
  const size_t SZ_MID = (size_t)NE * T_TOK * DDIM * 2;  //  33.5 MB
  const size_t SZ_SC  = (size_t)T_TOK * NE * 4;
  const size_t SZ_IDX = (size_t)NE * T_TOK * 4;
  const size_t SZ_CNT = 128;

  const size_t need_act = SZ_T + SZ_MID + SZ_SC + SZ_IDX + SZ_CNT;
  const bool predeq = ws_size >= SZ_WGU + SZ_WDN + need_act;
  ushort* wgu = (ushort*)ws;
  ushort* wdn = (ushort*)(ws + SZ_WGU);
  char* base2 = predeq ? (ws + SZ_WGU + SZ_WDN) : ws;
  ushort* tbuf   = (ushort*)base2;
  ushort* midHp  = (ushort*)(base2 + SZ_T);
  float*  scores = (float*)(base2 + SZ_T + SZ_MID);
  int*    cnts   = (int*)(base2 + SZ_T + SZ_MID + SZ_SC);
  int*    tokidx = (int*)(base2 + SZ_T + SZ_MID + SZ_SC + SZ_CNT);
  float*  outp   = (float*)d_out;

  if (predeq) {
    prep_kernel<<<NDQB + T_TOK, 256, 0, stream>>>(
        x, nw, rw, rb, gub, gus, dnb, dns, tbuf, scores, wgu, wdn, outp);
    scan_kernel<<<NE, 256, 0, stream>>>(scores, cnts, tokidx);
    mx_gemm_p<0><<<dim3(32, 8, NE), 256, 0, stream>>>(
        tbuf, wgu, gubias, scores, cnts, tokidx, midHp, nullptr);
    mx_gemm_p<1><<<dim3(16, 8, NE), 256, 0, stream>>>(
        midHp, wdn, dnbias, scores, cnts, tokidx, nullptr, outp);
  } else {
    router_kernel<<<T_TOK, 256, 0, stream>>>(x, nw, rw, rb, tbuf, scores, outp);
    scan_kernel<<<NE, 256, 0, stream>>>(scores, cnts, tokidx);
    gu_gemm_q<<<dim3(32, 8, NE), 256, 0, stream>>>(
        tbuf, gub, gus, gubias, scores, cnts, tokidx, midHp);
    dn_gemm_q<<<dim3(16, 8, NE), 256, 0, stream>>>(
        midHp, dnb, dns, dnbias, scores, cnts, tokidx, outp);
  }
}

// Round 18
// 336.869 us; speedup vs baseline: 1.1863x; 1.1863x over previous
//
#include <hip/hip_runtime.h>
#include <hip/hip_bf16.h>
#include <stdint.h>

#define T_TOK 1024
#define HDIM 2048
#define DDIM 2048
#define NE 8

typedef unsigned int uint;
typedef unsigned short ushort;

typedef _Float16 f16x8 __attribute__((ext_vector_type(8)));
typedef float f32x4 __attribute__((ext_vector_type(4)));

typedef __attribute__((address_space(1))) const void v_g;
typedef __attribute__((address_space(3))) void v_l;

__device__ __forceinline__ ushort f2h(float f) {
  _Float16 h = (_Float16)f;           // v_cvt_f16_f32, RTNE
  return *(ushort*)&h;
}

// e2m1 nibble * 2^(sc-127) -> fp16 bits (exact; subnormals handled; <2^-24 -> 0)
__device__ __forceinline__ uint dqh(uint nib, int sc) {
  uint m = nib & 7u;
  int e = (int)(m >> 1);
  int e16 = sc - 113 + e;                       // fp16 biased exponent
  uint mant = ((m & 1u) && m >= 2u) ? 0x200u : 0u;
  uint bits;
  if (m == 0u || e16 <= -10) bits = 0u;
  else if (e16 >= 1) bits = ((uint)e16 << 10) | mant;
  else bits = (0x400u | mant) >> (1 - e16);     // subnormal (exact for these values)
  return bits | ((nib & 8u) << 12);
}
__device__ __forceinline__ uint dq2h(uint b, int sc) {
  return dqh(b & 15u, sc) | (dqh((b >> 4) & 15u, sc) << 16);
}

// Pipeline sync primitives (counted vmcnt across raw barriers, T3+T4)
__device__ __forceinline__ void waitv4() {
  asm volatile("s_waitcnt vmcnt(4)" ::: "memory");
  __builtin_amdgcn_sched_barrier(0);
}
__device__ __forceinline__ void waitv0() {
  asm volatile("s_waitcnt vmcnt(0)" ::: "memory");
  __builtin_amdgcn_sched_barrier(0);
}
__device__ __forceinline__ void barrier_raw() {
  asm volatile("" ::: "memory");
  __builtin_amdgcn_s_barrier();
  asm volatile("" ::: "memory");
}

// --- router body (RMSNorm + f32 logits + top-4 softmax + residual out=x) -----
__device__ __forceinline__ void router_body(
    int t, const float* __restrict__ x, const float* __restrict__ nw,
    const float* __restrict__ rw, const float* __restrict__ rb,
    ushort* __restrict__ tbuf, float* __restrict__ scores,
    float* __restrict__ outp)
{
  const int tid = threadIdx.x;
  const float4* xr = (const float4*)(x + (size_t)t * HDIM);
  float4 v0 = xr[tid * 2], v1 = xr[tid * 2 + 1];
  // residual: out = x (replaces the D2D memcpy; dn's atomics come later in-stream)
  float4* orow = (float4*)(outp + (size_t)t * HDIM);
  orow[tid * 2] = v0;
  orow[tid * 2 + 1] = v1;
  float ss = v0.x*v0.x + v0.y*v0.y + v0.z*v0.z + v0.w*v0.w
           + v1.x*v1.x + v1.y*v1.y + v1.z*v1.z + v1.w*v1.w;
  __shared__ float red[256];
  red[tid] = ss;
  __syncthreads();
  for (int s = 128; s > 0; s >>= 1) {
    if (tid < s) red[tid] += red[tid + s];
    __syncthreads();
  }
  const float rstd = rsqrtf(red[0] * (1.0f / HDIM) + 1e-5f);
  float xv[8] = {v0.x, v0.y, v0.z, v0.w, v1.x, v1.y, v1.z, v1.w};
  float lp[NE];
#pragma unroll
  for (int e = 0; e < NE; ++e) lp[e] = 0.f;
  union { ushort us[8]; uint4 v; } pkh;
  const int h0 = tid * 8;
#pragma unroll
  for (int j = 0; j < 8; ++j) {
    int h = h0 + j;
    float tn = xv[j] * rstd * nw[h];
    pkh.us[j] = f2h(tn);
#pragma unroll
    for (int e = 0; e < NE; ++e) lp[e] += tn * rw[h * NE + e];
  }
  *(uint4*)(tbuf + (size_t)t * HDIM + h0) = pkh.v;
#pragma unroll
  for (int e = 0; e < NE; ++e)
#pragma unroll
    for (int off = 32; off > 0; off >>= 1) lp[e] += __shfl_down(lp[e], off);
  __shared__ float wred[4][NE];
  if ((tid & 63) == 0) {
#pragma unroll
    for (int e = 0; e < NE; ++e) wred[tid >> 6][e] = lp[e];
  }
  __syncthreads();
  if (tid == 0) {
    float lg[NE];
#pragma unroll
    for (int e = 0; e < NE; ++e)
      lg[e] = wred[0][e] + wred[1][e] + wred[2][e] + wred[3][e] + rb[e];
    bool used[NE] = {false, false, false, false, false, false, false, false};
    float tv[4]; int ti[4];
    for (int s = 0; s < 4; ++s) {          // ties: lowest index first (strict >)
      float best = -3.4e38f; int bi = 0;
      for (int e = 0; e < NE; ++e)
        if (!used[e] && lg[e] > best) { best = lg[e]; bi = e; }
      used[bi] = true; tv[s] = best; ti[s] = bi;
    }
    float den = 0.f, ev[4];
    for (int s = 0; s < 4; ++s) { ev[s] = expf(tv[s] - tv[0]); den += ev[s]; }
    float so[NE] = {0, 0, 0, 0, 0, 0, 0, 0};
    for (int s = 0; s < 4; ++s) so[ti[s]] = ev[s] / den;
#pragma unroll
    for (int e = 0; e < NE; ++e) scores[t * NE + e] = so[e];
  }
}

__global__ __launch_bounds__(256) void router_kernel(
    const float* __restrict__ x, const float* __restrict__ nw,
    const float* __restrict__ rw, const float* __restrict__ rb,
    ushort* __restrict__ tbuf, float* __restrict__ scores,
    float* __restrict__ outp)
{
  router_body(blockIdx.x, x, nw, rw, rb, tbuf, scores, outp);
}

// ---- fused prep: dequant (blocks 0..NDQB-1) + router (rest) — independent ----
#define NDQB ((NE * 4096 * 64 + NE * 2048 * 64) / 256)
__global__ __launch_bounds__(256) void prep_kernel(
    const float* __restrict__ x, const float* __restrict__ nw,
    const float* __restrict__ rw, const float* __restrict__ rb,
    const int* __restrict__ gub, const int* __restrict__ gus,
    const int* __restrict__ dnb, const int* __restrict__ dns,
    ushort* __restrict__ tbuf, float* __restrict__ scores,
    ushort* __restrict__ wgu, ushort* __restrict__ wdn,
    float* __restrict__ outp)
{
  if (blockIdx.x >= NDQB) {
    router_body(blockIdx.x - NDQB, x, nw, rw, rb, tbuf, scores, outp);
    return;
  }
  const int NG = NE * 4096 * 64;
  int tidg = blockIdx.x * 256 + threadIdx.x;
  const int* qb; const int* qs; ushort* dst; int bi;
  if (tidg < NG) { bi = tidg; qb = gub; qs = gus; dst = wgu; }
  else           { bi = tidg - NG; qb = dnb; qs = dns; dst = wdn; }
  int sc = qs[bi];
  const int4* bp = (const int4*)(qb + (size_t)bi * 16);
  int4 q0 = bp[0], q1 = bp[1], q2 = bp[2], q3 = bp[3];
  uint w[16];
  w[0]=dq2h(q0.x,sc);  w[1]=dq2h(q0.y,sc);  w[2]=dq2h(q0.z,sc);  w[3]=dq2h(q0.w,sc);
  w[4]=dq2h(q1.x,sc);  w[5]=dq2h(q1.y,sc);  w[6]=dq2h(q1.z,sc);  w[7]=dq2h(q1.w,sc);
  w[8]=dq2h(q2.x,sc);  w[9]=dq2h(q2.y,sc);  w[10]=dq2h(q2.z,sc); w[11]=dq2h(q2.w,sc);
  w[12]=dq2h(q3.x,sc); w[13]=dq2h(q3.y,sc); w[14]=dq2h(q3.z,sc); w[15]=dq2h(q3.w,sc);
  uint4* o = (uint4*)(dst + (size_t)bi * 32);
  o[0] = make_uint4(w[0], w[1], w[2], w[3]);
  o[1] = make_uint4(w[4], w[5], w[6], w[7]);
  o[2] = make_uint4(w[8], w[9], w[10], w[11]);
  o[3] = make_uint4(w[12], w[13], w[14], w[15]);
}

// ------------- per-expert token compaction (deterministic prefix scan) --------
__global__ __launch_bounds__(256) void scan_kernel(
    const float* __restrict__ scores, int* __restrict__ cnts, int* __restrict__ idx)
{
  const int e = blockIdx.x, tid = threadIdx.x;
  int loc[4], c = 0;
#pragma unroll
  for (int j = 0; j < 4; ++j) {
    int t = tid * 4 + j;
    loc[j] = (scores[t * NE + e] != 0.f) ? 1 : 0;
    c += loc[j];
  }
  __shared__ int sc[256];
  sc[tid] = c;
  __syncthreads();
  for (int off = 1; off < 256; off <<= 1) {
    int v = (tid >= off) ? sc[tid - off] : 0;
    __syncthreads();
    sc[tid] += v;
    __syncthreads();
  }
  int base = sc[tid] - c;
#pragma unroll
  for (int j = 0; j < 4; ++j)
    if (loc[j]) idx[e * T_TOK + base++] = tid * 4 + j;
  if (tid == 255) cnts[e] = sc[255];
}

// ---- pipelined fp16 GEMM: 128x128 tile, BK=32, 2-deep counted-vmcnt (T3+T4) --
// R16-exact (no setprio): 32 KB LDS dbuf + tok_s -> 4 blocks/CU.
// MODE 0: gate_up+GLU -> mid; MODE 1: down+scatter.
template<int MODE>
__global__ __launch_bounds__(256) void mx_gemm_p(
    const ushort* __restrict__ Abase,
    const ushort* __restrict__ Bw,
    const float* __restrict__ bias,
    const float* __restrict__ scores,
    const int* __restrict__ cnts,
    const int* __restrict__ tokidx,
    ushort* __restrict__ midH,
    float* __restrict__ outp)
{
  constexpr int NTOT = (MODE == 0) ? 2 * DDIM : HDIM;
  constexpr int K    = (MODE == 0) ? HDIM : DDIM;
  constexpr int NKT  = K / 32;
  const int nt = blockIdx.x, mt = blockIdx.y, e = blockIdx.z;
  const int cnt = cnts[e];
  const int m0 = mt * 128, n0 = nt * 128;
  if (m0 >= cnt) return;
  const ushort* A = Abase + (MODE == 0 ? (size_t)0 : (size_t)e * T_TOK * DDIM);

  __shared__ __align__(16) ushort As[2][128 * 32];   // 2 x 8 KB
  __shared__ __align__(16) ushort Bs[2][128 * 32];   // 2 x 8 KB
  __shared__ int tok_s[128];

  const int tid = threadIdx.x;
  const int lane = tid & 63;
  const int wv = tid >> 6;
  const int wm = wv >> 1, wn = wv & 1;
  const int fr = lane & 15, kg = lane >> 4;

  if (tid < 128) {
    int sl = m0 + tid;
    tok_s[tid] = (sl < cnt) ? tokidx[e * T_TOK + sl] : 0;
  }
  __syncthreads();

  int arow[2];
#pragma unroll
  for (int j = 0; j < 2; ++j) {
    int row = (tid + 256 * j) >> 2;
    arow[j] = (MODE == 0) ? tok_s[row] : (m0 + row);
  }

  f32x4 acc[4][4];
#pragma unroll
  for (int i = 0; i < 4; ++i)
#pragma unroll
    for (int j = 0; j < 4; ++j) acc[i][j] = f32x4{0.f, 0.f, 0.f, 0.f};

  // stage one K-tile (4 global_load_lds per thread: 2 A + 2 B), swizzled source
  auto do_stage = [&](int buf, int kt) {
#pragma unroll
    for (int j = 0; j < 2; ++j) {
      int cidx = tid + 256 * j;
      int row = cidx >> 2, ck = cidx & 3;
      int gck = ck ^ ((row >> 1) & 3);
      size_t go = (size_t)arow[j] * K + kt * 32 + gck * 8;
      __builtin_amdgcn_global_load_lds((v_g*)(A + go),
          (v_l*)((char*)&As[buf][0] + cidx * 16), 16, 0, 0);
    }
#pragma unroll
    for (int j = 0; j < 2; ++j) {
      int cidx = tid + 256 * j;
      int row = cidx >> 2, ck = cidx & 3;
      int gck = ck ^ ((row >> 1) & 3);
      const ushort* g = Bw + ((size_t)e * NTOT + n0 + row) * K + kt * 32 + gck * 8;
      __builtin_amdgcn_global_load_lds((v_g*)g,
          (v_l*)((char*)&Bs[buf][0] + cidx * 16), 16, 0, 0);
    }
  };

  auto do_compute = [&](int buf) {
    f16x8 aF[4], bF[4];
#pragma unroll
    for (int mi = 0; mi < 4; ++mi) {
      int r = wm * 64 + mi * 16 + fr;
      int ck = kg ^ ((r >> 1) & 3);
      aF[mi] = *(const f16x8*)(&As[buf][r * 32 + ck * 8]);
    }
#pragma unroll
    for (int ni = 0; ni < 4; ++ni) {
      int r = wn * 64 + ni * 16 + fr;
      int ck = kg ^ ((r >> 1) & 3);
      bF[ni] = *(const f16x8*)(&Bs[buf][r * 32 + ck * 8]);
    }
#pragma unroll
    for (int mi = 0; mi < 4; ++mi)
#pragma unroll
      for (int ni = 0; ni < 4; ++ni)
        acc[mi][ni] = __builtin_amdgcn_mfma_f32_16x16x32_f16(aF[mi], bF[ni], acc[mi][ni], 0, 0, 0);
  };

  // prologue: 2-deep prefetch
  do_stage(0, 0);
  do_stage(1, 1);
  waitv4();                         // tile0's 4 loads landed
  barrier_raw();                    // all waves' tile0 loads landed
#pragma unroll 2
  for (int kt = 0; kt < NKT; ++kt) {
    do_compute(kt & 1);             // tile kt
    if (kt == NKT - 1) break;
    barrier_raw();                  // all waves done READING buf kt&1
    if (kt + 2 < NKT) {
      do_stage(kt & 1, kt + 2);     // overwrite freed buffer; 8 outstanding
      waitv4();                     // tile kt+1's loads landed
    } else {
      waitv0();                     // tail drain
    }
    barrier_raw();                  // all waves have tile kt+1 ready
  }

  const int c = lane & 15, rg = lane >> 4;
  const int sbase = m0 + wm * 64, nbase = n0 + wn * 64;
  if constexpr (MODE == 0) {
#pragma unroll
    for (int mi = 0; mi < 4; ++mi)
#pragma unroll
      for (int ni = 0; ni < 4; ++ni) {
        int n = nbase + ni * 16 + c;
        float bv = bias[(size_t)e * NTOT + n];
#pragma unroll
        for (int r = 0; r < 4; ++r) {
          int slot = sbase + mi * 16 + rg * 4 + r;
          float val = acc[mi][ni][r] + bv;
          float other = __shfl_xor(val, 1);
          if (!(c & 1) && slot < cnt) {
            int tok = tok_s[slot - m0];
            float g = fminf(val, 7.0f);
            float u = fminf(fmaxf(other, -7.0f), 7.0f);
            float glu = g / (1.0f + expf(-1.702f * g));
            float mv = (u + 1.0f) * glu;
            float s = scores[tok * NE + e];
            midH[((size_t)e * T_TOK + slot) * DDIM + ((uint)n >> 1)] = f2h(mv * s);
          }
        }
      }
  } else {
#pragma unroll
    for (int mi = 0; mi < 4; ++mi)
#pragma unroll
      for (int ni = 0; ni < 4; ++ni) {
        int n = nbase + ni * 16 + c;
        float dbv = bias[(size_t)e * NTOT + n];
#pragma unroll
        for (int r = 0; r < 4; ++r) {
          int slot = sbase + mi * 16 + rg * 4 + r;
          if (slot < cnt) {
            int tok = tok_s[slot - m0];
            float s = scores[tok * NE + e];
            atomicAdd(outp + (size_t)tok * HDIM + n, acc[mi][ni][r] + s * dbv);
          }
        }
      }
  }
}

// ---- fallback kernels (inline fp16 dequant, simple 1-phase; ws-too-small) ----
__global__ __launch_bounds__(256) void gu_gemm_q(
    const ushort* __restrict__ At,
    const int* __restrict__ qblocks,
    const int* __restrict__ qscales,
    const float* __restrict__ bias,
    const float* __restrict__ scores,
    const int* __restrict__ cnts,
    const int* __restrict__ tokidx,
    ushort* __restrict__ midH)
{
  constexpr int NTOT = 2 * DDIM;
  constexpr int K = HDIM;
  const int nt = blockIdx.x, mt = blockIdx.y, e = blockIdx.z;
  const int cnt = cnts[e];
  const int m0 = mt * 128, n0 = nt * 128;
  if (m0 >= cnt) return;

  __shared__ __align__(16) ushort As[128 * 64];
  __shared__ __align__(16) ushort Bs[128 * 64];
  __shared__ int tok_s[128];

  const int tid = threadIdx.x;
  const int lane = tid & 63;
  const int wv = tid >> 6;
  const int wm = wv >> 1, wn = wv & 1;
  const int fr = lane & 15, kg = lane >> 4;

  if (tid < 128) {
    int sl = m0 + tid;
    tok_s[tid] = (sl < cnt) ? tokidx[e * T_TOK + sl] : 0;
  }
  __syncthreads();
  int arow[4];
#pragma unroll
  for (int j = 0; j < 4; ++j) arow[j] = tok_s[(tid + 256 * j) >> 3];

  f32x4 acc[4][4];
#pragma unroll
  for (int i = 0; i < 4; ++i)
#pragma unroll
    for (int j = 0; j < 4; ++j) acc[i][j] = f32x4{0.f, 0.f, 0.f, 0.f};

  for (int kt = 0; kt < K / 64; ++kt) {
#pragma unroll
    for (int j = 0; j < 4; ++j) {
      int cidx = tid + 256 * j;
      int row = cidx >> 3, ck = cidx & 7;
      int sck = ck ^ (row & 7);
      size_t go = (size_t)arow[j] * K + kt * 64 + sck * 8;
      __builtin_amdgcn_global_load_lds((v_g*)(At + go), (v_l*)((char*)As + cidx * 16), 16, 0, 0);
    }
    {
      const int brow = tid >> 1, bblk = tid & 1;
      int kb = kt * 2 + bblk;
      size_t bi = ((size_t)e * NTOT + n0 + brow) * (K / 32) + kb;
      int sc = qscales[bi];
      const int4* bp = (const int4*)(qblocks + bi * 16);
      int4 q0 = bp[0], q1 = bp[1], q2 = bp[2], q3 = bp[3];
      uint w[16];
      w[0]=dq2h(q0.x,sc);  w[1]=dq2h(q0.y,sc);  w[2]=dq2h(q0.z,sc);  w[3]=dq2h(q0.w,sc);
      w[4]=dq2h(q1.x,sc);  w[5]=dq2h(q1.y,sc);  w[6]=dq2h(q1.z,sc);  w[7]=dq2h(q1.w,sc);
      w[8]=dq2h(q2.x,sc);  w[9]=dq2h(q2.y,sc);  w[10]=dq2h(q2.z,sc); w[11]=dq2h(q2.w,sc);
      w[12]=dq2h(q3.x,sc); w[13]=dq2h(q3.y,sc); w[14]=dq2h(q3.z,sc); w[15]=dq2h(q3.w,sc);
#pragma unroll
      for (int q = 0; q < 4; ++q) {
        int ck = bblk * 4 + q;
        int sk = ck ^ (brow & 7);
        *(uint4*)((char*)Bs + brow * 128 + sk * 16) =
            make_uint4(w[4*q], w[4*q+1], w[4*q+2], w[4*q+3]);
      }
    }
    __syncthreads();
#pragma unroll
    for (int kh = 0; kh < 2; ++kh) {
      f16x8 aF[4], bF[4];
#pragma unroll
      for (int mi = 0; mi < 4; ++mi) {
        int r = wm * 64 + mi * 16 + fr;
        int ck = (kh * 4 + kg) ^ (r & 7);
        aF[mi] = *(const f16x8*)((const char*)As + r * 128 + ck * 16);
      }
#pragma unroll
      for (int ni = 0; ni < 4; ++ni) {
        int r = wn * 64 + ni * 16 + fr;
        int ck = (kh * 4 + kg) ^ (r & 7);
        bF[ni] = *(const f16x8*)((const char*)Bs + r * 128 + ck * 16);
      }
#pragma unroll
      for (int mi = 0; mi < 4; ++mi)
#pragma unroll
        for (int ni = 0; ni < 4; ++ni)
          acc[mi][ni] = __builtin_amdgcn_mfma_f32_16x16x32_f16(aF[mi], bF[ni], acc[mi][ni], 0, 0, 0);
    }
    __syncthreads();
  }

  const int c = lane & 15, rg = lane >> 4;
  const int sbase = m0 + wm * 64, nbase = n0 + wn * 64;
#pragma unroll
  for (int mi = 0; mi < 4; ++mi)
#pragma unroll
    for (int ni = 0; ni < 4; ++ni) {
      int n = nbase + ni * 16 + c;
      float bv = bias[(size_t)e * NTOT + n];
#pragma unroll
      for (int r = 0; r < 4; ++r) {
        int slot = sbase + mi * 16 + rg * 4 + r;
        float val = acc[mi][ni][r] + bv;
        float other = __shfl_xor(val, 1);
        if (!(c & 1) && slot < cnt) {
          int tok = tok_s[slot - m0];
          float g = fminf(val, 7.0f);
          float u = fminf(fmaxf(other, -7.0f), 7.0f);
          float glu = g / (1.0f + expf(-1.702f * g));
          float mv = (u + 1.0f) * glu;
          float s = scores[tok * NE + e];
          midH[((size_t)e * T_TOK + slot) * DDIM + ((uint)n >> 1)] = f2h(mv * s);
        }
      }
    }
}

__global__ __launch_bounds__(256) void dn_gemm_q(
    const ushort* __restrict__ Abase,
    const int* __restrict__ qblocks,
    const int* __restrict__ qscales,
    const float* __restrict__ bias,
    const float* __restrict__ scores,
    const int* __restrict__ cnts,
    const int* __restrict__ tokidx,
    float* __restrict__ outp)
{
  constexpr int NTOT = HDIM;
  constexpr int K    = DDIM;
  const int nt = blockIdx.x, mt = blockIdx.y, e = blockIdx.z;
  const int cnt = cnts[e];
  const int m0 = mt * 128, n0 = nt * 128;
  if (m0 >= cnt) return;
  const ushort* A = Abase + (size_t)e * T_TOK * DDIM;

  __shared__ __align__(16) ushort As[128 * 64];
  __shared__ __align__(16) ushort Bs[128 * 64];
  __shared__ int tok_s[128];

  const int tid = threadIdx.x;
  const int lane = tid & 63;
  const int wv = tid >> 6;
  const int wm = wv >> 1, wn = wv & 1;
  const int fr = lane & 15, kg = lane >> 4;

  if (tid < 128) {
    int sl = m0 + tid;
    tok_s[tid] = (sl < cnt) ? tokidx[e * T_TOK + sl] : 0;
  }
  __syncthreads();

  f32x4 acc[4][4];
#pragma unroll
  for (int i = 0; i < 4; ++i)
#pragma unroll
    for (int j = 0; j < 4; ++j) acc[i][j] = f32x4{0.f, 0.f, 0.f, 0.f};

  for (int kt = 0; kt < K / 64; ++kt) {
#pragma unroll
    for (int j = 0; j < 4; ++j) {
      int cidx = tid + 256 * j;
      int row = cidx >> 3, ck = cidx & 7;
      int sck = ck ^ (row & 7);
      size_t go = (size_t)(m0 + row) * K + kt * 64 + sck * 8;
      __builtin_amdgcn_global_load_lds((v_g*)(A + go), (v_l*)((char*)As + cidx * 16), 16, 0, 0);
    }
    {
      const int brow = tid >> 1, bblk = tid & 1;
      int kb = kt * 2 + bblk;
      size_t bi = ((size_t)e * NTOT + n0 + brow) * (K / 32) + kb;
      int sc = qscales[bi];
      const int4* bp = (const int4*)(qblocks + bi * 16);
      int4 q0 = bp[0], q1 = bp[1], q2 = bp[2], q3 = bp[3];
      uint w[16];
      w[0]=dq2h(q0.x,sc);  w[1]=dq2h(q0.y,sc);  w[2]=dq2h(q0.z,sc);  w[3]=dq2h(q0.w,sc);
      w[4]=dq2h(q1.x,sc);  w[5]=dq2h(q1.y,sc);  w[6]=dq2h(q1.z,sc);  w[7]=dq2h(q1.w,sc);
      w[8]=dq2h(q2.x,sc);  w[9]=dq2h(q2.y,sc);  w[10]=dq2h(q2.z,sc); w[11]=dq2h(q2.w,sc);
      w[12]=dq2h(q3.x,sc); w[13]=dq2h(q3.y,sc); w[14]=dq2h(q3.z,sc); w[15]=dq2h(q3.w,sc);
#pragma unroll
      for (int q = 0; q < 4; ++q) {
        int ck = bblk * 4 + q;
        int sk = ck ^ (brow & 7);
        *(uint4*)((char*)Bs + brow * 128 + sk * 16) =
            make_uint4(w[4*q], w[4*q+1], w[4*q+2], w[4*q+3]);
      }
    }
    __syncthreads();
#pragma unroll
    for (int kh = 0; kh < 2; ++kh) {
      f16x8 aF[4], bF[4];
#pragma unroll
      for (int mi = 0; mi < 4; ++mi) {
        int r = wm * 64 + mi * 16 + fr;
        int ck = (kh * 4 + kg) ^ (r & 7);
        aF[mi] = *(const f16x8*)((const char*)As + r * 128 + ck * 16);
      }
#pragma unroll
      for (int ni = 0; ni < 4; ++ni) {
        int r = wn * 64 + ni * 16 + fr;
        int ck = (kh * 4 + kg) ^ (r & 7);
        bF[ni] = *(const f16x8*)((const char*)Bs + r * 128 + ck * 16);
      }
#pragma unroll
      for (int mi = 0; mi < 4; ++mi)
#pragma unroll
        for (int ni = 0; ni < 4; ++ni)
          acc[mi][ni] = __builtin_amdgcn_mfma_f32_16x16x32_f16(aF[mi], bF[ni], acc[mi][ni], 0, 0, 0);
    }
    __syncthreads();
  }

  const int c = lane & 15, rg = lane >> 4;
  const int sbase = m0 + wm * 64, nbase = n0 + wn * 64;
#pragma unroll
  for (int mi = 0; mi < 4; ++mi)
#pragma unroll
    for (int ni = 0; ni < 4; ++ni) {
      int n = nbase + ni * 16 + c;
      float dbv = bias[(size_t)e * NTOT + n];
#pragma unroll
      for (int r = 0; r < 4; ++r) {
        int slot = sbase + mi * 16 + rg * 4 + r;
        if (slot < cnt) {
          int tok = tok_s[slot - m0];
          float s = scores[tok * NE + e];
          atomicAdd(outp + (size_t)tok * HDIM + n, acc[mi][ni][r] + s * dbv);
        }
      }
    }
}

extern "C" void kernel_launch(void* const* d_in, const int* in_sizes, int n_in,
                              void* d_out, int out_size, void* d_ws, size_t ws_size,
                              hipStream_t stream)
{
  const float* x      = (const float*)d_in[0];
  const float* nw     = (const float*)d_in[1];
  const float* rw     = (const float*)d_in[2];
  const float* rb     = (const float*)d_in[3];
  const int*   gus    = (const int*)d_in[4];
  const int*   gub    = (const int*)d_in[5];
  const float* gubias = (const float*)d_in[6];
  const int*   dns    = (const int*)d_in[7];
  const int*   dnb    = (const int*)d_in[8];
  const float* dnbias = (const float*)d_in[9];

  char* ws = (char*)d_ws;
  const size_t SZ_WGU = (size_t)NE * 4096 * 2048 * 2;   // 134 MB
  const size_t SZ_WDN = (size_t)NE * 2048 * 2048 * 2;   //  67 MB
  const size_t SZ_T   = (size_t)T_TOK * HDIM * 2;       //   4 MB
  const size_t SZ_MID = (size_t)NE * T_TOK * DDIM * 2;  //  33.5 MB
  const size_t SZ_SC  = (size_t)T_TOK * NE * 4;
  const size_t SZ_IDX = (size_t)NE * T_TOK * 4;
  const size_t SZ_CNT = 128;

  const size_t need_act = SZ_T + SZ_MID + SZ_SC + SZ_IDX + SZ_CNT;
  const bool predeq = ws_size >= SZ_WGU + SZ_WDN + need_act;
  ushort* wgu = (ushort*)ws;
  ushort* wdn = (ushort*)(ws + SZ_WGU);
  char* base2 = predeq ? (ws + SZ_WGU + SZ_WDN) : ws;
  ushort* tbuf   = (ushort*)base2;
  ushort* midHp  = (ushort*)(base2 + SZ_T);
  float*  scores = (float*)(base2 + SZ_T + SZ_MID);
  int*    cnts   = (int*)(base2 + SZ_T + SZ_MID + SZ_SC);
  int*    tokidx = (int*)(base2 + SZ_T + SZ_MID + SZ_SC + SZ_CNT);
  float*  outp   = (float*)d_out;

  if (predeq) {
    prep_kernel<<<NDQB + T_TOK, 256, 0, stream>>>(
        x, nw, rw, rb, gub, gus, dnb, dns, tbuf, scores, wgu, wdn, outp);
    scan_kernel<<<NE, 256, 0, stream>>>(scores, cnts, tokidx);
    mx_gemm_p<0><<<dim3(32, 8, NE), 256, 0, stream>>>(
        tbuf, wgu, gubias, scores, cnts, tokidx, midHp, nullptr);
    mx_gemm_p<1><<<dim3(16, 8, NE), 256, 0, stream>>>(
        midHp, wdn, dnbias, scores, cnts, tokidx, nullptr, outp);
  } else {
    router_kernel<<<T_TOK, 256, 0, stream>>>(x, nw, rw, rb, tbuf, scores, outp);
    scan_kernel<<<NE, 256, 0, stream>>>(scores, cnts, tokidx);
    gu_gemm_q<<<dim3(32, 8, NE), 256, 0, stream>>>(
        tbuf, gub, gus, gubias, scores, cnts, tokidx, midHp);
    dn_gemm_q<<<dim3(16, 8, NE), 256, 0, stream>>>(
        midHp, dnb, dns, dnbias, scores, cnts, tokidx, outp);
  }
}

// Round 19
// 318.106 us; speedup vs baseline: 1.2563x; 1.0590x over previous
//
#include <hip/hip_runtime.h>
#include <hip/hip_bf16.h>
#include <stdint.h>

#define T_TOK 1024
#define HDIM 2048
#define DDIM 2048
#define NE 8

typedef unsigned int uint;
typedef unsigned short ushort;

typedef _Float16 f16x8 __attribute__((ext_vector_type(8)));
typedef float f32x4 __attribute__((ext_vector_type(4)));

typedef __attribute__((address_space(1))) const void v_g;
typedef __attribute__((address_space(3))) void v_l;

__device__ __forceinline__ ushort f2h(float f) {
  _Float16 h = (_Float16)f;           // v_cvt_f16_f32, RTNE
  return *(ushort*)&h;
}

// e2m1 nibble * 2^(sc-127) -> fp16 bits (exact; subnormals handled; <2^-24 -> 0)
__device__ __forceinline__ uint dqh(uint nib, int sc) {
  uint m = nib & 7u;
  int e = (int)(m >> 1);
  int e16 = sc - 113 + e;                       // fp16 biased exponent
  uint mant = ((m & 1u) && m >= 2u) ? 0x200u : 0u;
  uint bits;
  if (m == 0u || e16 <= -10) bits = 0u;
  else if (e16 >= 1) bits = ((uint)e16 << 10) | mant;
  else bits = (0x400u | mant) >> (1 - e16);     // subnormal (exact for these values)
  return bits | ((nib & 8u) << 12);
}
__device__ __forceinline__ uint dq2h(uint b, int sc) {
  return dqh(b & 15u, sc) | (dqh((b >> 4) & 15u, sc) << 16);
}

// Pipeline sync primitives (counted vmcnt across raw barriers, T3+T4)
__device__ __forceinline__ void waitv4() {
  asm volatile("s_waitcnt vmcnt(4)" ::: "memory");
  __builtin_amdgcn_sched_barrier(0);
}
__device__ __forceinline__ void waitv0() {
  asm volatile("s_waitcnt vmcnt(0)" ::: "memory");
  __builtin_amdgcn_sched_barrier(0);
}
__device__ __forceinline__ void barrier_raw() {
  asm volatile("" ::: "memory");
  __builtin_amdgcn_s_barrier();
  asm volatile("" ::: "memory");
}

// --- router body (RMSNorm + f32 logits + top-4 softmax) ----------------------
__device__ __forceinline__ void router_body(
    int t, const float* __restrict__ x, const float* __restrict__ nw,
    const float* __restrict__ rw, const float* __restrict__ rb,
    ushort* __restrict__ tbuf, float* __restrict__ scores)
{
  const int tid = threadIdx.x;
  const float4* xr = (const float4*)(x + (size_t)t * HDIM);
  float4 v0 = xr[tid * 2], v1 = xr[tid * 2 + 1];
  float ss = v0.x*v0.x + v0.y*v0.y + v0.z*v0.z + v0.w*v0.w
           + v1.x*v1.x + v1.y*v1.y + v1.z*v1.z + v1.w*v1.w;
  __shared__ float red[256];
  red[tid] = ss;
  __syncthreads();
  for (int s = 128; s > 0; s >>= 1) {
    if (tid < s) red[tid] += red[tid + s];
    __syncthreads();
  }
  const float rstd = rsqrtf(red[0] * (1.0f / HDIM) + 1e-5f);
  float xv[8] = {v0.x, v0.y, v0.z, v0.w, v1.x, v1.y, v1.z, v1.w};
  float lp[NE];
#pragma unroll
  for (int e = 0; e < NE; ++e) lp[e] = 0.f;
  union { ushort us[8]; uint4 v; } pkh;
  const int h0 = tid * 8;
#pragma unroll
  for (int j = 0; j < 8; ++j) {
    int h = h0 + j;
    float tn = xv[j] * rstd * nw[h];
    pkh.us[j] = f2h(tn);
#pragma unroll
    for (int e = 0; e < NE; ++e) lp[e] += tn * rw[h * NE + e];
  }
  *(uint4*)(tbuf + (size_t)t * HDIM + h0) = pkh.v;
#pragma unroll
  for (int e = 0; e < NE; ++e)
#pragma unroll
    for (int off = 32; off > 0; off >>= 1) lp[e] += __shfl_down(lp[e], off);
  __shared__ float wred[4][NE];
  if ((tid & 63) == 0) {
#pragma unroll
    for (int e = 0; e < NE; ++e) wred[tid >> 6][e] = lp[e];
  }
  __syncthreads();
  if (tid == 0) {
    float lg[NE];
#pragma unroll
    for (int e = 0; e < NE; ++e)
      lg[e] = wred[0][e] + wred[1][e] + wred[2][e] + wred[3][e] + rb[e];
    bool used[NE] = {false, false, false, false, false, false, false, false};
    float tv[4]; int ti[4];
    for (int s = 0; s < 4; ++s) {          // ties: lowest index first (strict >)
      float best = -3.4e38f; int bi = 0;
      for (int e = 0; e < NE; ++e)
        if (!used[e] && lg[e] > best) { best = lg[e]; bi = e; }
      used[bi] = true; tv[s] = best; ti[s] = bi;
    }
    float den = 0.f, ev[4];
    for (int s = 0; s < 4; ++s) { ev[s] = expf(tv[s] - tv[0]); den += ev[s]; }
    float so[NE] = {0, 0, 0, 0, 0, 0, 0, 0};
    for (int s = 0; s < 4; ++s) so[ti[s]] = ev[s] / den;
#pragma unroll
    for (int e = 0; e < NE; ++e) scores[t * NE + e] = so[e];
  }
}

__global__ __launch_bounds__(256) void router_kernel(
    const float* __restrict__ x, const float* __restrict__ nw,
    const float* __restrict__ rw, const float* __restrict__ rb,
    ushort* __restrict__ tbuf, float* __restrict__ scores)
{
  router_body(blockIdx.x, x, nw, rw, rb, tbuf, scores);
}

// ---- fused prep: dequant (blocks 0..NDQB-1) + router (rest) — independent ----
#define NDQB ((NE * 4096 * 64 + NE * 2048 * 64) / 256)
__global__ __launch_bounds__(256) void prep_kernel(
    const float* __restrict__ x, const float* __restrict__ nw,
    const float* __restrict__ rw, const float* __restrict__ rb,
    const int* __restrict__ gub, const int* __restrict__ gus,
    const int* __restrict__ dnb, const int* __restrict__ dns,
    ushort* __restrict__ tbuf, float* __restrict__ scores,
    ushort* __restrict__ wgu, ushort* __restrict__ wdn)
{
  if (blockIdx.x >= NDQB) {
    router_body(blockIdx.x - NDQB, x, nw, rw, rb, tbuf, scores);
    return;
  }
  const int NG = NE * 4096 * 64;
  int tidg = blockIdx.x * 256 + threadIdx.x;
  const int* qb; const int* qs; ushort* dst; int bi;
  if (tidg < NG) { bi = tidg; qb = gub; qs = gus; dst = wgu; }
  else           { bi = tidg - NG; qb = dnb; qs = dns; dst = wdn; }
  int sc = qs[bi];
  const int4* bp = (const int4*)(qb + (size_t)bi * 16);
  int4 q0 = bp[0], q1 = bp[1], q2 = bp[2], q3 = bp[3];
  uint w[16];
  w[0]=dq2h(q0.x,sc);  w[1]=dq2h(q0.y,sc);  w[2]=dq2h(q0.z,sc);  w[3]=dq2h(q0.w,sc);
  w[4]=dq2h(q1.x,sc);  w[5]=dq2h(q1.y,sc);  w[6]=dq2h(q1.z,sc);  w[7]=dq2h(q1.w,sc);
  w[8]=dq2h(q2.x,sc);  w[9]=dq2h(q2.y,sc);  w[10]=dq2h(q2.z,sc); w[11]=dq2h(q2.w,sc);
  w[12]=dq2h(q3.x,sc); w[13]=dq2h(q3.y,sc); w[14]=dq2h(q3.z,sc); w[15]=dq2h(q3.w,sc);
  uint4* o = (uint4*)(dst + (size_t)bi * 32);
  o[0] = make_uint4(w[0], w[1], w[2], w[3]);
  o[1] = make_uint4(w[4], w[5], w[6], w[7]);
  o[2] = make_uint4(w[8], w[9], w[10], w[11]);
  o[3] = make_uint4(w[12], w[13], w[14], w[15]);
}

// -- per-expert token compaction + inverse slot map (deterministic scan) -------
__global__ __launch_bounds__(256) void scan_kernel(
    const float* __restrict__ scores, int* __restrict__ cnts,
    int* __restrict__ idx, int* __restrict__ slotmap)
{
  const int e = blockIdx.x, tid = threadIdx.x;
  int loc[4], c = 0;
#pragma unroll
  for (int j = 0; j < 4; ++j) {
    int t = tid * 4 + j;
    loc[j] = (scores[t * NE + e] != 0.f) ? 1 : 0;
    c += loc[j];
  }
  __shared__ int sc[256];
  sc[tid] = c;
  __syncthreads();
  for (int off = 1; off < 256; off <<= 1) {
    int v = (tid >= off) ? sc[tid - off] : 0;
    __syncthreads();
    sc[tid] += v;
    __syncthreads();
  }
  int base = sc[tid] - c;
#pragma unroll
  for (int j = 0; j < 4; ++j)
    if (loc[j]) {
      int t = tid * 4 + j;
      idx[e * T_TOK + base] = t;
      slotmap[t * NE + e] = base;
      base++;
    }
  if (tid == 255) cnts[e] = sc[255];
}

// ---- pipelined fp16 GEMM: 128x128 tile, BK=32, 2-deep counted-vmcnt (T3+T4) --
// MODE 0: gate_up+GLU -> mid (fp16, score folded).
// MODE 1: down + scatter atomicAdd to out (fallback path).
// MODE 2: down -> compacted midD[e][slot][h] plain stores (no atomics).
template<int MODE>
__global__ __launch_bounds__(256) void mx_gemm_p(
    const ushort* __restrict__ Abase,
    const ushort* __restrict__ Bw,
    const float* __restrict__ bias,
    const float* __restrict__ scores,
    const int* __restrict__ cnts,
    const int* __restrict__ tokidx,
    ushort* __restrict__ midH,
    float* __restrict__ outp)
{
  constexpr int NTOT = (MODE == 0) ? 2 * DDIM : HDIM;
  constexpr int K    = (MODE == 0) ? HDIM : DDIM;
  constexpr int NKT  = K / 32;
  const int nt = blockIdx.x, mt = blockIdx.y, e = blockIdx.z;
  const int cnt = cnts[e];
  const int m0 = mt * 128, n0 = nt * 128;
  if (m0 >= cnt) return;
  const ushort* A = Abase + (MODE == 0 ? (size_t)0 : (size_t)e * T_TOK * DDIM);

  __shared__ __align__(16) ushort As[2][128 * 32];   // 2 x 8 KB
  __shared__ __align__(16) ushort Bs[2][128 * 32];   // 2 x 8 KB
  __shared__ int tok_s[128];

  const int tid = threadIdx.x;
  const int lane = tid & 63;
  const int wv = tid >> 6;
  const int wm = wv >> 1, wn = wv & 1;
  const int fr = lane & 15, kg = lane >> 4;

  if (tid < 128) {
    int sl = m0 + tid;
    tok_s[tid] = (sl < cnt) ? tokidx[e * T_TOK + sl] : 0;
  }
  __syncthreads();

  int arow[2];
#pragma unroll
  for (int j = 0; j < 2; ++j) {
    int row = (tid + 256 * j) >> 2;
    arow[j] = (MODE == 0) ? tok_s[row] : (m0 + row);
  }

  f32x4 acc[4][4];
#pragma unroll
  for (int i = 0; i < 4; ++i)
#pragma unroll
    for (int j = 0; j < 4; ++j) acc[i][j] = f32x4{0.f, 0.f, 0.f, 0.f};

  // stage one K-tile (4 global_load_lds per thread: 2 A + 2 B), swizzled source
  auto do_stage = [&](int buf, int kt) {
#pragma unroll
    for (int j = 0; j < 2; ++j) {
      int cidx = tid + 256 * j;
      int row = cidx >> 2, ck = cidx & 3;
      int gck = ck ^ ((row >> 1) & 3);
      size_t go = (size_t)arow[j] * K + kt * 32 + gck * 8;
      __builtin_amdgcn_global_load_lds((v_g*)(A + go),
          (v_l*)((char*)&As[buf][0] + cidx * 16), 16, 0, 0);
    }
#pragma unroll
    for (int j = 0; j < 2; ++j) {
      int cidx = tid + 256 * j;
      int row = cidx >> 2, ck = cidx & 3;
      int gck = ck ^ ((row >> 1) & 3);
      const ushort* g = Bw + ((size_t)e * NTOT + n0 + row) * K + kt * 32 + gck * 8;
      __builtin_amdgcn_global_load_lds((v_g*)g,
          (v_l*)((char*)&Bs[buf][0] + cidx * 16), 16, 0, 0);
    }
  };

  auto do_compute = [&](int buf) {
    f16x8 aF[4], bF[4];
#pragma unroll
    for (int mi = 0; mi < 4; ++mi) {
      int r = wm * 64 + mi * 16 + fr;
      int ck = kg ^ ((r >> 1) & 3);
      aF[mi] = *(const f16x8*)(&As[buf][r * 32 + ck * 8]);
    }
#pragma unroll
    for (int ni = 0; ni < 4; ++ni) {
      int r = wn * 64 + ni * 16 + fr;
      int ck = kg ^ ((r >> 1) & 3);
      bF[ni] = *(const f16x8*)(&Bs[buf][r * 32 + ck * 8]);
    }
#pragma unroll
    for (int mi = 0; mi < 4; ++mi)
#pragma unroll
      for (int ni = 0; ni < 4; ++ni)
        acc[mi][ni] = __builtin_amdgcn_mfma_f32_16x16x32_f16(aF[mi], bF[ni], acc[mi][ni], 0, 0, 0);
  };

  // prologue: 2-deep prefetch
  do_stage(0, 0);
  do_stage(1, 1);
  waitv4();                         // tile0's 4 loads landed
  barrier_raw();                    // all waves' tile0 loads landed
#pragma unroll 2
  for (int kt = 0; kt < NKT; ++kt) {
    do_compute(kt & 1);             // tile kt
    if (kt == NKT - 1) break;
    barrier_raw();                  // all waves done READING buf kt&1
    if (kt + 2 < NKT) {
      do_stage(kt & 1, kt + 2);     // overwrite freed buffer; 8 outstanding
      waitv4();                     // tile kt+1's loads landed
    } else {
      waitv0();                     // tail drain
    }
    barrier_raw();                  // all waves have tile kt+1 ready
  }

  const int c = lane & 15, rg = lane >> 4;
  const int sbase = m0 + wm * 64, nbase = n0 + wn * 64;
  if constexpr (MODE == 0) {
#pragma unroll
    for (int mi = 0; mi < 4; ++mi)
#pragma unroll
      for (int ni = 0; ni < 4; ++ni) {
        int n = nbase + ni * 16 + c;
        float bv = bias[(size_t)e * NTOT + n];
#pragma unroll
        for (int r = 0; r < 4; ++r) {
          int slot = sbase + mi * 16 + rg * 4 + r;
          float val = acc[mi][ni][r] + bv;
          float other = __shfl_xor(val, 1);
          if (!(c & 1) && slot < cnt) {
            int tok = tok_s[slot - m0];
            float g = fminf(val, 7.0f);
            float u = fminf(fmaxf(other, -7.0f), 7.0f);
            float glu = g / (1.0f + expf(-1.702f * g));
            float mv = (u + 1.0f) * glu;
            float s = scores[tok * NE + e];
            midH[((size_t)e * T_TOK + slot) * DDIM + ((uint)n >> 1)] = f2h(mv * s);
          }
        }
      }
  } else if constexpr (MODE == 1) {
#pragma unroll
    for (int mi = 0; mi < 4; ++mi)
#pragma unroll
      for (int ni = 0; ni < 4; ++ni) {
        int n = nbase + ni * 16 + c;
        float dbv = bias[(size_t)e * NTOT + n];
#pragma unroll
        for (int r = 0; r < 4; ++r) {
          int slot = sbase + mi * 16 + rg * 4 + r;
          if (slot < cnt) {
            int tok = tok_s[slot - m0];
            float s = scores[tok * NE + e];
            atomicAdd(outp + (size_t)tok * HDIM + n, acc[mi][ni][r] + s * dbv);
          }
        }
      }
  } else {   // MODE 2: compacted, atomic-free store (bias/score handled in gather)
#pragma unroll
    for (int mi = 0; mi < 4; ++mi)
#pragma unroll
      for (int ni = 0; ni < 4; ++ni) {
        int n = nbase + ni * 16 + c;
#pragma unroll
        for (int r = 0; r < 4; ++r) {
          int slot = sbase + mi * 16 + rg * 4 + r;
          if (slot < cnt)
            outp[((size_t)e * T_TOK + slot) * HDIM + n] = acc[mi][ni][r];
        }
      }
  }
}

// ---- gather: out[t] = x[t] + sum_{e selected} (midD[e][slot][h] + s*dn_bias) --
__global__ __launch_bounds__(256) void gather_kernel(
    const float* __restrict__ x, const float* __restrict__ midD,
    const float* __restrict__ dnbias, const float* __restrict__ scores,
    const int* __restrict__ slotmap, float* __restrict__ outp)
{
  const int t = blockIdx.x, tid = threadIdx.x;
  const int h0 = tid * 8;
  const float4* xr = (const float4*)(x + (size_t)t * HDIM + h0);
  float4 a0 = xr[0], a1 = xr[1];
  float sc[NE]; int sl[NE];
#pragma unroll
  for (int e = 0; e < NE; ++e) sc[e] = scores[t * NE + e];
#pragma unroll
  for (int e = 0; e < NE; ++e) sl[e] = slotmap[t * NE + e];
#pragma unroll
  for (int e = 0; e < NE; ++e) {
    if (sc[e] != 0.f) {
      const float4* mr = (const float4*)(midD + ((size_t)e * T_TOK + sl[e]) * HDIM + h0);
      const float4* br = (const float4*)(dnbias + (size_t)e * HDIM + h0);
      float4 m0 = mr[0], m1 = mr[1];
      float4 b0 = br[0], b1 = br[1];
      float s = sc[e];
      a0.x += m0.x + s * b0.x; a0.y += m0.y + s * b0.y;
      a0.z += m0.z + s * b0.z; a0.w += m0.w + s * b0.w;
      a1.x += m1.x + s * b1.x; a1.y += m1.y + s * b1.y;
      a1.z += m1.z + s * b1.z; a1.w += m1.w + s * b1.w;
    }
  }
  float4* orow = (float4*)(outp + (size_t)t * HDIM + h0);
  orow[0] = a0;
  orow[1] = a1;
}

// ---- fallback kernels (inline fp16 dequant, simple 1-phase; ws-too-small) ----
__global__ __launch_bounds__(256) void gu_gemm_q(
    const ushort* __restrict__ At,
    const int* __restrict__ qblocks,
    const int* __restrict__ qscales,
    const float* __restrict__ bias,
    const float* __restrict__ scores,
    const int* __restrict__ cnts,
    const int* __restrict__ tokidx,
    ushort* __restrict__ midH)
{
  constexpr int NTOT = 2 * DDIM;
  constexpr int K = HDIM;
  const int nt = blockIdx.x, mt = blockIdx.y, e = blockIdx.z;
  const int cnt = cnts[e];
  const int m0 = mt * 128, n0 = nt * 128;
  if (m0 >= cnt) return;

  __shared__ __align__(16) ushort As[128 * 64];
  __shared__ __align__(16) ushort Bs[128 * 64];
  __shared__ int tok_s[128];

  const int tid = threadIdx.x;
  const int lane = tid & 63;
  const int wv = tid >> 6;
  const int wm = wv >> 1, wn = wv & 1;
  const int fr = lane & 15, kg = lane >> 4;

  if (tid < 128) {
    int sl = m0 + tid;
    tok_s[tid] = (sl < cnt) ? tokidx[e * T_TOK + sl] : 0;
  }
  __syncthreads();
  int arow[4];
#pragma unroll
  for (int j = 0; j < 4; ++j) arow[j] = tok_s[(tid + 256 * j) >> 3];

  f32x4 acc[4][4];
#pragma unroll
  for (int i = 0; i < 4; ++i)
#pragma unroll
    for (int j = 0; j < 4; ++j) acc[i][j] = f32x4{0.f, 0.f, 0.f, 0.f};

  for (int kt = 0; kt < K / 64; ++kt) {
#pragma unroll
    for (int j = 0; j < 4; ++j) {
      int cidx = tid + 256 * j;
      int row = cidx >> 3, ck = cidx & 7;
      int sck = ck ^ (row & 7);
      size_t go = (size_t)arow[j] * K + kt * 64 + sck * 8;
      __builtin_amdgcn_global_load_lds((v_g*)(At + go), (v_l*)((char*)As + cidx * 16), 16, 0, 0);
    }
    {
      const int brow = tid >> 1, bblk = tid & 1;
      int kb = kt * 2 + bblk;
      size_t bi = ((size_t)e * NTOT + n0 + brow) * (K / 32) + kb;
      int sc = qscales[bi];
      const int4* bp = (const int4*)(qblocks + bi * 16);
      int4 q0 = bp[0], q1 = bp[1], q2 = bp[2], q3 = bp[3];
      uint w[16];
      w[0]=dq2h(q0.x,sc);  w[1]=dq2h(q0.y,sc);  w[2]=dq2h(q0.z,sc);  w[3]=dq2h(q0.w,sc);
      w[4]=dq2h(q1.x,sc);  w[5]=dq2h(q1.y,sc);  w[6]=dq2h(q1.z,sc);  w[7]=dq2h(q1.w,sc);
      w[8]=dq2h(q2.x,sc);  w[9]=dq2h(q2.y,sc);  w[10]=dq2h(q2.z,sc); w[11]=dq2h(q2.w,sc);
      w[12]=dq2h(q3.x,sc); w[13]=dq2h(q3.y,sc); w[14]=dq2h(q3.z,sc); w[15]=dq2h(q3.w,sc);
#pragma unroll
      for (int q = 0; q < 4; ++q) {
        int ck = bblk * 4 + q;
        int sk = ck ^ (brow & 7);
        *(uint4*)((char*)Bs + brow * 128 + sk * 16) =
            make_uint4(w[4*q], w[4*q+1], w[4*q+2], w[4*q+3]);
      }
    }
    __syncthreads();
#pragma unroll
    for (int kh = 0; kh < 2; ++kh) {
      f16x8 aF[4], bF[4];
#pragma unroll
      for (int mi = 0; mi < 4; ++mi) {
        int r = wm * 64 + mi * 16 + fr;
        int ck = (kh * 4 + kg) ^ (r & 7);
        aF[mi] = *(const f16x8*)((const char*)As + r * 128 + ck * 16);
      }
#pragma unroll
      for (int ni = 0; ni < 4; ++ni) {
        int r = wn * 64 + ni * 16 + fr;
        int ck = (kh * 4 + kg) ^ (r & 7);
        bF[ni] = *(const f16x8*)((const char*)Bs + r * 128 + ck * 16);
      }
#pragma unroll
      for (int mi = 0; mi < 4; ++mi)
#pragma unroll
        for (int ni = 0; ni < 4; ++ni)
          acc[mi][ni] = __builtin_amdgcn_mfma_f32_16x16x32_f16(aF[mi], bF[ni], acc[mi][ni], 0, 0, 0);
    }
    __syncthreads();
  }

  const int c = lane & 15, rg = lane >> 4;
  const int sbase = m0 + wm * 64, nbase = n0 + wn * 64;
#pragma unroll
  for (int mi = 0; mi < 4; ++mi)
#pragma unroll
    for (int ni = 0; ni < 4; ++ni) {
      int n = nbase + ni * 16 + c;
      float bv = bias[(size_t)e * NTOT + n];
#pragma unroll
      for (int r = 0; r < 4; ++r) {
        int slot = sbase + mi * 16 + rg * 4 + r;
        float val = acc[mi][ni][r] + bv;
        float other = __shfl_xor(val, 1);
        if (!(c & 1) && slot < cnt) {
          int tok = tok_s[slot - m0];
          float g = fminf(val, 7.0f);
          float u = fminf(fmaxf(other, -7.0f), 7.0f);
          float glu = g / (1.0f + expf(-1.702f * g));
          float mv = (u + 1.0f) * glu;
          float s = scores[tok * NE + e];
          midH[((size_t)e * T_TOK + slot) * DDIM + ((uint)n >> 1)] = f2h(mv * s);
        }
      }
    }
}

__global__ __launch_bounds__(256) void dn_gemm_q(
    const ushort* __restrict__ Abase,
    const int* __restrict__ qblocks,
    const int* __restrict__ qscales,
    const float* __restrict__ bias,
    const float* __restrict__ scores,
    const int* __restrict__ cnts,
    const int* __restrict__ tokidx,
    float* __restrict__ outp)
{
  constexpr int NTOT = HDIM;
  constexpr int K    = DDIM;
  const int nt = blockIdx.x, mt = blockIdx.y, e = blockIdx.z;
  const int cnt = cnts[e];
  const int m0 = mt * 128, n0 = nt * 128;
  if (m0 >= cnt) return;
  const ushort* A = Abase + (size_t)e * T_TOK * DDIM;

  __shared__ __align__(16) ushort As[128 * 64];
  __shared__ __align__(16) ushort Bs[128 * 64];
  __shared__ int tok_s[128];

  const int tid = threadIdx.x;
  const int lane = tid & 63;
  const int wv = tid >> 6;
  const int wm = wv >> 1, wn = wv & 1;
  const int fr = lane & 15, kg = lane >> 4;

  if (tid < 128) {
    int sl = m0 + tid;
    tok_s[tid] = (sl < cnt) ? tokidx[e * T_TOK + sl] : 0;
  }
  __syncthreads();

  f32x4 acc[4][4];
#pragma unroll
  for (int i = 0; i < 4; ++i)
#pragma unroll
    for (int j = 0; j < 4; ++j) acc[i][j] = f32x4{0.f, 0.f, 0.f, 0.f};

  for (int kt = 0; kt < K / 64; ++kt) {
#pragma unroll
    for (int j = 0; j < 4; ++j) {
      int cidx = tid + 256 * j;
      int row = cidx >> 3, ck = cidx & 7;
      int sck = ck ^ (row & 7);
      size_t go = (size_t)(m0 + row) * K + kt * 64 + sck * 8;
      __builtin_amdgcn_global_load_lds((v_g*)(A + go), (v_l*)((char*)As + cidx * 16), 16, 0, 0);
    }
    {
      const int brow = tid >> 1, bblk = tid & 1;
      int kb = kt * 2 + bblk;
      size_t bi = ((size_t)e * NTOT + n0 + brow) * (K / 32) + kb;
      int sc = qscales[bi];
      const int4* bp = (const int4*)(qblocks + bi * 16);
      int4 q0 = bp[0], q1 = bp[1], q2 = bp[2], q3 = bp[3];
      uint w[16];
      w[0]=dq2h(q0.x,sc);  w[1]=dq2h(q0.y,sc);  w[2]=dq2h(q0.z,sc);  w[3]=dq2h(q0.w,sc);
      w[4]=dq2h(q1.x,sc);  w[5]=dq2h(q1.y,sc);  w[6]=dq2h(q1.z,sc);  w[7]=dq2h(q1.w,sc);
      w[8]=dq2h(q2.x,sc);  w[9]=dq2h(q2.y,sc);  w[10]=dq2h(q2.z,sc); w[11]=dq2h(q2.w,sc);
      w[12]=dq2h(q3.x,sc); w[13]=dq2h(q3.y,sc); w[14]=dq2h(q3.z,sc); w[15]=dq2h(q3.w,sc);
#pragma unroll
      for (int q = 0; q < 4; ++q) {
        int ck = bblk * 4 + q;
        int sk = ck ^ (brow & 7);
        *(uint4*)((char*)Bs + brow * 128 + sk * 16) =
            make_uint4(w[4*q], w[4*q+1], w[4*q+2], w[4*q+3]);
      }
    }
    __syncthreads();
#pragma unroll
    for (int kh = 0; kh < 2; ++kh) {
      f16x8 aF[4], bF[4];
#pragma unroll
      for (int mi = 0; mi < 4; ++mi) {
        int r = wm * 64 + mi * 16 + fr;
        int ck = (kh * 4 + kg) ^ (r & 7);
        aF[mi] = *(const f16x8*)((const char*)As + r * 128 + ck * 16);
      }
#pragma unroll
      for (int ni = 0; ni < 4; ++ni) {
        int r = wn * 64 + ni * 16 + fr;
        int ck = (kh * 4 + kg) ^ (r & 7);
        bF[ni] = *(const f16x8*)((const char*)Bs + r * 128 + ck * 16);
      }
#pragma unroll
      for (int mi = 0; mi < 4; ++mi)
#pragma unroll
        for (int ni = 0; ni < 4; ++ni)
          acc[mi][ni] = __builtin_amdgcn_mfma_f32_16x16x32_f16(aF[mi], bF[ni], acc[mi][ni], 0, 0, 0);
    }
    __syncthreads();
  }

  const int c = lane & 15, rg = lane >> 4;
  const int sbase = m0 + wm * 64, nbase = n0 + wn * 64;
#pragma unroll
  for (int mi = 0; mi < 4; ++mi)
#pragma unroll
    for (int ni = 0; ni < 4; ++ni) {
      int n = nbase + ni * 16 + c;
      float dbv = bias[(size_t)e * NTOT + n];
#pragma unroll
      for (int r = 0; r < 4; ++r) {
        int slot = sbase + mi * 16 + rg * 4 + r;
        if (slot < cnt) {
          int tok = tok_s[slot - m0];
          float s = scores[tok * NE + e];
          atomicAdd(outp + (size_t)tok * HDIM + n, acc[mi][ni][r] + s * dbv);
        }
      }
    }
}

extern "C" void kernel_launch(void* const* d_in, const int* in_sizes, int n_in,
                              void* d_out, int out_size, void* d_ws, size_t ws_size,
                              hipStream_t stream)
{
  const float* x      = (const float*)d_in[0];
  const float* nw     = (const float*)d_in[1];
  const float* rw     = (const float*)d_in[2];
  const float* rb     = (const float*)d_in[3];
  const int*   gus    = (const int*)d_in[4];
  const int*   gub    = (const int*)d_in[5];
  const float* gubias = (const float*)d_in[6];
  const int*   dns    = (const int*)d_in[7];
  const int*   dnb    = (const int*)d_in[8];
  const float* dnbias = (const float*)d_in[9];

  char* ws = (char*)d_ws;
  const size_t SZ_WGU  = (size_t)NE * 4096 * 2048 * 2;   // 134 MB
  const size_t SZ_WDN  = (size_t)NE * 2048 * 2048 * 2;   //  67 MB
  const size_t SZ_T    = (size_t)T_TOK * HDIM * 2;       //   4 MB
  const size_t SZ_MID  = (size_t)NE * T_TOK * DDIM * 2;  //  33.5 MB
  const size_t SZ_MIDD = (size_t)NE * T_TOK * HDIM * 4;  //  67 MB (f32 compacted dn out)
  const size_t SZ_SC   = (size_t)T_TOK * NE * 4;
  const size_t SZ_IDX  = (size_t)NE * T_TOK * 4;
  const size_t SZ_SLOT = (size_t)T_TOK * NE * 4;
  const size_t SZ_CNT  = 128;

  const size_t need_mid = SZ_WGU + SZ_WDN + SZ_T + SZ_MID + SZ_SC + SZ_IDX + SZ_SLOT + SZ_CNT;
  const size_t need_big = need_mid + SZ_MIDD;
  const bool predeq = ws_size >= need_mid;
  const bool bigws  = ws_size >= need_big;

  ushort* wgu = (ushort*)ws;
  ushort* wdn = (ushort*)(ws + SZ_WGU);
  char* base2 = predeq ? (ws + SZ_WGU + SZ_WDN) : ws;
  ushort* tbuf   = (ushort*)base2;
  ushort* midHp  = (ushort*)(base2 + SZ_T);
  float*  scores = (float*)(base2 + SZ_T + SZ_MID);
  int*    cnts   = (int*)(base2 + SZ_T + SZ_MID + SZ_SC);
  int*    tokidx = (int*)(base2 + SZ_T + SZ_MID + SZ_SC + SZ_CNT);
  int*    slotmap= (int*)(base2 + SZ_T + SZ_MID + SZ_SC + SZ_CNT + SZ_IDX);
  float*  midD   = (float*)(base2 + SZ_T + SZ_MID + SZ_SC + SZ_CNT + SZ_IDX + SZ_SLOT);
  float*  outp   = (float*)d_out;

  if (predeq) {
    prep_kernel<<<NDQB + T_TOK, 256, 0, stream>>>(
        x, nw, rw, rb, gub, gus, dnb, dns, tbuf, scores, wgu, wdn);
    scan_kernel<<<NE, 256, 0, stream>>>(scores, cnts, tokidx, slotmap);
    mx_gemm_p<0><<<dim3(32, 8, NE), 256, 0, stream>>>(
        tbuf, wgu, gubias, scores, cnts, tokidx, midHp, nullptr);
    if (bigws) {
      mx_gemm_p<2><<<dim3(16, 8, NE), 256, 0, stream>>>(
          midHp, wdn, dnbias, scores, cnts, tokidx, nullptr, midD);
      gather_kernel<<<T_TOK, 256, 0, stream>>>(
          x, midD, dnbias, scores, slotmap, outp);
    } else {
      hipMemcpyAsync(d_out, (void*)x, (size_t)T_TOK * HDIM * 4,
                     hipMemcpyDeviceToDevice, stream);
      mx_gemm_p<1><<<dim3(16, 8, NE), 256, 0, stream>>>(
          midHp, wdn, dnbias, scores, cnts, tokidx, nullptr, outp);
    }
  } else {
    hipMemcpyAsync(d_out, (void*)x, (size_t)T_TOK * HDIM * 4,
                   hipMemcpyDeviceToDevice, stream);
    router_kernel<<<T_TOK, 256, 0, stream>>>(x, nw, rw, rb, tbuf, scores);
    scan_kernel<<<NE, 256, 0, stream>>>(scores, cnts, tokidx, slotmap);
    gu_gemm_q<<<dim3(32, 8, NE), 256, 0, stream>>>(
        tbuf, gub, gus, gubias, scores, cnts, tokidx, midHp);
    dn_gemm_q<<<dim3(16, 8, NE), 256, 0, stream>>>(
        midHp, dnb, dns, dnbias, scores, cnts, tokidx, outp);
  }
}

// Round 20
// 291.317 us; speedup vs baseline: 1.3718x; 1.0920x over previous
//
#include <hip/hip_runtime.h>
#include <hip/hip_bf16.h>
#include <stdint.h>

#define T_TOK 1024
#define HDIM 2048
#define DDIM 2048
#define NE 8

typedef unsigned int uint;
typedef unsigned short ushort;

typedef _Float16 f16x8 __attribute__((ext_vector_type(8)));
typedef float f32x4 __attribute__((ext_vector_type(4)));

typedef __attribute__((address_space(1))) const void v_g;
typedef __attribute__((address_space(3))) void v_l;

__device__ __forceinline__ ushort f2h(float f) {
  _Float16 h = (_Float16)f;           // v_cvt_f16_f32, RTNE
  return *(ushort*)&h;
}

// e2m1 nibble * 2^(sc-127) -> fp16 bits (exact; subnormals handled; <2^-24 -> 0)
__device__ __forceinline__ uint dqh(uint nib, int sc) {
  uint m = nib & 7u;
  int e = (int)(m >> 1);
  int e16 = sc - 113 + e;                       // fp16 biased exponent
  uint mant = ((m & 1u) && m >= 2u) ? 0x200u : 0u;
  uint bits;
  if (m == 0u || e16 <= -10) bits = 0u;
  else if (e16 >= 1) bits = ((uint)e16 << 10) | mant;
  else bits = (0x400u | mant) >> (1 - e16);     // subnormal (exact for these values)
  return bits | ((nib & 8u) << 12);
}
__device__ __forceinline__ uint dq2h(uint b, int sc) {
  return dqh(b & 15u, sc) | (dqh((b >> 4) & 15u, sc) << 16);
}

// one scale-block dequant: 16 int32 (packed nibbles) -> 32 fp16
__device__ __forceinline__ void dq_block(
    const int* __restrict__ qb, const int* __restrict__ qs,
    ushort* __restrict__ dst, size_t bi)
{
  int sc = qs[bi];
  const int4* bp = (const int4*)(qb + bi * 16);
  int4 q0 = bp[0], q1 = bp[1], q2 = bp[2], q3 = bp[3];
  uint w[16];
  w[0]=dq2h(q0.x,sc);  w[1]=dq2h(q0.y,sc);  w[2]=dq2h(q0.z,sc);  w[3]=dq2h(q0.w,sc);
  w[4]=dq2h(q1.x,sc);  w[5]=dq2h(q1.y,sc);  w[6]=dq2h(q1.z,sc);  w[7]=dq2h(q1.w,sc);
  w[8]=dq2h(q2.x,sc);  w[9]=dq2h(q2.y,sc);  w[10]=dq2h(q2.z,sc); w[11]=dq2h(q2.w,sc);
  w[12]=dq2h(q3.x,sc); w[13]=dq2h(q3.y,sc); w[14]=dq2h(q3.z,sc); w[15]=dq2h(q3.w,sc);
  uint4* o = (uint4*)(dst + bi * 32);
  o[0] = make_uint4(w[0], w[1], w[2], w[3]);
  o[1] = make_uint4(w[4], w[5], w[6], w[7]);
  o[2] = make_uint4(w[8], w[9], w[10], w[11]);
  o[3] = make_uint4(w[12], w[13], w[14], w[15]);
}

// Pipeline sync primitives (counted vmcnt across raw barriers, T3+T4)
__device__ __forceinline__ void waitv4() {
  asm volatile("s_waitcnt vmcnt(4)" ::: "memory");
  __builtin_amdgcn_sched_barrier(0);
}
__device__ __forceinline__ void waitv0() {
  asm volatile("s_waitcnt vmcnt(0)" ::: "memory");
  __builtin_amdgcn_sched_barrier(0);
}
__device__ __forceinline__ void barrier_raw() {
  asm volatile("" ::: "memory");
  __builtin_amdgcn_s_barrier();
  asm volatile("" ::: "memory");
}

// --- router body (RMSNorm + f32 logits + top-4 softmax) ----------------------
__device__ __forceinline__ void router_body(
    int t, const float* __restrict__ x, const float* __restrict__ nw,
    const float* __restrict__ rw, const float* __restrict__ rb,
    ushort* __restrict__ tbuf, float* __restrict__ scores)
{
  const int tid = threadIdx.x;
  const float4* xr = (const float4*)(x + (size_t)t * HDIM);
  float4 v0 = xr[tid * 2], v1 = xr[tid * 2 + 1];
  float ss = v0.x*v0.x + v0.y*v0.y + v0.z*v0.z + v0.w*v0.w
           + v1.x*v1.x + v1.y*v1.y + v1.z*v1.z + v1.w*v1.w;
  __shared__ float red[256];
  red[tid] = ss;
  __syncthreads();
  for (int s = 128; s > 0; s >>= 1) {
    if (tid < s) red[tid] += red[tid + s];
    __syncthreads();
  }
  const float rstd = rsqrtf(red[0] * (1.0f / HDIM) + 1e-5f);
  float xv[8] = {v0.x, v0.y, v0.z, v0.w, v1.x, v1.y, v1.z, v1.w};
  float lp[NE];
#pragma unroll
  for (int e = 0; e < NE; ++e) lp[e] = 0.f;
  union { ushort us[8]; uint4 v; } pkh;
  const int h0 = tid * 8;
#pragma unroll
  for (int j = 0; j < 8; ++j) {
    int h = h0 + j;
    float tn = xv[j] * rstd * nw[h];
    pkh.us[j] = f2h(tn);
#pragma unroll
    for (int e = 0; e < NE; ++e) lp[e] += tn * rw[h * NE + e];
  }
  *(uint4*)(tbuf + (size_t)t * HDIM + h0) = pkh.v;
#pragma unroll
  for (int e = 0; e < NE; ++e)
#pragma unroll
    for (int off = 32; off > 0; off >>= 1) lp[e] += __shfl_down(lp[e], off);
  __shared__ float wred[4][NE];
  if ((tid & 63) == 0) {
#pragma unroll
    for (int e = 0; e < NE; ++e) wred[tid >> 6][e] = lp[e];
  }
  __syncthreads();
  if (tid == 0) {
    float lg[NE];
#pragma unroll
    for (int e = 0; e < NE; ++e)
      lg[e] = wred[0][e] + wred[1][e] + wred[2][e] + wred[3][e] + rb[e];
    bool used[NE] = {false, false, false, false, false, false, false, false};
    float tv[4]; int ti[4];
    for (int s = 0; s < 4; ++s) {          // ties: lowest index first (strict >)
      float best = -3.4e38f; int bi = 0;
      for (int e = 0; e < NE; ++e)
        if (!used[e] && lg[e] > best) { best = lg[e]; bi = e; }
      used[bi] = true; tv[s] = best; ti[s] = bi;
    }
    float den = 0.f, ev[4];
    for (int s = 0; s < 4; ++s) { ev[s] = expf(tv[s] - tv[0]); den += ev[s]; }
    float so[NE] = {0, 0, 0, 0, 0, 0, 0, 0};
    for (int s = 0; s < 4; ++s) so[ti[s]] = ev[s] / den;
#pragma unroll
    for (int e = 0; e < NE; ++e) scores[t * NE + e] = so[e];
  }
}

__global__ __launch_bounds__(256) void router_kernel(
    const float* __restrict__ x, const float* __restrict__ nw,
    const float* __restrict__ rw, const float* __restrict__ rb,
    ushort* __restrict__ tbuf, float* __restrict__ scores)
{
  router_body(blockIdx.x, x, nw, rw, rb, tbuf, scores);
}

// ---- prep: gate_up dequant (blocks 0..NGUB-1) + router (rest) ---------------
#define NGUB (NE * 4096 * 64 / 256)        // 8192 blocks, gu weights only
__global__ __launch_bounds__(256) void prep_kernel(
    const float* __restrict__ x, const float* __restrict__ nw,
    const float* __restrict__ rw, const float* __restrict__ rb,
    const int* __restrict__ gub, const int* __restrict__ gus,
    ushort* __restrict__ tbuf, float* __restrict__ scores,
    ushort* __restrict__ wgu)
{
  if (blockIdx.x >= NGUB) {
    router_body(blockIdx.x - NGUB, x, nw, rw, rb, tbuf, scores);
    return;
  }
  size_t bi = (size_t)blockIdx.x * 256 + threadIdx.x;
  dq_block(gub, gus, wgu, bi);
}

// -- per-expert token compaction + inverse slot map (deterministic scan) -------
__global__ __launch_bounds__(256) void scan_kernel(
    const float* __restrict__ scores, int* __restrict__ cnts,
    int* __restrict__ idx, int* __restrict__ slotmap)
{
  const int e = blockIdx.x, tid = threadIdx.x;
  int loc[4], c = 0;
#pragma unroll
  for (int j = 0; j < 4; ++j) {
    int t = tid * 4 + j;
    loc[j] = (scores[t * NE + e] != 0.f) ? 1 : 0;
    c += loc[j];
  }
  __shared__ int sc[256];
  sc[tid] = c;
  __syncthreads();
  for (int off = 1; off < 256; off <<= 1) {
    int v = (tid >= off) ? sc[tid - off] : 0;
    __syncthreads();
    sc[tid] += v;
    __syncthreads();
  }
  int base = sc[tid] - c;
#pragma unroll
  for (int j = 0; j < 4; ++j)
    if (loc[j]) {
      int t = tid * 4 + j;
      idx[e * T_TOK + base] = t;
      slotmap[t * NE + e] = base;
      base++;
    }
  if (tid == 255) cnts[e] = sc[255];
}

// ---- pipelined fp16 GEMM: 128x128 tile, BK=32, 2-deep counted-vmcnt (T3+T4) --
// MODE 0: gate_up+GLU -> mid; z>=NE blocks instead dequant dn weights (fused,
//         rides gu's idle memory pipe). MODE 1: down+scatter atomics (fallback).
// MODE 2: down -> compacted midD[e][slot][h] plain stores (no atomics).
template<int MODE>
__global__ __launch_bounds__(256) void mx_gemm_p(
    const ushort* __restrict__ Abase,
    const ushort* __restrict__ Bw,
    const float* __restrict__ bias,
    const float* __restrict__ scores,
    const int* __restrict__ cnts,
    const int* __restrict__ tokidx,
    ushort* __restrict__ midH,
    float* __restrict__ outp,
    const int* __restrict__ dnb,
    const int* __restrict__ dns,
    ushort* __restrict__ wdn)
{
  constexpr int NTOT = (MODE == 0) ? 2 * DDIM : HDIM;
  constexpr int K    = (MODE == 0) ? HDIM : DDIM;
  constexpr int NKT  = K / 32;
  const int nt = blockIdx.x, mt = blockIdx.y, e = blockIdx.z;
  if constexpr (MODE == 0) {
    if (e >= NE) {                 // fused dn-weight dequant block
      size_t bi = ((size_t)(e - NE) * 256 + mt * 32 + nt) * 256 + threadIdx.x;
      dq_block(dnb, dns, wdn, bi);
      return;
    }
  }
  const int cnt = cnts[e];
  const int m0 = mt * 128, n0 = nt * 128;
  if (m0 >= cnt) return;
  const ushort* A = Abase + (MODE == 0 ? (size_t)0 : (size_t)e * T_TOK * DDIM);

  __shared__ __align__(16) ushort As[2][128 * 32];   // 2 x 8 KB
  __shared__ __align__(16) ushort Bs[2][128 * 32];   // 2 x 8 KB
  __shared__ int tok_s[128];

  const int tid = threadIdx.x;
  const int lane = tid & 63;
  const int wv = tid >> 6;
  const int wm = wv >> 1, wn = wv & 1;
  const int fr = lane & 15, kg = lane >> 4;

  if (tid < 128) {
    int sl = m0 + tid;
    tok_s[tid] = (sl < cnt) ? tokidx[e * T_TOK + sl] : 0;
  }
  __syncthreads();

  int arow[2];
#pragma unroll
  for (int j = 0; j < 2; ++j) {
    int row = (tid + 256 * j) >> 2;
    arow[j] = (MODE == 0) ? tok_s[row] : (m0 + row);
  }

  f32x4 acc[4][4];
#pragma unroll
  for (int i = 0; i < 4; ++i)
#pragma unroll
    for (int j = 0; j < 4; ++j) acc[i][j] = f32x4{0.f, 0.f, 0.f, 0.f};

  // stage one K-tile (4 global_load_lds per thread: 2 A + 2 B), swizzled source
  auto do_stage = [&](int buf, int kt) {
#pragma unroll
    for (int j = 0; j < 2; ++j) {
      int cidx = tid + 256 * j;
      int row = cidx >> 2, ck = cidx & 3;
      int gck = ck ^ ((row >> 1) & 3);
      size_t go = (size_t)arow[j] * K + kt * 32 + gck * 8;
      __builtin_amdgcn_global_load_lds((v_g*)(A + go),
          (v_l*)((char*)&As[buf][0] + cidx * 16), 16, 0, 0);
    }
#pragma unroll
    for (int j = 0; j < 2; ++j) {
      int cidx = tid + 256 * j;
      int row = cidx >> 2, ck = cidx & 3;
      int gck = ck ^ ((row >> 1) & 3);
      const ushort* g = Bw + ((size_t)e * NTOT + n0 + row) * K + kt * 32 + gck * 8;
      __builtin_amdgcn_global_load_lds((v_g*)g,
          (v_l*)((char*)&Bs[buf][0] + cidx * 16), 16, 0, 0);
    }
  };

  auto do_compute = [&](int buf) {
    f16x8 aF[4], bF[4];
#pragma unroll
    for (int mi = 0; mi < 4; ++mi) {
      int r = wm * 64 + mi * 16 + fr;
      int ck = kg ^ ((r >> 1) & 3);
      aF[mi] = *(const f16x8*)(&As[buf][r * 32 + ck * 8]);
    }
#pragma unroll
    for (int ni = 0; ni < 4; ++ni) {
      int r = wn * 64 + ni * 16 + fr;
      int ck = kg ^ ((r >> 1) & 3);
      bF[ni] = *(const f16x8*)(&Bs[buf][r * 32 + ck * 8]);
    }
#pragma unroll
    for (int mi = 0; mi < 4; ++mi)
#pragma unroll
      for (int ni = 0; ni < 4; ++ni)
        acc[mi][ni] = __builtin_amdgcn_mfma_f32_16x16x32_f16(aF[mi], bF[ni], acc[mi][ni], 0, 0, 0);
  };

  // prologue: 2-deep prefetch
  do_stage(0, 0);
  do_stage(1, 1);
  waitv4();                         // tile0's 4 loads landed
  barrier_raw();                    // all waves' tile0 loads landed
#pragma unroll 2
  for (int kt = 0; kt < NKT; ++kt) {
    do_compute(kt & 1);             // tile kt
    if (kt == NKT - 1) break;
    barrier_raw();                  // all waves done READING buf kt&1
    if (kt + 2 < NKT) {
      do_stage(kt & 1, kt + 2);     // overwrite freed buffer; 8 outstanding
      waitv4();                     // tile kt+1's loads landed
    } else {
      waitv0();                     // tail drain
    }
    barrier_raw();                  // all waves have tile kt+1 ready
  }

  const int c = lane & 15, rg = lane >> 4;
  const int sbase = m0 + wm * 64, nbase = n0 + wn * 64;
  if constexpr (MODE == 0) {
#pragma unroll
    for (int mi = 0; mi < 4; ++mi)
#pragma unroll
      for (int ni = 0; ni < 4; ++ni) {
        int n = nbase + ni * 16 + c;
        float bv = bias[(size_t)e * NTOT + n];
#pragma unroll
        for (int r = 0; r < 4; ++r) {
          int slot = sbase + mi * 16 + rg * 4 + r;
          float val = acc[mi][ni][r] + bv;
          float other = __shfl_xor(val, 1);
          if (!(c & 1) && slot < cnt) {
            int tok = tok_s[slot - m0];
            float g = fminf(val, 7.0f);
            float u = fminf(fmaxf(other, -7.0f), 7.0f);
            float glu = g / (1.0f + expf(-1.702f * g));
            float mv = (u + 1.0f) * glu;
            float s = scores[tok * NE + e];
            midH[((size_t)e * T_TOK + slot) * DDIM + ((uint)n >> 1)] = f2h(mv * s);
          }
        }
      }
  } else if constexpr (MODE == 1) {
#pragma unroll
    for (int mi = 0; mi < 4; ++mi)
#pragma unroll
      for (int ni = 0; ni < 4; ++ni) {
        int n = nbase + ni * 16 + c;
        float dbv = bias[(size_t)e * NTOT + n];
#pragma unroll
        for (int r = 0; r < 4; ++r) {
          int slot = sbase + mi * 16 + rg * 4 + r;
          if (slot < cnt) {
            int tok = tok_s[slot - m0];
            float s = scores[tok * NE + e];
            atomicAdd(outp + (size_t)tok * HDIM + n, acc[mi][ni][r] + s * dbv);
          }
        }
      }
  } else {   // MODE 2: compacted, atomic-free store (bias/score handled in gather)
#pragma unroll
    for (int mi = 0; mi < 4; ++mi)
#pragma unroll
      for (int ni = 0; ni < 4; ++ni) {
        int n = nbase + ni * 16 + c;
#pragma unroll
        for (int r = 0; r < 4; ++r) {
          int slot = sbase + mi * 16 + rg * 4 + r;
          if (slot < cnt)
            outp[((size_t)e * T_TOK + slot) * HDIM + n] = acc[mi][ni][r];
        }
      }
  }
}

// ---- gather: out[t] = x[t] + sum_{e selected} (midD[e][slot][h] + s*dn_bias) --
__global__ __launch_bounds__(256) void gather_kernel(
    const float* __restrict__ x, const float* __restrict__ midD,
    const float* __restrict__ dnbias, const float* __restrict__ scores,
    const int* __restrict__ slotmap, float* __restrict__ outp)
{
  const int t = blockIdx.x, tid = threadIdx.x;
  const int h0 = tid * 8;
  const float4* xr = (const float4*)(x + (size_t)t * HDIM + h0);
  float4 a0 = xr[0], a1 = xr[1];
  float sc[NE]; int sl[NE];
#pragma unroll
  for (int e = 0; e < NE; ++e) sc[e] = scores[t * NE + e];
#pragma unroll
  for (int e = 0; e < NE; ++e) sl[e] = slotmap[t * NE + e];
#pragma unroll
  for (int e = 0; e < NE; ++e) {
    if (sc[e] != 0.f) {
      const float4* mr = (const float4*)(midD + ((size_t)e * T_TOK + sl[e]) * HDIM + h0);
      const float4* br = (const float4*)(dnbias + (size_t)e * HDIM + h0);
      float4 m0 = mr[0], m1 = mr[1];
      float4 b0 = br[0], b1 = br[1];
      float s = sc[e];
      a0.x += m0.x + s * b0.x; a0.y += m0.y + s * b0.y;
      a0.z += m0.z + s * b0.z; a0.w += m0.w + s * b0.w;
      a1.x += m1.x + s * b1.x; a1.y += m1.y + s * b1.y;
      a1.z += m1.z + s * b1.z; a1.w += m1.w + s * b1.w;
    }
  }
  float4* orow = (float4*)(outp + (size_t)t * HDIM + h0);
  orow[0] = a0;
  orow[1] = a1;
}

// ---- fallback kernels (inline fp16 dequant, simple 1-phase; ws-too-small) ----
__global__ __launch_bounds__(256) void gu_gemm_q(
    const ushort* __restrict__ At,
    const int* __restrict__ qblocks,
    const int* __restrict__ qscales,
    const float* __restrict__ bias,
    const float* __restrict__ scores,
    const int* __restrict__ cnts,
    const int* __restrict__ tokidx,
    ushort* __restrict__ midH)
{
  constexpr int NTOT = 2 * DDIM;
  constexpr int K = HDIM;
  const int nt = blockIdx.x, mt = blockIdx.y, e = blockIdx.z;
  const int cnt = cnts[e];
  const int m0 = mt * 128, n0 = nt * 128;
  if (m0 >= cnt) return;

  __shared__ __align__(16) ushort As[128 * 64];
  __shared__ __align__(16) ushort Bs[128 * 64];
  __shared__ int tok_s[128];

  const int tid = threadIdx.x;
  const int lane = tid & 63;
  const int wv = tid >> 6;
  const int wm = wv >> 1, wn = wv & 1;
  const int fr = lane & 15, kg = lane >> 4;

  if (tid < 128) {
    int sl = m0 + tid;
    tok_s[tid] = (sl < cnt) ? tokidx[e * T_TOK + sl] : 0;
  }
  __syncthreads();
  int arow[4];
#pragma unroll
  for (int j = 0; j < 4; ++j) arow[j] = tok_s[(tid + 256 * j) >> 3];

  f32x4 acc[4][4];
#pragma unroll
  for (int i = 0; i < 4; ++i)
#pragma unroll
    for (int j = 0; j < 4; ++j) acc[i][j] = f32x4{0.f, 0.f, 0.f, 0.f};

  for (int kt = 0; kt < K / 64; ++kt) {
#pragma unroll
    for (int j = 0; j < 4; ++j) {
      int cidx = tid + 256 * j;
      int row = cidx >> 3, ck = cidx & 7;
      int sck = ck ^ (row & 7);
      size_t go = (size_t)arow[j] * K + kt * 64 + sck * 8;
      __builtin_amdgcn_global_load_lds((v_g*)(At + go), (v_l*)((char*)As + cidx * 16), 16, 0, 0);
    }
    {
      const int brow = tid >> 1, bblk = tid & 1;
      int kb = kt * 2 + bblk;
      size_t bi = ((size_t)e * NTOT + n0 + brow) * (K / 32) + kb;
      int sc = qscales[bi];
      const int4* bp = (const int4*)(qblocks + bi * 16);
      int4 q0 = bp[0], q1 = bp[1], q2 = bp[2], q3 = bp[3];
      uint w[16];
      w[0]=dq2h(q0.x,sc);  w[1]=dq2h(q0.y,sc);  w[2]=dq2h(q0.z,sc);  w[3]=dq2h(q0.w,sc);
      w[4]=dq2h(q1.x,sc);  w[5]=dq2h(q1.y,sc);  w[6]=dq2h(q1.z,sc);  w[7]=dq2h(q1.w,sc);
      w[8]=dq2h(q2.x,sc);  w[9]=dq2h(q2.y,sc);  w[10]=dq2h(q2.z,sc); w[11]=dq2h(q2.w,sc);
      w[12]=dq2h(q3.x,sc); w[13]=dq2h(q3.y,sc); w[14]=dq2h(q3.z,sc); w[15]=dq2h(q3.w,sc);
#pragma unroll
      for (int q = 0; q < 4; ++q) {
        int ck = bblk * 4 + q;
        int sk = ck ^ (brow & 7);
        *(uint4*)((char*)Bs + brow * 128 + sk * 16) =
            make_uint4(w[4*q], w[4*q+1], w[4*q+2], w[4*q+3]);
      }
    }
    __syncthreads();
#pragma unroll
    for (int kh = 0; kh < 2; ++kh) {
      f16x8 aF[4], bF[4];
#pragma unroll
      for (int mi = 0; mi < 4; ++mi) {
        int r = wm * 64 + mi * 16 + fr;
        int ck = (kh * 4 + kg) ^ (r & 7);
        aF[mi] = *(const f16x8*)((const char*)As + r * 128 + ck * 16);
      }
#pragma unroll
      for (int ni = 0; ni < 4; ++ni) {
        int r = wn * 64 + ni * 16 + fr;
        int ck = (kh * 4 + kg) ^ (r & 7);
        bF[ni] = *(const f16x8*)((const char*)Bs + r * 128 + ck * 16);
      }
#pragma unroll
      for (int mi = 0; mi < 4; ++mi)
#pragma unroll
        for (int ni = 0; ni < 4; ++ni)
          acc[mi][ni] = __builtin_amdgcn_mfma_f32_16x16x32_f16(aF[mi], bF[ni], acc[mi][ni], 0, 0, 0);
    }
    __syncthreads();
  }

  const int c = lane & 15, rg = lane >> 4;
  const int sbase = m0 + wm * 64, nbase = n0 + wn * 64;
#pragma unroll
  for (int mi = 0; mi < 4; ++mi)
#pragma unroll
    for (int ni = 0; ni < 4; ++ni) {
      int n = nbase + ni * 16 + c;
      float bv = bias[(size_t)e * NTOT + n];
#pragma unroll
      for (int r = 0; r < 4; ++r) {
        int slot = sbase + mi * 16 + rg * 4 + r;
        float val = acc[mi][ni][r] + bv;
        float other = __shfl_xor(val, 1);
        if (!(c & 1) && slot < cnt) {
          int tok = tok_s[slot - m0];
          float g = fminf(val, 7.0f);
          float u = fminf(fmaxf(other, -7.0f), 7.0f);
          float glu = g / (1.0f + expf(-1.702f * g));
          float mv = (u + 1.0f) * glu;
          float s = scores[tok * NE + e];
          midH[((size_t)e * T_TOK + slot) * DDIM + ((uint)n >> 1)] = f2h(mv * s);
        }
      }
    }
}

__global__ __launch_bounds__(256) void dn_gemm_q(
    const ushort* __restrict__ Abase,
    const int* __restrict__ qblocks,
    const int* __restrict__ qscales,
    const float* __restrict__ bias,
    const float* __restrict__ scores,
    const int* __restrict__ cnts,
    const int* __restrict__ tokidx,
    float* __restrict__ outp)
{
  constexpr int NTOT = HDIM;
  constexpr int K    = DDIM;
  const int nt = blockIdx.x, mt = blockIdx.y, e = blockIdx.z;
  const int cnt = cnts[e];
  const int m0 = mt * 128, n0 = nt * 128;
  if (m0 >= cnt) return;
  const ushort* A = Abase + (size_t)e * T_TOK * DDIM;

  __shared__ __align__(16) ushort As[128 * 64];
  __shared__ __align__(16) ushort Bs[128 * 64];
  __shared__ int tok_s[128];

  const int tid = threadIdx.x;
  const int lane = tid & 63;
  const int wv = tid >> 6;
  const int wm = wv >> 1, wn = wv & 1;
  const int fr = lane & 15, kg = lane >> 4;

  if (tid < 128) {
    int sl = m0 + tid;
    tok_s[tid] = (sl < cnt) ? tokidx[e * T_TOK + sl] : 0;
  }
  __syncthreads();

  f32x4 acc[4][4];
#pragma unroll
  for (int i = 0; i < 4; ++i)
#pragma unroll
    for (int j = 0; j < 4; ++j) acc[i][j] = f32x4{0.f, 0.f, 0.f, 0.f};

  for (int kt = 0; kt < K / 64; ++kt) {
#pragma unroll
    for (int j = 0; j < 4; ++j) {
      int cidx = tid + 256 * j;
      int row = cidx >> 3, ck = cidx & 7;
      int sck = ck ^ (row & 7);
      size_t go = (size_t)(m0 + row) * K + kt * 64 + sck * 8;
      __builtin_amdgcn_global_load_lds((v_g*)(A + go), (v_l*)((char*)As + cidx * 16), 16, 0, 0);
    }
    {
      const int brow = tid >> 1, bblk = tid & 1;
      int kb = kt * 2 + bblk;
      size_t bi = ((size_t)e * NTOT + n0 + brow) * (K / 32) + kb;
      int sc = qscales[bi];
      const int4* bp = (const int4*)(qblocks + bi * 16);
      int4 q0 = bp[0], q1 = bp[1], q2 = bp[2], q3 = bp[3];
      uint w[16];
      w[0]=dq2h(q0.x,sc);  w[1]=dq2h(q0.y,sc);  w[2]=dq2h(q0.z,sc);  w[3]=dq2h(q0.w,sc);
      w[4]=dq2h(q1.x,sc);  w[5]=dq2h(q1.y,sc);  w[6]=dq2h(q1.z,sc);  w[7]=dq2h(q1.w,sc);
      w[8]=dq2h(q2.x,sc);  w[9]=dq2h(q2.y,sc);  w[10]=dq2h(q2.z,sc); w[11]=dq2h(q2.w,sc);
      w[12]=dq2h(q3.x,sc); w[13]=dq2h(q3.y,sc); w[14]=dq2h(q3.z,sc); w[15]=dq2h(q3.w,sc);
#pragma unroll
      for (int q = 0; q < 4; ++q) {
        int ck = bblk * 4 + q;
        int sk = ck ^ (brow & 7);
        *(uint4*)((char*)Bs + brow * 128 + sk * 16) =
            make_uint4(w[4*q], w[4*q+1], w[4*q+2], w[4*q+3]);
      }
    }
    __syncthreads();
#pragma unroll
    for (int kh = 0; kh < 2; ++kh) {
      f16x8 aF[4], bF[4];
#pragma unroll
      for (int mi = 0; mi < 4; ++mi) {
        int r = wm * 64 + mi * 16 + fr;
        int ck = (kh * 4 + kg) ^ (r & 7);
        aF[mi] = *(const f16x8*)((const char*)As + r * 128 + ck * 16);
      }
#pragma unroll
      for (int ni = 0; ni < 4; ++ni) {
        int r = wn * 64 + ni * 16 + fr;
        int ck = (kh * 4 + kg) ^ (r & 7);
        bF[ni] = *(const f16x8*)((const char*)Bs + r * 128 + ck * 16);
      }
#pragma unroll
      for (int mi = 0; mi < 4; ++mi)
#pragma unroll
        for (int ni = 0; ni < 4; ++ni)
          acc[mi][ni] = __builtin_amdgcn_mfma_f32_16x16x32_f16(aF[mi], bF[ni], acc[mi][ni], 0, 0, 0);
    }
    __syncthreads();
  }

  const int c = lane & 15, rg = lane >> 4;
  const int sbase = m0 + wm * 64, nbase = n0 + wn * 64;
#pragma unroll
  for (int mi = 0; mi < 4; ++mi)
#pragma unroll
    for (int ni = 0; ni < 4; ++ni) {
      int n = nbase + ni * 16 + c;
      float dbv = bias[(size_t)e * NTOT + n];
#pragma unroll
      for (int r = 0; r < 4; ++r) {
        int slot = sbase + mi * 16 + rg * 4 + r;
        if (slot < cnt) {
          int tok = tok_s[slot - m0];
          float s = scores[tok * NE + e];
          atomicAdd(outp + (size_t)tok * HDIM + n, acc[mi][ni][r] + s * dbv);
        }
      }
    }
}

extern "C" void kernel_launch(void* const* d_in, const int* in_sizes, int n_in,
                              void* d_out, int out_size, void* d_ws, size_t ws_size,
                              hipStream_t stream)
{
  const float* x      = (const float*)d_in[0];
  const float* nw     = (const float*)d_in[1];
  const float* rw     = (const float*)d_in[2];
  const float* rb     = (const float*)d_in[3];
  const int*   gus    = (const int*)d_in[4];
  const int*   gub    = (const int*)d_in[5];
  const float* gubias = (const float*)d_in[6];
  const int*   dns    = (const int*)d_in[7];
  const int*   dnb    = (const int*)d_in[8];
  const float* dnbias = (const float*)d_in[9];

  char* ws = (char*)d_ws;
  const size_t SZ_WGU  = (size_t)NE * 4096 * 2048 * 2;   // 134 MB
  const size_t SZ_WDN  = (size_t)NE * 2048 * 2048 * 2;   //  67 MB
  const size_t SZ_T    = (size_t)T_TOK * HDIM * 2;       //   4 MB
  const size_t SZ_MID  = (size_t)NE * T_TOK * DDIM * 2;  //  33.5 MB
  const size_t SZ_MIDD = (size_t)NE * T_TOK * HDIM * 4;  //  67 MB (f32 compacted dn out)
  const size_t SZ_SC   = (size_t)T_TOK * NE * 4;
  const size_t SZ_IDX  = (size_t)NE * T_TOK * 4;
  const size_t SZ_SLOT = (size_t)T_TOK * NE * 4;
  const size_t SZ_CNT  = 128;

  const size_t need_mid = SZ_WGU + SZ_WDN + SZ_T + SZ_MID + SZ_SC + SZ_IDX + SZ_SLOT + SZ_CNT;
  const size_t need_big = need_mid + SZ_MIDD;
  const bool predeq = ws_size >= need_mid;
  const bool bigws  = ws_size >= need_big;

  ushort* wgu = (ushort*)ws;
  ushort* wdn = (ushort*)(ws + SZ_WGU);
  char* base2 = predeq ? (ws + SZ_WGU + SZ_WDN) : ws;
  ushort* tbuf   = (ushort*)base2;
  ushort* midHp  = (ushort*)(base2 + SZ_T);
  float*  scores = (float*)(base2 + SZ_T + SZ_MID);
  int*    cnts   = (int*)(base2 + SZ_T + SZ_MID + SZ_SC);
  int*    tokidx = (int*)(base2 + SZ_T + SZ_MID + SZ_SC + SZ_CNT);
  int*    slotmap= (int*)(base2 + SZ_T + SZ_MID + SZ_SC + SZ_CNT + SZ_IDX);
  float*  midD   = (float*)(base2 + SZ_T + SZ_MID + SZ_SC + SZ_CNT + SZ_IDX + SZ_SLOT);
  float*  outp   = (float*)d_out;

  if (predeq) {
    prep_kernel<<<NGUB + T_TOK, 256, 0, stream>>>(
        x, nw, rw, rb, gub, gus, tbuf, scores, wgu);
    scan_kernel<<<NE, 256, 0, stream>>>(scores, cnts, tokidx, slotmap);
    // gate_up GEMM + fused dn-weight dequant (z in [NE, NE+16))
    mx_gemm_p<0><<<dim3(32, 8, NE + 16), 256, 0, stream>>>(
        tbuf, wgu, gubias, scores, cnts, tokidx, midHp, nullptr, dnb, dns, wdn);
    if (bigws) {
      mx_gemm_p<2><<<dim3(16, 8, NE), 256, 0, stream>>>(
          midHp, wdn, dnbias, scores, cnts, tokidx, nullptr, midD, nullptr, nullptr, nullptr);
      gather_kernel<<<T_TOK, 256, 0, stream>>>(
          x, midD, dnbias, scores, slotmap, outp);
    } else {
      hipMemcpyAsync(d_out, (void*)x, (size_t)T_TOK * HDIM * 4,
                     hipMemcpyDeviceToDevice, stream);
      mx_gemm_p<1><<<dim3(16, 8, NE), 256, 0, stream>>>(
          midHp, wdn, dnbias, scores, cnts, tokidx, nullptr, outp, nullptr, nullptr, nullptr);
    }
  } else {
    hipMemcpyAsync(d_out, (void*)x, (size_t)T_TOK * HDIM * 4,
                   hipMemcpyDeviceToDevice, stream);
    router_kernel<<<T_TOK, 256, 0, stream>>>(x, nw, rw, rb, tbuf, scores);
    scan_kernel<<<NE, 256, 0, stream>>>(scores, cnts, tokidx, slotmap);
    gu_gemm_q<<<dim3(32, 8, NE), 256, 0, stream>>>(
        tbuf, gub, gus, gubias, scores, cnts, tokidx, midHp);
    dn_gemm_q<<<dim3(16, 8, NE), 256, 0, stream>>>(
        midHp, dnb, dns, dnbias, scores, cnts, tokidx, outp);
  }
}

// Round 21
// 289.648 us; speedup vs baseline: 1.3797x; 1.0058x over previous
//
#include <hip/hip_runtime.h>
#include <hip/hip_bf16.h>
#include <stdint.h>

#define T_TOK 1024
#define HDIM 2048
#define DDIM 2048
#define NE 8

typedef unsigned int uint;
typedef unsigned short ushort;

typedef _Float16 f16x8 __attribute__((ext_vector_type(8)));
typedef float f32x4 __attribute__((ext_vector_type(4)));

typedef __attribute__((address_space(1))) const void v_g;
typedef __attribute__((address_space(3))) void v_l;

__device__ __forceinline__ ushort f2h(float f) {
  _Float16 h = (_Float16)f;           // v_cvt_f16_f32, RTNE
  return *(ushort*)&h;
}

// e2m1 nibble * 2^(sc-127) -> fp16 bits (exact; subnormals handled; <2^-24 -> 0)
__device__ __forceinline__ uint dqh(uint nib, int sc) {
  uint m = nib & 7u;
  int e = (int)(m >> 1);
  int e16 = sc - 113 + e;                       // fp16 biased exponent
  uint mant = ((m & 1u) && m >= 2u) ? 0x200u : 0u;
  uint bits;
  if (m == 0u || e16 <= -10) bits = 0u;
  else if (e16 >= 1) bits = ((uint)e16 << 10) | mant;
  else bits = (0x400u | mant) >> (1 - e16);     // subnormal (exact for these values)
  return bits | ((nib & 8u) << 12);
}
__device__ __forceinline__ uint dq2h(uint b, int sc) {
  return dqh(b & 15u, sc) | (dqh((b >> 4) & 15u, sc) << 16);
}

// one scale-block dequant: 16 int32 (packed nibbles) -> 32 fp16
__device__ __forceinline__ void dq_block(
    const int* __restrict__ qb, const int* __restrict__ qs,
    ushort* __restrict__ dst, size_t bi)
{
  int sc = qs[bi];
  const int4* bp = (const int4*)(qb + bi * 16);
  int4 q0 = bp[0], q1 = bp[1], q2 = bp[2], q3 = bp[3];
  uint w[16];
  w[0]=dq2h(q0.x,sc);  w[1]=dq2h(q0.y,sc);  w[2]=dq2h(q0.z,sc);  w[3]=dq2h(q0.w,sc);
  w[4]=dq2h(q1.x,sc);  w[5]=dq2h(q1.y,sc);  w[6]=dq2h(q1.z,sc);  w[7]=dq2h(q1.w,sc);
  w[8]=dq2h(q2.x,sc);  w[9]=dq2h(q2.y,sc);  w[10]=dq2h(q2.z,sc); w[11]=dq2h(q2.w,sc);
  w[12]=dq2h(q3.x,sc); w[13]=dq2h(q3.y,sc); w[14]=dq2h(q3.z,sc); w[15]=dq2h(q3.w,sc);
  uint4* o = (uint4*)(dst + bi * 32);
  o[0] = make_uint4(w[0], w[1], w[2], w[3]);
  o[1] = make_uint4(w[4], w[5], w[6], w[7]);
  o[2] = make_uint4(w[8], w[9], w[10], w[11]);
  o[3] = make_uint4(w[12], w[13], w[14], w[15]);
}

// Pipeline sync primitives (counted vmcnt across raw barriers, T3+T4)
__device__ __forceinline__ void waitv4() {
  asm volatile("s_waitcnt vmcnt(4)" ::: "memory");
  __builtin_amdgcn_sched_barrier(0);
}
__device__ __forceinline__ void waitv0() {
  asm volatile("s_waitcnt vmcnt(0)" ::: "memory");
  __builtin_amdgcn_sched_barrier(0);
}
__device__ __forceinline__ void barrier_raw() {
  asm volatile("" ::: "memory");
  __builtin_amdgcn_s_barrier();
  asm volatile("" ::: "memory");
}

// --- router body (RMSNorm + f32 logits + top-4 softmax) ----------------------
__device__ __forceinline__ void router_body(
    int t, const float* __restrict__ x, const float* __restrict__ nw,
    const float* __restrict__ rw, const float* __restrict__ rb,
    ushort* __restrict__ tbuf, float* __restrict__ scores)
{
  const int tid = threadIdx.x;
  const float4* xr = (const float4*)(x + (size_t)t * HDIM);
  float4 v0 = xr[tid * 2], v1 = xr[tid * 2 + 1];
  float ss = v0.x*v0.x + v0.y*v0.y + v0.z*v0.z + v0.w*v0.w
           + v1.x*v1.x + v1.y*v1.y + v1.z*v1.z + v1.w*v1.w;
  __shared__ float red[256];
  red[tid] = ss;
  __syncthreads();
  for (int s = 128; s > 0; s >>= 1) {
    if (tid < s) red[tid] += red[tid + s];
    __syncthreads();
  }
  const float rstd = rsqrtf(red[0] * (1.0f / HDIM) + 1e-5f);
  float xv[8] = {v0.x, v0.y, v0.z, v0.w, v1.x, v1.y, v1.z, v1.w};
  float lp[NE];
#pragma unroll
  for (int e = 0; e < NE; ++e) lp[e] = 0.f;
  union { ushort us[8]; uint4 v; } pkh;
  const int h0 = tid * 8;
#pragma unroll
  for (int j = 0; j < 8; ++j) {
    int h = h0 + j;
    float tn = xv[j] * rstd * nw[h];
    pkh.us[j] = f2h(tn);
#pragma unroll
    for (int e = 0; e < NE; ++e) lp[e] += tn * rw[h * NE + e];
  }
  *(uint4*)(tbuf + (size_t)t * HDIM + h0) = pkh.v;
#pragma unroll
  for (int e = 0; e < NE; ++e)
#pragma unroll
    for (int off = 32; off > 0; off >>= 1) lp[e] += __shfl_down(lp[e], off);
  __shared__ float wred[4][NE];
  if ((tid & 63) == 0) {
#pragma unroll
    for (int e = 0; e < NE; ++e) wred[tid >> 6][e] = lp[e];
  }
  __syncthreads();
  if (tid == 0) {
    float lg[NE];
#pragma unroll
    for (int e = 0; e < NE; ++e)
      lg[e] = wred[0][e] + wred[1][e] + wred[2][e] + wred[3][e] + rb[e];
    bool used[NE] = {false, false, false, false, false, false, false, false};
    float tv[4]; int ti[4];
    for (int s = 0; s < 4; ++s) {          // ties: lowest index first (strict >)
      float best = -3.4e38f; int bi = 0;
      for (int e = 0; e < NE; ++e)
        if (!used[e] && lg[e] > best) { best = lg[e]; bi = e; }
      used[bi] = true; tv[s] = best; ti[s] = bi;
    }
    float den = 0.f, ev[4];
    for (int s = 0; s < 4; ++s) { ev[s] = expf(tv[s] - tv[0]); den += ev[s]; }
    float so[NE] = {0, 0, 0, 0, 0, 0, 0, 0};
    for (int s = 0; s < 4; ++s) so[ti[s]] = ev[s] / den;
#pragma unroll
    for (int e = 0; e < NE; ++e) scores[t * NE + e] = so[e];
  }
}

__global__ __launch_bounds__(256) void router_kernel(
    const float* __restrict__ x, const float* __restrict__ nw,
    const float* __restrict__ rw, const float* __restrict__ rb,
    ushort* __restrict__ tbuf, float* __restrict__ scores)
{
  router_body(blockIdx.x, x, nw, rw, rb, tbuf, scores);
}

// ---- prep: gate_up dequant (blocks 0..NGUB-1) + router (rest) ---------------
#define NGUB (NE * 4096 * 64 / 256)        // 8192 blocks, gu weights only
__global__ __launch_bounds__(256) void prep_kernel(
    const float* __restrict__ x, const float* __restrict__ nw,
    const float* __restrict__ rw, const float* __restrict__ rb,
    const int* __restrict__ gub, const int* __restrict__ gus,
    ushort* __restrict__ tbuf, float* __restrict__ scores,
    ushort* __restrict__ wgu)
{
  if (blockIdx.x >= NGUB) {
    router_body(blockIdx.x - NGUB, x, nw, rw, rb, tbuf, scores);
    return;
  }
  size_t bi = (size_t)blockIdx.x * 256 + threadIdx.x;
  dq_block(gub, gus, wgu, bi);
}

// -- per-expert token compaction + inverse slot map (deterministic scan) -------
__global__ __launch_bounds__(256) void scan_kernel(
    const float* __restrict__ scores, int* __restrict__ cnts,
    int* __restrict__ idx, int* __restrict__ slotmap)
{
  const int e = blockIdx.x, tid = threadIdx.x;
  int loc[4], c = 0;
#pragma unroll
  for (int j = 0; j < 4; ++j) {
    int t = tid * 4 + j;
    loc[j] = (scores[t * NE + e] != 0.f) ? 1 : 0;
    c += loc[j];
  }
  __shared__ int sc[256];
  sc[tid] = c;
  __syncthreads();
  for (int off = 1; off < 256; off <<= 1) {
    int v = (tid >= off) ? sc[tid - off] : 0;
    __syncthreads();
    sc[tid] += v;
    __syncthreads();
  }
  int base = sc[tid] - c;
#pragma unroll
  for (int j = 0; j < 4; ++j)
    if (loc[j]) {
      int t = tid * 4 + j;
      idx[e * T_TOK + base] = t;
      slotmap[t * NE + e] = base;
      base++;
    }
  if (tid == 255) cnts[e] = sc[255];
}

// ---- pipelined fp16 GEMM: 128x128 tile, BK=32, 2-deep counted-vmcnt (T3+T4) --
// MODE 0: gate_up+GLU -> mid; z>=NE blocks instead dequant dn weights (fused,
//         rides gu's idle memory pipe). MODE 1: down+scatter atomics (fallback).
// MODE 2: down -> compacted midD[e][slot][h] fp16 plain stores (no atomics).
template<int MODE>
__global__ __launch_bounds__(256) void mx_gemm_p(
    const ushort* __restrict__ Abase,
    const ushort* __restrict__ Bw,
    const float* __restrict__ bias,
    const float* __restrict__ scores,
    const int* __restrict__ cnts,
    const int* __restrict__ tokidx,
    ushort* __restrict__ midH,
    float* __restrict__ outp,
    const int* __restrict__ dnb,
    const int* __restrict__ dns,
    ushort* __restrict__ wdn)
{
  constexpr int NTOT = (MODE == 0) ? 2 * DDIM : HDIM;
  constexpr int K    = (MODE == 0) ? HDIM : DDIM;
  constexpr int NKT  = K / 32;
  const int nt = blockIdx.x, mt = blockIdx.y, e = blockIdx.z;
  if constexpr (MODE == 0) {
    if (e >= NE) {                 // fused dn-weight dequant block
      size_t bi = ((size_t)(e - NE) * 256 + mt * 32 + nt) * 256 + threadIdx.x;
      dq_block(dnb, dns, wdn, bi);
      return;
    }
  }
  const int cnt = cnts[e];
  const int m0 = mt * 128, n0 = nt * 128;
  if (m0 >= cnt) return;
  const ushort* A = Abase + (MODE == 0 ? (size_t)0 : (size_t)e * T_TOK * DDIM);

  __shared__ __align__(16) ushort As[2][128 * 32];   // 2 x 8 KB
  __shared__ __align__(16) ushort Bs[2][128 * 32];   // 2 x 8 KB
  __shared__ int tok_s[128];

  const int tid = threadIdx.x;
  const int lane = tid & 63;
  const int wv = tid >> 6;
  const int wm = wv >> 1, wn = wv & 1;
  const int fr = lane & 15, kg = lane >> 4;

  if (tid < 128) {
    int sl = m0 + tid;
    tok_s[tid] = (sl < cnt) ? tokidx[e * T_TOK + sl] : 0;
  }
  __syncthreads();

  int arow[2];
#pragma unroll
  for (int j = 0; j < 2; ++j) {
    int row = (tid + 256 * j) >> 2;
    arow[j] = (MODE == 0) ? tok_s[row] : (m0 + row);
  }

  f32x4 acc[4][4];
#pragma unroll
  for (int i = 0; i < 4; ++i)
#pragma unroll
    for (int j = 0; j < 4; ++j) acc[i][j] = f32x4{0.f, 0.f, 0.f, 0.f};

  // stage one K-tile (4 global_load_lds per thread: 2 A + 2 B), swizzled source
  auto do_stage = [&](int buf, int kt) {
#pragma unroll
    for (int j = 0; j < 2; ++j) {
      int cidx = tid + 256 * j;
      int row = cidx >> 2, ck = cidx & 3;
      int gck = ck ^ ((row >> 1) & 3);
      size_t go = (size_t)arow[j] * K + kt * 32 + gck * 8;
      __builtin_amdgcn_global_load_lds((v_g*)(A + go),
          (v_l*)((char*)&As[buf][0] + cidx * 16), 16, 0, 0);
    }
#pragma unroll
    for (int j = 0; j < 2; ++j) {
      int cidx = tid + 256 * j;
      int row = cidx >> 2, ck = cidx & 3;
      int gck = ck ^ ((row >> 1) & 3);
      const ushort* g = Bw + ((size_t)e * NTOT + n0 + row) * K + kt * 32 + gck * 8;
      __builtin_amdgcn_global_load_lds((v_g*)g,
          (v_l*)((char*)&Bs[buf][0] + cidx * 16), 16, 0, 0);
    }
  };

  auto do_compute = [&](int buf) {
    f16x8 aF[4], bF[4];
#pragma unroll
    for (int mi = 0; mi < 4; ++mi) {
      int r = wm * 64 + mi * 16 + fr;
      int ck = kg ^ ((r >> 1) & 3);
      aF[mi] = *(const f16x8*)(&As[buf][r * 32 + ck * 8]);
    }
#pragma unroll
    for (int ni = 0; ni < 4; ++ni) {
      int r = wn * 64 + ni * 16 + fr;
      int ck = kg ^ ((r >> 1) & 3);
      bF[ni] = *(const f16x8*)(&Bs[buf][r * 32 + ck * 8]);
    }
#pragma unroll
    for (int mi = 0; mi < 4; ++mi)
#pragma unroll
      for (int ni = 0; ni < 4; ++ni)
        acc[mi][ni] = __builtin_amdgcn_mfma_f32_16x16x32_f16(aF[mi], bF[ni], acc[mi][ni], 0, 0, 0);
  };

  // prologue: 2-deep prefetch
  do_stage(0, 0);
  do_stage(1, 1);
  waitv4();                         // tile0's 4 loads landed
  barrier_raw();                    // all waves' tile0 loads landed
#pragma unroll 2
  for (int kt = 0; kt < NKT; ++kt) {
    do_compute(kt & 1);             // tile kt
    if (kt == NKT - 1) break;
    barrier_raw();                  // all waves done READING buf kt&1
    if (kt + 2 < NKT) {
      do_stage(kt & 1, kt + 2);     // overwrite freed buffer; 8 outstanding
      waitv4();                     // tile kt+1's loads landed
    } else {
      waitv0();                     // tail drain
    }
    barrier_raw();                  // all waves have tile kt+1 ready
  }

  const int c = lane & 15, rg = lane >> 4;
  const int sbase = m0 + wm * 64, nbase = n0 + wn * 64;
  if constexpr (MODE == 0) {
#pragma unroll
    for (int mi = 0; mi < 4; ++mi)
#pragma unroll
      for (int ni = 0; ni < 4; ++ni) {
        int n = nbase + ni * 16 + c;
        float bv = bias[(size_t)e * NTOT + n];
#pragma unroll
        for (int r = 0; r < 4; ++r) {
          int slot = sbase + mi * 16 + rg * 4 + r;
          float val = acc[mi][ni][r] + bv;
          float other = __shfl_xor(val, 1);
          if (!(c & 1) && slot < cnt) {
            int tok = tok_s[slot - m0];
            float g = fminf(val, 7.0f);
            float u = fminf(fmaxf(other, -7.0f), 7.0f);
            float glu = g / (1.0f + expf(-1.702f * g));
            float mv = (u + 1.0f) * glu;
            float s = scores[tok * NE + e];
            midH[((size_t)e * T_TOK + slot) * DDIM + ((uint)n >> 1)] = f2h(mv * s);
          }
        }
      }
  } else if constexpr (MODE == 1) {
#pragma unroll
    for (int mi = 0; mi < 4; ++mi)
#pragma unroll
      for (int ni = 0; ni < 4; ++ni) {
        int n = nbase + ni * 16 + c;
        float dbv = bias[(size_t)e * NTOT + n];
#pragma unroll
        for (int r = 0; r < 4; ++r) {
          int slot = sbase + mi * 16 + rg * 4 + r;
          if (slot < cnt) {
            int tok = tok_s[slot - m0];
            float s = scores[tok * NE + e];
            atomicAdd(outp + (size_t)tok * HDIM + n, acc[mi][ni][r] + s * dbv);
          }
        }
      }
  } else {   // MODE 2: compacted, atomic-free fp16 store (bias/score in gather)
#pragma unroll
    for (int mi = 0; mi < 4; ++mi)
#pragma unroll
      for (int ni = 0; ni < 4; ++ni) {
        int n = nbase + ni * 16 + c;
#pragma unroll
        for (int r = 0; r < 4; ++r) {
          int slot = sbase + mi * 16 + rg * 4 + r;
          if (slot < cnt)
            midH[((size_t)e * T_TOK + slot) * HDIM + n] = f2h(acc[mi][ni][r]);
        }
      }
  }
}

// ---- gather: out[t] = x[t] + sum_{e selected} (midD[e][slot][h] + s*dn_bias) --
__global__ __launch_bounds__(256) void gather_kernel(
    const float* __restrict__ x, const ushort* __restrict__ midD,
    const float* __restrict__ dnbias, const float* __restrict__ scores,
    const int* __restrict__ slotmap, float* __restrict__ outp)
{
  const int t = blockIdx.x, tid = threadIdx.x;
  const int h0 = tid * 8;
  const float4* xr = (const float4*)(x + (size_t)t * HDIM + h0);
  float4 a0 = xr[0], a1 = xr[1];
  float sc[NE]; int sl[NE];
#pragma unroll
  for (int e = 0; e < NE; ++e) sc[e] = scores[t * NE + e];
#pragma unroll
  for (int e = 0; e < NE; ++e) sl[e] = slotmap[t * NE + e];
#pragma unroll
  for (int e = 0; e < NE; ++e) {
    if (sc[e] != 0.f) {
      const f16x8 m8 = *(const f16x8*)(midD + ((size_t)e * T_TOK + sl[e]) * HDIM + h0);
      const float4* br = (const float4*)(dnbias + (size_t)e * HDIM + h0);
      float4 b0 = br[0], b1 = br[1];
      float s = sc[e];
      a0.x += (float)m8[0] + s * b0.x; a0.y += (float)m8[1] + s * b0.y;
      a0.z += (float)m8[2] + s * b0.z; a0.w += (float)m8[3] + s * b0.w;
      a1.x += (float)m8[4] + s * b1.x; a1.y += (float)m8[5] + s * b1.y;
      a1.z += (float)m8[6] + s * b1.z; a1.w += (float)m8[7] + s * b1.w;
    }
  }
  float4* orow = (float4*)(outp + (size_t)t * HDIM + h0);
  orow[0] = a0;
  orow[1] = a1;
}

// ---- fallback kernels (inline fp16 dequant, simple 1-phase; ws-too-small) ----
__global__ __launch_bounds__(256) void gu_gemm_q(
    const ushort* __restrict__ At,
    const int* __restrict__ qblocks,
    const int* __restrict__ qscales,
    const float* __restrict__ bias,
    const float* __restrict__ scores,
    const int* __restrict__ cnts,
    const int* __restrict__ tokidx,
    ushort* __restrict__ midH)
{
  constexpr int NTOT = 2 * DDIM;
  constexpr int K = HDIM;
  const int nt = blockIdx.x, mt = blockIdx.y, e = blockIdx.z;
  const int cnt = cnts[e];
  const int m0 = mt * 128, n0 = nt * 128;
  if (m0 >= cnt) return;

  __shared__ __align__(16) ushort As[128 * 64];
  __shared__ __align__(16) ushort Bs[128 * 64];
  __shared__ int tok_s[128];

  const int tid = threadIdx.x;
  const int lane = tid & 63;
  const int wv = tid >> 6;
  const int wm = wv >> 1, wn = wv & 1;
  const int fr = lane & 15, kg = lane >> 4;

  if (tid < 128) {
    int sl = m0 + tid;
    tok_s[tid] = (sl < cnt) ? tokidx[e * T_TOK + sl] : 0;
  }
  __syncthreads();
  int arow[4];
#pragma unroll
  for (int j = 0; j < 4; ++j) arow[j] = tok_s[(tid + 256 * j) >> 3];

  f32x4 acc[4][4];
#pragma unroll
  for (int i = 0; i < 4; ++i)
#pragma unroll
    for (int j = 0; j < 4; ++j) acc[i][j] = f32x4{0.f, 0.f, 0.f, 0.f};

  for (int kt = 0; kt < K / 64; ++kt) {
#pragma unroll
    for (int j = 0; j < 4; ++j) {
      int cidx = tid + 256 * j;
      int row = cidx >> 3, ck = cidx & 7;
      int sck = ck ^ (row & 7);
      size_t go = (size_t)arow[j] * K + kt * 64 + sck * 8;
      __builtin_amdgcn_global_load_lds((v_g*)(At + go), (v_l*)((char*)As + cidx * 16), 16, 0, 0);
    }
    {
      const int brow = tid >> 1, bblk = tid & 1;
      int kb = kt * 2 + bblk;
      size_t bi = ((size_t)e * NTOT + n0 + brow) * (K / 32) + kb;
      int sc = qscales[bi];
      const int4* bp = (const int4*)(qblocks + bi * 16);
      int4 q0 = bp[0], q1 = bp[1], q2 = bp[2], q3 = bp[3];
      uint w[16];
      w[0]=dq2h(q0.x,sc);  w[1]=dq2h(q0.y,sc);  w[2]=dq2h(q0.z,sc);  w[3]=dq2h(q0.w,sc);
      w[4]=dq2h(q1.x,sc);  w[5]=dq2h(q1.y,sc);  w[6]=dq2h(q1.z,sc);  w[7]=dq2h(q1.w,sc);
      w[8]=dq2h(q2.x,sc);  w[9]=dq2h(q2.y,sc);  w[10]=dq2h(q2.z,sc); w[11]=dq2h(q2.w,sc);
      w[12]=dq2h(q3.x,sc); w[13]=dq2h(q3.y,sc); w[14]=dq2h(q3.z,sc); w[15]=dq2h(q3.w,sc);
#pragma unroll
      for (int q = 0; q < 4; ++q) {
        int ck = bblk * 4 + q;
        int sk = ck ^ (brow & 7);
        *(uint4*)((char*)Bs + brow * 128 + sk * 16) =
            make_uint4(w[4*q], w[4*q+1], w[4*q+2], w[4*q+3]);
      }
    }
    __syncthreads();
#pragma unroll
    for (int kh = 0; kh < 2; ++kh) {
      f16x8 aF[4], bF[4];
#pragma unroll
      for (int mi = 0; mi < 4; ++mi) {
        int r = wm * 64 + mi * 16 + fr;
        int ck = (kh * 4 + kg) ^ (r & 7);
        aF[mi] = *(const f16x8*)((const char*)As + r * 128 + ck * 16);
      }
#pragma unroll
      for (int ni = 0; ni < 4; ++ni) {
        int r = wn * 64 + ni * 16 + fr;
        int ck = (kh * 4 + kg) ^ (r & 7);
        bF[ni] = *(const f16x8*)((const char*)Bs + r * 128 + ck * 16);
      }
#pragma unroll
      for (int mi = 0; mi < 4; ++mi)
#pragma unroll
        for (int ni = 0; ni < 4; ++ni)
          acc[mi][ni] = __builtin_amdgcn_mfma_f32_16x16x32_f16(aF[mi], bF[ni], acc[mi][ni], 0, 0, 0);
    }
    __syncthreads();
  }

  const int c = lane & 15, rg = lane >> 4;
  const int sbase = m0 + wm * 64, nbase = n0 + wn * 64;
#pragma unroll
  for (int mi = 0; mi < 4; ++mi)
#pragma unroll
    for (int ni = 0; ni < 4; ++ni) {
      int n = nbase + ni * 16 + c;
      float bv = bias[(size_t)e * NTOT + n];
#pragma unroll
      for (int r = 0; r < 4; ++r) {
        int slot = sbase + mi * 16 + rg * 4 + r;
        float val = acc[mi][ni][r] + bv;
        float other = __shfl_xor(val, 1);
        if (!(c & 1) && slot < cnt) {
          int tok = tok_s[slot - m0];
          float g = fminf(val, 7.0f);
          float u = fminf(fmaxf(other, -7.0f), 7.0f);
          float glu = g / (1.0f + expf(-1.702f * g));
          float mv = (u + 1.0f) * glu;
          float s = scores[tok * NE + e];
          midH[((size_t)e * T_TOK + slot) * DDIM + ((uint)n >> 1)] = f2h(mv * s);
        }
      }
    }
}

__global__ __launch_bounds__(256) void dn_gemm_q(
    const ushort* __restrict__ Abase,
    const int* __restrict__ qblocks,
    const int* __restrict__ qscales,
    const float* __restrict__ bias,
    const float* __restrict__ scores,
    const int* __restrict__ cnts,
    const int* __restrict__ tokidx,
    float* __restrict__ outp)
{
  constexpr int NTOT = HDIM;
  constexpr int K    = DDIM;
  const int nt = blockIdx.x, mt = blockIdx.y, e = blockIdx.z;
  const int cnt = cnts[e];
  const int m0 = mt * 128, n0 = nt * 128;
  if (m0 >= cnt) return;
  const ushort* A = Abase + (size_t)e * T_TOK * DDIM;

  __shared__ __align__(16) ushort As[128 * 64];
  __shared__ __align__(16) ushort Bs[128 * 64];
  __shared__ int tok_s[128];

  const int tid = threadIdx.x;
  const int lane = tid & 63;
  const int wv = tid >> 6;
  const int wm = wv >> 1, wn = wv & 1;
  const int fr = lane & 15, kg = lane >> 4;

  if (tid < 128) {
    int sl = m0 + tid;
    tok_s[tid] = (sl < cnt) ? tokidx[e * T_TOK + sl] : 0;
  }
  __syncthreads();

  f32x4 acc[4][4];
#pragma unroll
  for (int i = 0; i < 4; ++i)
#pragma unroll
    for (int j = 0; j < 4; ++j) acc[i][j] = f32x4{0.f, 0.f, 0.f, 0.f};

  for (int kt = 0; kt < K / 64; ++kt) {
#pragma unroll
    for (int j = 0; j < 4; ++j) {
      int cidx = tid + 256 * j;
      int row = cidx >> 3, ck = cidx & 7;
      int sck = ck ^ (row & 7);
      size_t go = (size_t)(m0 + row) * K + kt * 64 + sck * 8;
      __builtin_amdgcn_global_load_lds((v_g*)(A + go), (v_l*)((char*)As + cidx * 16), 16, 0, 0);
    }
    {
      const int brow = tid >> 1, bblk = tid & 1;
      int kb = kt * 2 + bblk;
      size_t bi = ((size_t)e * NTOT + n0 + brow) * (K / 32) + kb;
      int sc = qscales[bi];
      const int4* bp = (const int4*)(qblocks + bi * 16);
      int4 q0 = bp[0], q1 = bp[1], q2 = bp[2], q3 = bp[3];
      uint w[16];
      w[0]=dq2h(q0.x,sc);  w[1]=dq2h(q0.y,sc);  w[2]=dq2h(q0.z,sc);  w[3]=dq2h(q0.w,sc);
      w[4]=dq2h(q1.x,sc);  w[5]=dq2h(q1.y,sc);  w[6]=dq2h(q1.z,sc);  w[7]=dq2h(q1.w,sc);
      w[8]=dq2h(q2.x,sc);  w[9]=dq2h(q2.y,sc);  w[10]=dq2h(q2.z,sc); w[11]=dq2h(q2.w,sc);
      w[12]=dq2h(q3.x,sc); w[13]=dq2h(q3.y,sc); w[14]=dq2h(q3.z,sc); w[15]=dq2h(q3.w,sc);
#pragma unroll
      for (int q = 0; q < 4; ++q) {
        int ck = bblk * 4 + q;
        int sk = ck ^ (brow & 7);
        *(uint4*)((char*)Bs + brow * 128 + sk * 16) =
            make_uint4(w[4*q], w[4*q+1], w[4*q+2], w[4*q+3]);
      }
    }
    __syncthreads();
#pragma unroll
    for (int kh = 0; kh < 2; ++kh) {
      f16x8 aF[4], bF[4];
#pragma unroll
      for (int mi = 0; mi < 4; ++mi) {
        int r = wm * 64 + mi * 16 + fr;
        int ck = (kh * 4 + kg) ^ (r & 7);
        aF[mi] = *(const f16x8*)((const char*)As + r * 128 + ck * 16);
      }
#pragma unroll
      for (int ni = 0; ni < 4; ++ni) {
        int r = wn * 64 + ni * 16 + fr;
        int ck = (kh * 4 + kg) ^ (r & 7);
        bF[ni] = *(const f16x8*)((const char*)Bs + r * 128 + ck * 16);
      }
#pragma unroll
      for (int mi = 0; mi < 4; ++mi)
#pragma unroll
        for (int ni = 0; ni < 4; ++ni)
          acc[mi][ni] = __builtin_amdgcn_mfma_f32_16x16x32_f16(aF[mi], bF[ni], acc[mi][ni], 0, 0, 0);
    }
    __syncthreads();
  }

  const int c = lane & 15, rg = lane >> 4;
  const int sbase = m0 + wm * 64, nbase = n0 + wn * 64;
#pragma unroll
  for (int mi = 0; mi < 4; ++mi)
#pragma unroll
    for (int ni = 0; ni < 4; ++ni) {
      int n = nbase + ni * 16 + c;
      float dbv = bias[(size_t)e * NTOT + n];
#pragma unroll
      for (int r = 0; r < 4; ++r) {
        int slot = sbase + mi * 16 + rg * 4 + r;
        if (slot < cnt) {
          int tok = tok_s[slot - m0];
          float s = scores[tok * NE + e];
          atomicAdd(outp + (size_t)tok * HDIM + n, acc[mi][ni][r] + s * dbv);
        }
      }
    }
}

extern "C" void kernel_launch(void* const* d_in, const int* in_sizes, int n_in,
                              void* d_out, int out_size, void* d_ws, size_t ws_size,
                              hipStream_t stream)
{
  const float* x      = (const float*)d_in[0];
  const float* nw     = (const float*)d_in[1];
  const float* rw     = (const float*)d_in[2];
  const float* rb     = (const float*)d_in[3];
  const int*   gus    = (const int*)d_in[4];
  const int*   gub    = (const int*)d_in[5];
  const float* gubias = (const float*)d_in[6];
  const int*   dns    = (const int*)d_in[7];
  const int*   dnb    = (const int*)d_in[8];
  const float* dnbias = (const float*)d_in[9];

  char* ws = (char*)d_ws;
  const size_t SZ_WGU  = (size_t)NE * 4096 * 2048 * 2;   // 134 MB
  const size_t SZ_WDN  = (size_t)NE * 2048 * 2048 * 2;   //  67 MB
  const size_t SZ_T    = (size_t)T_TOK * HDIM * 2;       //   4 MB
  const size_t SZ_MID  = (size_t)NE * T_TOK * DDIM * 2;  //  33.5 MB
  const size_t SZ_MIDD = (size_t)NE * T_TOK * HDIM * 2;  //  33.5 MB (fp16 compacted dn out)
  const size_t SZ_SC   = (size_t)T_TOK * NE * 4;
  const size_t SZ_IDX  = (size_t)NE * T_TOK * 4;
  const size_t SZ_SLOT = (size_t)T_TOK * NE * 4;
  const size_t SZ_CNT  = 128;

  const size_t need_mid = SZ_WGU + SZ_WDN + SZ_T + SZ_MID + SZ_SC + SZ_IDX + SZ_SLOT + SZ_CNT;
  const size_t need_big = need_mid + SZ_MIDD;
  const bool predeq = ws_size >= need_mid;
  const bool bigws  = ws_size >= need_big;

  ushort* wgu = (ushort*)ws;
  ushort* wdn = (ushort*)(ws + SZ_WGU);
  char* base2 = predeq ? (ws + SZ_WGU + SZ_WDN) : ws;
  ushort* tbuf   = (ushort*)base2;
  ushort* midHp  = (ushort*)(base2 + SZ_T);
  float*  scores = (float*)(base2 + SZ_T + SZ_MID);
  int*    cnts   = (int*)(base2 + SZ_T + SZ_MID + SZ_SC);
  int*    tokidx = (int*)(base2 + SZ_T + SZ_MID + SZ_SC + SZ_CNT);
  int*    slotmap= (int*)(base2 + SZ_T + SZ_MID + SZ_SC + SZ_CNT + SZ_IDX);
  ushort* midD   = (ushort*)(base2 + SZ_T + SZ_MID + SZ_SC + SZ_CNT + SZ_IDX + SZ_SLOT);
  float*  outp   = (float*)d_out;

  if (predeq) {
    prep_kernel<<<NGUB + T_TOK, 256, 0, stream>>>(
        x, nw, rw, rb, gub, gus, tbuf, scores, wgu);
    scan_kernel<<<NE, 256, 0, stream>>>(scores, cnts, tokidx, slotmap);
    // gate_up GEMM + fused dn-weight dequant (z in [NE, NE+16))
    mx_gemm_p<0><<<dim3(32, 8, NE + 16), 256, 0, stream>>>(
        tbuf, wgu, gubias, scores, cnts, tokidx, midHp, nullptr, dnb, dns, wdn);
    if (bigws) {
      mx_gemm_p<2><<<dim3(16, 8, NE), 256, 0, stream>>>(
          midHp, wdn, dnbias, scores, cnts, tokidx, midD, nullptr, nullptr, nullptr, nullptr);
      gather_kernel<<<T_TOK, 256, 0, stream>>>(
          x, midD, dnbias, scores, slotmap, outp);
    } else {
      hipMemcpyAsync(d_out, (void*)x, (size_t)T_TOK * HDIM * 4,
                     hipMemcpyDeviceToDevice, stream);
      mx_gemm_p<1><<<dim3(16, 8, NE), 256, 0, stream>>>(
          midHp, wdn, dnbias, scores, cnts, tokidx, nullptr, outp, nullptr, nullptr, nullptr);
    }
  } else {
    hipMemcpyAsync(d_out, (void*)x, (size_t)T_TOK * HDIM * 4,
                   hipMemcpyDeviceToDevice, stream);
    router_kernel<<<T_TOK, 256, 0, stream>>>(x, nw, rw, rb, tbuf, scores);
    scan_kernel<<<NE, 256, 0, stream>>>(scores, cnts, tokidx, slotmap);
    gu_gemm_q<<<dim3(32, 8, NE), 256, 0, stream>>>(
        tbuf, gub, gus, gubias, scores, cnts, tokidx, midHp);
    dn_gemm_q<<<dim3(16, 8, NE), 256, 0, stream>>>(
        midHp, dnb, dns, dnbias, scores, cnts, tokidx, outp);
  }
}

// Round 22
// 289.355 us; speedup vs baseline: 1.3811x; 1.0010x over previous
//
#include <hip/hip_runtime.h>
#include <hip/hip_bf16.h>
#include <stdint.h>

#define T_TOK 1024
#define HDIM 2048
#define DDIM 2048
#define NE 8

typedef unsigned int uint;
typedef unsigned short ushort;

typedef _Float16 f16x8 __attribute__((ext_vector_type(8)));
typedef float f32x4 __attribute__((ext_vector_type(4)));

typedef __attribute__((address_space(1))) const void v_g;
typedef __attribute__((address_space(3))) void v_l;

__device__ __forceinline__ ushort f2h(float f) {
  _Float16 h = (_Float16)f;           // v_cvt_f16_f32, RTNE
  return *(ushort*)&h;
}

// e2m1 nibble * 2^(sc-127) -> fp16 bits (exact; subnormals handled; <2^-24 -> 0)
__device__ __forceinline__ uint dqh(uint nib, int sc) {
  uint m = nib & 7u;
  int e = (int)(m >> 1);
  int e16 = sc - 113 + e;                       // fp16 biased exponent
  uint mant = ((m & 1u) && m >= 2u) ? 0x200u : 0u;
  uint bits;
  if (m == 0u || e16 <= -10) bits = 0u;
  else if (e16 >= 1) bits = ((uint)e16 << 10) | mant;
  else bits = (0x400u | mant) >> (1 - e16);     // subnormal (exact for these values)
  return bits | ((nib & 8u) << 12);
}
__device__ __forceinline__ uint dq2h(uint b, int sc) {
  return dqh(b & 15u, sc) | (dqh((b >> 4) & 15u, sc) << 16);
}

// one scale-block dequant: 16 int32 (packed nibbles) -> 32 fp16
__device__ __forceinline__ void dq_block(
    const int* __restrict__ qb, const int* __restrict__ qs,
    ushort* __restrict__ dst, size_t bi)
{
  int sc = qs[bi];
  const int4* bp = (const int4*)(qb + bi * 16);
  int4 q0 = bp[0], q1 = bp[1], q2 = bp[2], q3 = bp[3];
  uint w[16];
  w[0]=dq2h(q0.x,sc);  w[1]=dq2h(q0.y,sc);  w[2]=dq2h(q0.z,sc);  w[3]=dq2h(q0.w,sc);
  w[4]=dq2h(q1.x,sc);  w[5]=dq2h(q1.y,sc);  w[6]=dq2h(q1.z,sc);  w[7]=dq2h(q1.w,sc);
  w[8]=dq2h(q2.x,sc);  w[9]=dq2h(q2.y,sc);  w[10]=dq2h(q2.z,sc); w[11]=dq2h(q2.w,sc);
  w[12]=dq2h(q3.x,sc); w[13]=dq2h(q3.y,sc); w[14]=dq2h(q3.z,sc); w[15]=dq2h(q3.w,sc);
  uint4* o = (uint4*)(dst + bi * 32);
  o[0] = make_uint4(w[0], w[1], w[2], w[3]);
  o[1] = make_uint4(w[4], w[5], w[6], w[7]);
  o[2] = make_uint4(w[8], w[9], w[10], w[11]);
  o[3] = make_uint4(w[12], w[13], w[14], w[15]);
}

// Pipeline sync primitives (counted vmcnt across raw barriers, T3+T4)
__device__ __forceinline__ void waitv4() {
  asm volatile("s_waitcnt vmcnt(4)" ::: "memory");
  __builtin_amdgcn_sched_barrier(0);
}
__device__ __forceinline__ void waitv0() {
  asm volatile("s_waitcnt vmcnt(0)" ::: "memory");
  __builtin_amdgcn_sched_barrier(0);
}
__device__ __forceinline__ void barrier_raw() {
  asm volatile("" ::: "memory");
  __builtin_amdgcn_s_barrier();
  asm volatile("" ::: "memory");
}

// --- router body (RMSNorm + f32 logits + top-4 softmax) ----------------------
__device__ __forceinline__ void router_body(
    int t, const float* __restrict__ x, const float* __restrict__ nw,
    const float* __restrict__ rw, const float* __restrict__ rb,
    ushort* __restrict__ tbuf, float* __restrict__ scores)
{
  const int tid = threadIdx.x;
  const float4* xr = (const float4*)(x + (size_t)t * HDIM);
  float4 v0 = xr[tid * 2], v1 = xr[tid * 2 + 1];
  float ss = v0.x*v0.x + v0.y*v0.y + v0.z*v0.z + v0.w*v0.w
           + v1.x*v1.x + v1.y*v1.y + v1.z*v1.z + v1.w*v1.w;
  __shared__ float red[256];
  red[tid] = ss;
  __syncthreads();
  for (int s = 128; s > 0; s >>= 1) {
    if (tid < s) red[tid] += red[tid + s];
    __syncthreads();
  }
  const float rstd = rsqrtf(red[0] * (1.0f / HDIM) + 1e-5f);
  float xv[8] = {v0.x, v0.y, v0.z, v0.w, v1.x, v1.y, v1.z, v1.w};
  float lp[NE];
#pragma unroll
  for (int e = 0; e < NE; ++e) lp[e] = 0.f;
  union { ushort us[8]; uint4 v; } pkh;
  const int h0 = tid * 8;
#pragma unroll
  for (int j = 0; j < 8; ++j) {
    int h = h0 + j;
    float tn = xv[j] * rstd * nw[h];
    pkh.us[j] = f2h(tn);
#pragma unroll
    for (int e = 0; e < NE; ++e) lp[e] += tn * rw[h * NE + e];
  }
  *(uint4*)(tbuf + (size_t)t * HDIM + h0) = pkh.v;
#pragma unroll
  for (int e = 0; e < NE; ++e)
#pragma unroll
    for (int off = 32; off > 0; off >>= 1) lp[e] += __shfl_down(lp[e], off);
  __shared__ float wred[4][NE];
  if ((tid & 63) == 0) {
#pragma unroll
    for (int e = 0; e < NE; ++e) wred[tid >> 6][e] = lp[e];
  }
  __syncthreads();
  if (tid == 0) {
    float lg[NE];
#pragma unroll
    for (int e = 0; e < NE; ++e)
      lg[e] = wred[0][e] + wred[1][e] + wred[2][e] + wred[3][e] + rb[e];
    bool used[NE] = {false, false, false, false, false, false, false, false};
    float tv[4]; int ti[4];
    for (int s = 0; s < 4; ++s) {          // ties: lowest index first (strict >)
      float best = -3.4e38f; int bi = 0;
      for (int e = 0; e < NE; ++e)
        if (!used[e] && lg[e] > best) { best = lg[e]; bi = e; }
      used[bi] = true; tv[s] = best; ti[s] = bi;
    }
    float den = 0.f, ev[4];
    for (int s = 0; s < 4; ++s) { ev[s] = expf(tv[s] - tv[0]); den += ev[s]; }
    float so[NE] = {0, 0, 0, 0, 0, 0, 0, 0};
    for (int s = 0; s < 4; ++s) so[ti[s]] = ev[s] / den;
#pragma unroll
    for (int e = 0; e < NE; ++e) scores[t * NE + e] = so[e];
  }
}

__global__ __launch_bounds__(256) void router_kernel(
    const float* __restrict__ x, const float* __restrict__ nw,
    const float* __restrict__ rw, const float* __restrict__ rb,
    ushort* __restrict__ tbuf, float* __restrict__ scores)
{
  router_body(blockIdx.x, x, nw, rw, rb, tbuf, scores);
}

// ---- prep: gate_up dequant (blocks 0..NGUB-1) + router (rest) ---------------
#define NGUB (NE * 4096 * 64 / 256)        // 8192 blocks, gu weights only
__global__ __launch_bounds__(256) void prep_kernel(
    const float* __restrict__ x, const float* __restrict__ nw,
    const float* __restrict__ rw, const float* __restrict__ rb,
    const int* __restrict__ gub, const int* __restrict__ gus,
    ushort* __restrict__ tbuf, float* __restrict__ scores,
    ushort* __restrict__ wgu)
{
  if (blockIdx.x >= NGUB) {
    router_body(blockIdx.x - NGUB, x, nw, rw, rb, tbuf, scores);
    return;
  }
  size_t bi = (size_t)blockIdx.x * 256 + threadIdx.x;
  dq_block(gub, gus, wgu, bi);
}

// -- per-expert token compaction + inverse slot map (deterministic scan) -------
__global__ __launch_bounds__(256) void scan_kernel(
    const float* __restrict__ scores, int* __restrict__ cnts,
    int* __restrict__ idx, int* __restrict__ slotmap)
{
  const int e = blockIdx.x, tid = threadIdx.x;
  int loc[4], c = 0;
#pragma unroll
  for (int j = 0; j < 4; ++j) {
    int t = tid * 4 + j;
    loc[j] = (scores[t * NE + e] != 0.f) ? 1 : 0;
    c += loc[j];
  }
  __shared__ int sc[256];
  sc[tid] = c;
  __syncthreads();
  for (int off = 1; off < 256; off <<= 1) {
    int v = (tid >= off) ? sc[tid - off] : 0;
    __syncthreads();
    sc[tid] += v;
    __syncthreads();
  }
  int base = sc[tid] - c;
#pragma unroll
  for (int j = 0; j < 4; ++j)
    if (loc[j]) {
      int t = tid * 4 + j;
      idx[e * T_TOK + base] = t;
      slotmap[t * NE + e] = base;
      base++;
    }
  if (tid == 255) cnts[e] = sc[255];
}

// ---- pipelined fp16 GEMM: 128x128 tile, BK=32, 2-deep counted-vmcnt (T3+T4) --
// MODE 0: gate_up+GLU -> mid; z>=NE blocks instead dequant dn weights (fused).
// MODE 1: down + scatter atomics to out (fallback path).
// MODE 2: down, split-K x2 (z = 2e+kh) -> fp16 plane midD[kh][e][slot][h].
template<int MODE>
__global__ __launch_bounds__(256) void mx_gemm_p(
    const ushort* __restrict__ Abase,
    const ushort* __restrict__ Bw,
    const float* __restrict__ bias,
    const float* __restrict__ scores,
    const int* __restrict__ cnts,
    const int* __restrict__ tokidx,
    ushort* __restrict__ midH,
    float* __restrict__ outp,
    const int* __restrict__ dnb,
    const int* __restrict__ dns,
    ushort* __restrict__ wdn)
{
  constexpr int NTOT = (MODE == 0) ? 2 * DDIM : HDIM;
  constexpr int K    = (MODE == 0) ? HDIM : DDIM;
  constexpr int KSPAN = (MODE == 2) ? K / 2 : K;     // K range per block
  constexpr int NKT  = KSPAN / 32;
  const int nt = blockIdx.x, mt = blockIdx.y;
  const int e  = (MODE == 2) ? (blockIdx.z >> 1) : blockIdx.z;
  const int kh = (MODE == 2) ? (blockIdx.z & 1) : 0;
  const int koff = kh * KSPAN;                        // 0 unless MODE 2
  if constexpr (MODE == 0) {
    if (e >= NE) {                 // fused dn-weight dequant block
      size_t bi = ((size_t)(e - NE) * 256 + mt * 32 + nt) * 256 + threadIdx.x;
      dq_block(dnb, dns, wdn, bi);
      return;
    }
  }
  const int cnt = cnts[e];
  const int m0 = mt * 128, n0 = nt * 128;
  if (m0 >= cnt) return;
  const ushort* A = Abase + (MODE == 0 ? (size_t)0 : (size_t)e * T_TOK * DDIM);

  __shared__ __align__(16) ushort As[2][128 * 32];   // 2 x 8 KB
  __shared__ __align__(16) ushort Bs[2][128 * 32];   // 2 x 8 KB
  __shared__ int tok_s[128];

  const int tid = threadIdx.x;
  const int lane = tid & 63;
  const int wv = tid >> 6;
  const int wm = wv >> 1, wn = wv & 1;
  const int fr = lane & 15, kg = lane >> 4;

  if (tid < 128) {
    int sl = m0 + tid;
    tok_s[tid] = (sl < cnt) ? tokidx[e * T_TOK + sl] : 0;
  }
  __syncthreads();

  int arow[2];
#pragma unroll
  for (int j = 0; j < 2; ++j) {
    int row = (tid + 256 * j) >> 2;
    arow[j] = (MODE == 0) ? tok_s[row] : (m0 + row);
  }

  f32x4 acc[4][4];
#pragma unroll
  for (int i = 0; i < 4; ++i)
#pragma unroll
    for (int j = 0; j < 4; ++j) acc[i][j] = f32x4{0.f, 0.f, 0.f, 0.f};

  // stage one K-tile (4 global_load_lds per thread: 2 A + 2 B), swizzled source
  auto do_stage = [&](int buf, int kt) {
#pragma unroll
    for (int j = 0; j < 2; ++j) {
      int cidx = tid + 256 * j;
      int row = cidx >> 2, ck = cidx & 3;
      int gck = ck ^ ((row >> 1) & 3);
      size_t go = (size_t)arow[j] * K + koff + kt * 32 + gck * 8;
      __builtin_amdgcn_global_load_lds((v_g*)(A + go),
          (v_l*)((char*)&As[buf][0] + cidx * 16), 16, 0, 0);
    }
#pragma unroll
    for (int j = 0; j < 2; ++j) {
      int cidx = tid + 256 * j;
      int row = cidx >> 2, ck = cidx & 3;
      int gck = ck ^ ((row >> 1) & 3);
      const ushort* g = Bw + ((size_t)e * NTOT + n0 + row) * K + koff + kt * 32 + gck * 8;
      __builtin_amdgcn_global_load_lds((v_g*)g,
          (v_l*)((char*)&Bs[buf][0] + cidx * 16), 16, 0, 0);
    }
  };

  auto do_compute = [&](int buf) {
    f16x8 aF[4], bF[4];
#pragma unroll
    for (int mi = 0; mi < 4; ++mi) {
      int r = wm * 64 + mi * 16 + fr;
      int ck = kg ^ ((r >> 1) & 3);
      aF[mi] = *(const f16x8*)(&As[buf][r * 32 + ck * 8]);
    }
#pragma unroll
    for (int ni = 0; ni < 4; ++ni) {
      int r = wn * 64 + ni * 16 + fr;
      int ck = kg ^ ((r >> 1) & 3);
      bF[ni] = *(const f16x8*)(&Bs[buf][r * 32 + ck * 8]);
    }
#pragma unroll
    for (int mi = 0; mi < 4; ++mi)
#pragma unroll
      for (int ni = 0; ni < 4; ++ni)
        acc[mi][ni] = __builtin_amdgcn_mfma_f32_16x16x32_f16(aF[mi], bF[ni], acc[mi][ni], 0, 0, 0);
  };

  // prologue: 2-deep prefetch
  do_stage(0, 0);
  do_stage(1, 1);
  waitv4();                         // tile0's 4 loads landed
  barrier_raw();                    // all waves' tile0 loads landed
#pragma unroll 2
  for (int kt = 0; kt < NKT; ++kt) {
    do_compute(kt & 1);             // tile kt
    if (kt == NKT - 1) break;
    barrier_raw();                  // all waves done READING buf kt&1
    if (kt + 2 < NKT) {
      do_stage(kt & 1, kt + 2);     // overwrite freed buffer; 8 outstanding
      waitv4();                     // tile kt+1's loads landed
    } else {
      waitv0();                     // tail drain
    }
    barrier_raw();                  // all waves have tile kt+1 ready
  }

  const int c = lane & 15, rg = lane >> 4;
  const int sbase = m0 + wm * 64, nbase = n0 + wn * 64;
  if constexpr (MODE == 0) {
#pragma unroll
    for (int mi = 0; mi < 4; ++mi)
#pragma unroll
      for (int ni = 0; ni < 4; ++ni) {
        int n = nbase + ni * 16 + c;
        float bv = bias[(size_t)e * NTOT + n];
#pragma unroll
        for (int r = 0; r < 4; ++r) {
          int slot = sbase + mi * 16 + rg * 4 + r;
          float val = acc[mi][ni][r] + bv;
          float other = __shfl_xor(val, 1);
          if (!(c & 1) && slot < cnt) {
            int tok = tok_s[slot - m0];
            float g = fminf(val, 7.0f);
            float u = fminf(fmaxf(other, -7.0f), 7.0f);
            float glu = g / (1.0f + expf(-1.702f * g));
            float mv = (u + 1.0f) * glu;
            float s = scores[tok * NE + e];
            midH[((size_t)e * T_TOK + slot) * DDIM + ((uint)n >> 1)] = f2h(mv * s);
          }
        }
      }
  } else if constexpr (MODE == 1) {
#pragma unroll
    for (int mi = 0; mi < 4; ++mi)
#pragma unroll
      for (int ni = 0; ni < 4; ++ni) {
        int n = nbase + ni * 16 + c;
        float dbv = bias[(size_t)e * NTOT + n];
#pragma unroll
        for (int r = 0; r < 4; ++r) {
          int slot = sbase + mi * 16 + rg * 4 + r;
          if (slot < cnt) {
            int tok = tok_s[slot - m0];
            float s = scores[tok * NE + e];
            atomicAdd(outp + (size_t)tok * HDIM + n, acc[mi][ni][r] + s * dbv);
          }
        }
      }
  } else {   // MODE 2: compacted fp16 plane store (bias/score in gather)
    ushort* plane = midH + (size_t)kh * NE * T_TOK * HDIM;
#pragma unroll
    for (int mi = 0; mi < 4; ++mi)
#pragma unroll
      for (int ni = 0; ni < 4; ++ni) {
        int n = nbase + ni * 16 + c;
#pragma unroll
        for (int r = 0; r < 4; ++r) {
          int slot = sbase + mi * 16 + rg * 4 + r;
          if (slot < cnt)
            plane[((size_t)e * T_TOK + slot) * HDIM + n] = f2h(acc[mi][ni][r]);
        }
      }
  }
}

// -- gather: out[t] = x[t] + sum_e (midD0 + midD1 + s*dn_bias), fixed e-order --
__global__ __launch_bounds__(256) void gather_kernel(
    const float* __restrict__ x, const ushort* __restrict__ midD,
    const float* __restrict__ dnbias, const float* __restrict__ scores,
    const int* __restrict__ slotmap, float* __restrict__ outp)
{
  const int t = blockIdx.x, tid = threadIdx.x;
  const int h0 = tid * 8;
  const float4* xr = (const float4*)(x + (size_t)t * HDIM + h0);
  float4 a0 = xr[0], a1 = xr[1];
  const ushort* midD1 = midD + (size_t)NE * T_TOK * HDIM;
  float sc[NE]; int sl[NE];
#pragma unroll
  for (int e = 0; e < NE; ++e) sc[e] = scores[t * NE + e];
#pragma unroll
  for (int e = 0; e < NE; ++e) sl[e] = slotmap[t * NE + e];
#pragma unroll
  for (int e = 0; e < NE; ++e) {
    if (sc[e] != 0.f) {
      size_t off = ((size_t)e * T_TOK + sl[e]) * HDIM + h0;
      const f16x8 m8 = *(const f16x8*)(midD + off);
      const f16x8 p8 = *(const f16x8*)(midD1 + off);
      const float4* br = (const float4*)(dnbias + (size_t)e * HDIM + h0);
      float4 b0 = br[0], b1 = br[1];
      float s = sc[e];
      a0.x += (float)m8[0] + (float)p8[0] + s * b0.x;
      a0.y += (float)m8[1] + (float)p8[1] + s * b0.y;
      a0.z += (float)m8[2] + (float)p8[2] + s * b0.z;
      a0.w += (float)m8[3] + (float)p8[3] + s * b0.w;
      a1.x += (float)m8[4] + (float)p8[4] + s * b1.x;
      a1.y += (float)m8[5] + (float)p8[5] + s * b1.y;
      a1.z += (float)m8[6] + (float)p8[6] + s * b1.z;
      a1.w += (float)m8[7] + (float)p8[7] + s * b1.w;
    }
  }
  float4* orow = (float4*)(outp + (size_t)t * HDIM + h0);
  orow[0] = a0;
  orow[1] = a1;
}

// ---- fallback kernels (inline fp16 dequant, simple 1-phase; ws-too-small) ----
__global__ __launch_bounds__(256) void gu_gemm_q(
    const ushort* __restrict__ At,
    const int* __restrict__ qblocks,
    const int* __restrict__ qscales,
    const float* __restrict__ bias,
    const float* __restrict__ scores,
    const int* __restrict__ cnts,
    const int* __restrict__ tokidx,
    ushort* __restrict__ midH)
{
  constexpr int NTOT = 2 * DDIM;
  constexpr int K = HDIM;
  const int nt = blockIdx.x, mt = blockIdx.y, e = blockIdx.z;
  const int cnt = cnts[e];
  const int m0 = mt * 128, n0 = nt * 128;
  if (m0 >= cnt) return;

  __shared__ __align__(16) ushort As[128 * 64];
  __shared__ __align__(16) ushort Bs[128 * 64];
  __shared__ int tok_s[128];

  const int tid = threadIdx.x;
  const int lane = tid & 63;
  const int wv = tid >> 6;
  const int wm = wv >> 1, wn = wv & 1;
  const int fr = lane & 15, kg = lane >> 4;

  if (tid < 128) {
    int sl = m0 + tid;
    tok_s[tid] = (sl < cnt) ? tokidx[e * T_TOK + sl] : 0;
  }
  __syncthreads();
  int arow[4];
#pragma unroll
  for (int j = 0; j < 4; ++j) arow[j] = tok_s[(tid + 256 * j) >> 3];

  f32x4 acc[4][4];
#pragma unroll
  for (int i = 0; i < 4; ++i)
#pragma unroll
    for (int j = 0; j < 4; ++j) acc[i][j] = f32x4{0.f, 0.f, 0.f, 0.f};

  for (int kt = 0; kt < K / 64; ++kt) {
#pragma unroll
    for (int j = 0; j < 4; ++j) {
      int cidx = tid + 256 * j;
      int row = cidx >> 3, ck = cidx & 7;
      int sck = ck ^ (row & 7);
      size_t go = (size_t)arow[j] * K + kt * 64 + sck * 8;
      __builtin_amdgcn_global_load_lds((v_g*)(At + go), (v_l*)((char*)As + cidx * 16), 16, 0, 0);
    }
    {
      const int brow = tid >> 1, bblk = tid & 1;
      int kb = kt * 2 + bblk;
      size_t bi = ((size_t)e * NTOT + n0 + brow) * (K / 32) + kb;
      int sc = qscales[bi];
      const int4* bp = (const int4*)(qblocks + bi * 16);
      int4 q0 = bp[0], q1 = bp[1], q2 = bp[2], q3 = bp[3];
      uint w[16];
      w[0]=dq2h(q0.x,sc);  w[1]=dq2h(q0.y,sc);  w[2]=dq2h(q0.z,sc);  w[3]=dq2h(q0.w,sc);
      w[4]=dq2h(q1.x,sc);  w[5]=dq2h(q1.y,sc);  w[6]=dq2h(q1.z,sc);  w[7]=dq2h(q1.w,sc);
      w[8]=dq2h(q2.x,sc);  w[9]=dq2h(q2.y,sc);  w[10]=dq2h(q2.z,sc); w[11]=dq2h(q2.w,sc);
      w[12]=dq2h(q3.x,sc); w[13]=dq2h(q3.y,sc); w[14]=dq2h(q3.z,sc); w[15]=dq2h(q3.w,sc);
#pragma unroll
      for (int q = 0; q < 4; ++q) {
        int ck = bblk * 4 + q;
        int sk = ck ^ (brow & 7);
        *(uint4*)((char*)Bs + brow * 128 + sk * 16) =
            make_uint4(w[4*q], w[4*q+1], w[4*q+2], w[4*q+3]);
      }
    }
    __syncthreads();
#pragma unroll
    for (int kh = 0; kh < 2; ++kh) {
      f16x8 aF[4], bF[4];
#pragma unroll
      for (int mi = 0; mi < 4; ++mi) {
        int r = wm * 64 + mi * 16 + fr;
        int ck = (kh * 4 + kg) ^ (r & 7);
        aF[mi] = *(const f16x8*)((const char*)As + r * 128 + ck * 16);
      }
#pragma unroll
      for (int ni = 0; ni < 4; ++ni) {
        int r = wn * 64 + ni * 16 + fr;
        int ck = (kh * 4 + kg) ^ (r & 7);
        bF[ni] = *(const f16x8*)((const char*)Bs + r * 128 + ck * 16);
      }
#pragma unroll
      for (int mi = 0; mi < 4; ++mi)
#pragma unroll
        for (int ni = 0; ni < 4; ++ni)
          acc[mi][ni] = __builtin_amdgcn_mfma_f32_16x16x32_f16(aF[mi], bF[ni], acc[mi][ni], 0, 0, 0);
    }
    __syncthreads();
  }

  const int c = lane & 15, rg = lane >> 4;
  const int sbase = m0 + wm * 64, nbase = n0 + wn * 64;
#pragma unroll
  for (int mi = 0; mi < 4; ++mi)
#pragma unroll
    for (int ni = 0; ni < 4; ++ni) {
      int n = nbase + ni * 16 + c;
      float bv = bias[(size_t)e * NTOT + n];
#pragma unroll
      for (int r = 0; r < 4; ++r) {
        int slot = sbase + mi * 16 + rg * 4 + r;
        float val = acc[mi][ni][r] + bv;
        float other = __shfl_xor(val, 1);
        if (!(c & 1) && slot < cnt) {
          int tok = tok_s[slot - m0];
          float g = fminf(val, 7.0f);
          float u = fminf(fmaxf(other, -7.0f), 7.0f);
          float glu = g / (1.0f + expf(-1.702f * g));
          float mv = (u + 1.0f) * glu;
          float s = scores[tok * NE + e];
          midH[((size_t)e * T_TOK + slot) * DDIM + ((uint)n >> 1)] = f2h(mv * s);
        }
      }
    }
}

__global__ __launch_bounds__(256) void dn_gemm_q(
    const ushort* __restrict__ Abase,
    const int* __restrict__ qblocks,
    const int* __restrict__ qscales,
    const float* __restrict__ bias,
    const float* __restrict__ scores,
    const int* __restrict__ cnts,
    const int* __restrict__ tokidx,
    float* __restrict__ outp)
{
  constexpr int NTOT = HDIM;
  constexpr int K    = DDIM;
  const int nt = blockIdx.x, mt = blockIdx.y, e = blockIdx.z;
  const int cnt = cnts[e];
  const int m0 = mt * 128, n0 = nt * 128;
  if (m0 >= cnt) return;
  const ushort* A = Abase + (size_t)e * T_TOK * DDIM;

  __shared__ __align__(16) ushort As[128 * 64];
  __shared__ __align__(16) ushort Bs[128 * 64];
  __shared__ int tok_s[128];

  const int tid = threadIdx.x;
  const int lane = tid & 63;
  const int wv = tid >> 6;
  const int wm = wv >> 1, wn = wv & 1;
  const int fr = lane & 15, kg = lane >> 4;

  if (tid < 128) {
    int sl = m0 + tid;
    tok_s[tid] = (sl < cnt) ? tokidx[e * T_TOK + sl] : 0;
  }
  __syncthreads();

  f32x4 acc[4][4];
#pragma unroll
  for (int i = 0; i < 4; ++i)
#pragma unroll
    for (int j = 0; j < 4; ++j) acc[i][j] = f32x4{0.f, 0.f, 0.f, 0.f};

  for (int kt = 0; kt < K / 64; ++kt) {
#pragma unroll
    for (int j = 0; j < 4; ++j) {
      int cidx = tid + 256 * j;
      int row = cidx >> 3, ck = cidx & 7;
      int sck = ck ^ (row & 7);
      size_t go = (size_t)(m0 + row) * K + kt * 64 + sck * 8;
      __builtin_amdgcn_global_load_lds((v_g*)(A + go), (v_l*)((char*)As + cidx * 16), 16, 0, 0);
    }
    {
      const int brow = tid >> 1, bblk = tid & 1;
      int kb = kt * 2 + bblk;
      size_t bi = ((size_t)e * NTOT + n0 + brow) * (K / 32) + kb;
      int sc = qscales[bi];
      const int4* bp = (const int4*)(qblocks + bi * 16);
      int4 q0 = bp[0], q1 = bp[1], q2 = bp[2], q3 = bp[3];
      uint w[16];
      w[0]=dq2h(q0.x,sc);  w[1]=dq2h(q0.y,sc);  w[2]=dq2h(q0.z,sc);  w[3]=dq2h(q0.w,sc);
      w[4]=dq2h(q1.x,sc);  w[5]=dq2h(q1.y,sc);  w[6]=dq2h(q1.z,sc);  w[7]=dq2h(q1.w,sc);
      w[8]=dq2h(q2.x,sc);  w[9]=dq2h(q2.y,sc);  w[10]=dq2h(q2.z,sc); w[11]=dq2h(q2.w,sc);
      w[12]=dq2h(q3.x,sc); w[13]=dq2h(q3.y,sc); w[14]=dq2h(q3.z,sc); w[15]=dq2h(q3.w,sc);
#pragma unroll
      for (int q = 0; q < 4; ++q) {
        int ck = bblk * 4 + q;
        int sk = ck ^ (brow & 7);
        *(uint4*)((char*)Bs + brow * 128 + sk * 16) =
            make_uint4(w[4*q], w[4*q+1], w[4*q+2], w[4*q+3]);
      }
    }
    __syncthreads();
#pragma unroll
    for (int kh = 0; kh < 2; ++kh) {
      f16x8 aF[4], bF[4];
#pragma unroll
      for (int mi = 0; mi < 4; ++mi) {
        int r = wm * 64 + mi * 16 + fr;
        int ck = (kh * 4 + kg) ^ (r & 7);
        aF[mi] = *(const f16x8*)((const char*)As + r * 128 + ck * 16);
      }
#pragma unroll
      for (int ni = 0; ni < 4; ++ni) {
        int r = wn * 64 + ni * 16 + fr;
        int ck = (kh * 4 + kg) ^ (r & 7);
        bF[ni] = *(const f16x8*)((const char*)Bs + r * 128 + ck * 16);
      }
#pragma unroll
      for (int mi = 0; mi < 4; ++mi)
#pragma unroll
        for (int ni = 0; ni < 4; ++ni)
          acc[mi][ni] = __builtin_amdgcn_mfma_f32_16x16x32_f16(aF[mi], bF[ni], acc[mi][ni], 0, 0, 0);
    }
    __syncthreads();
  }

  const int c = lane & 15, rg = lane >> 4;
  const int sbase = m0 + wm * 64, nbase = n0 + wn * 64;
#pragma unroll
  for (int mi = 0; mi < 4; ++mi)
#pragma unroll
    for (int ni = 0; ni < 4; ++ni) {
      int n = nbase + ni * 16 + c;
      float dbv = bias[(size_t)e * NTOT + n];
#pragma unroll
      for (int r = 0; r < 4; ++r) {
        int slot = sbase + mi * 16 + rg * 4 + r;
        if (slot < cnt) {
          int tok = tok_s[slot - m0];
          float s = scores[tok * NE + e];
          atomicAdd(outp + (size_t)tok * HDIM + n, acc[mi][ni][r] + s * dbv);
        }
      }
    }
}

extern "C" void kernel_launch(void* const* d_in, const int* in_sizes, int n_in,
                              void* d_out, int out_size, void* d_ws, size_t ws_size,
                              hipStream_t stream)
{
  const float* x      = (const float*)d_in[0];
  const float* nw     = (const float*)d_in[1];
  const float* rw     = (const float*)d_in[2];
  const float* rb     = (const float*)d_in[3];
  const int*   gus    = (const int*)d_in[4];
  const int*   gub    = (const int*)d_in[5];
  const float* gubias = (const float*)d_in[6];
  const int*   dns    = (const int*)d_in[7];
  const int*   dnb    = (const int*)d_in[8];
  const float* dnbias = (const float*)d_in[9];

  char* ws = (char*)d_ws;
  const size_t SZ_WGU  = (size_t)NE * 4096 * 2048 * 2;   // 134 MB
  const size_t SZ_WDN  = (size_t)NE * 2048 * 2048 * 2;   //  67 MB
  const size_t SZ_T    = (size_t)T_TOK * HDIM * 2;       //   4 MB
  const size_t SZ_MID  = (size_t)NE * T_TOK * DDIM * 2;  //  33.5 MB
  const size_t SZ_MIDD = (size_t)2 * NE * T_TOK * HDIM * 2; // 67 MB (2 fp16 planes)
  const size_t SZ_SC   = (size_t)T_TOK * NE * 4;
  const size_t SZ_IDX  = (size_t)NE * T_TOK * 4;
  const size_t SZ_SLOT = (size_t)T_TOK * NE * 4;
  const size_t SZ_CNT  = 128;

  const size_t need_mid = SZ_WGU + SZ_WDN + SZ_T + SZ_MID + SZ_SC + SZ_IDX + SZ_SLOT + SZ_CNT;
  const size_t need_big = need_mid + SZ_MIDD;
  const bool predeq = ws_size >= need_mid;
  const bool bigws  = ws_size >= need_big;

  ushort* wgu = (ushort*)ws;
  ushort* wdn = (ushort*)(ws + SZ_WGU);
  char* base2 = predeq ? (ws + SZ_WGU + SZ_WDN) : ws;
  ushort* tbuf   = (ushort*)base2;
  ushort* midHp  = (ushort*)(base2 + SZ_T);
  float*  scores = (float*)(base2 + SZ_T + SZ_MID);
  int*    cnts   = (int*)(base2 + SZ_T + SZ_MID + SZ_SC);
  int*    tokidx = (int*)(base2 + SZ_T + SZ_MID + SZ_SC + SZ_CNT);
  int*    slotmap= (int*)(base2 + SZ_T + SZ_MID + SZ_SC + SZ_CNT + SZ_IDX);
  ushort* midD   = (ushort*)(base2 + SZ_T + SZ_MID + SZ_SC + SZ_CNT + SZ_IDX + SZ_SLOT);
  float*  outp   = (float*)d_out;

  if (predeq) {
    prep_kernel<<<NGUB + T_TOK, 256, 0, stream>>>(
        x, nw, rw, rb, gub, gus, tbuf, scores, wgu);
    scan_kernel<<<NE, 256, 0, stream>>>(scores, cnts, tokidx, slotmap);
    // gate_up GEMM + fused dn-weight dequant (z in [NE, NE+16))
    mx_gemm_p<0><<<dim3(32, 8, NE + 16), 256, 0, stream>>>(
        tbuf, wgu, gubias, scores, cnts, tokidx, midHp, nullptr, dnb, dns, wdn);
    if (bigws) {
      // down GEMM, split-K x2 -> two fp16 planes of midD
      mx_gemm_p<2><<<dim3(16, 8, NE * 2), 256, 0, stream>>>(
          midHp, wdn, dnbias, scores, cnts, tokidx, midD, nullptr, nullptr, nullptr, nullptr);
      gather_kernel<<<T_TOK, 256, 0, stream>>>(
          x, midD, dnbias, scores, slotmap, outp);
    } else {
      hipMemcpyAsync(d_out, (void*)x, (size_t)T_TOK * HDIM * 4,
                     hipMemcpyDeviceToDevice, stream);
      mx_gemm_p<1><<<dim3(16, 8, NE), 256, 0, stream>>>(
          midHp, wdn, dnbias, scores, cnts, tokidx, nullptr, outp, nullptr, nullptr, nullptr);
    }
  } else {
    hipMemcpyAsync(d_out, (void*)x, (size_t)T_TOK * HDIM * 4,
                   hipMemcpyDeviceToDevice, stream);
    router_kernel<<<T_TOK, 256, 0, stream>>>(x, nw, rw, rb, tbuf, scores);
    scan_kernel<<<NE, 256, 0, stream>>>(scores, cnts, tokidx, slotmap);
    gu_gemm_q<<<dim3(32, 8, NE), 256, 0, stream>>>(
        tbuf, gub, gus, gubias, scores, cnts, tokidx, midHp);
    dn_gemm_q<<<dim3(16, 8, NE), 256, 0, stream>>>(
        midHp, dnb, dns, dnbias, scores, cnts, tokidx, outp);
  }
}

// Round 23
// 289.351 us; speedup vs baseline: 1.3811x; 1.0000x over previous
//
#include <hip/hip_runtime.h>
#include <hip/hip_bf16.h>
#include <stdint.h>

#define T_TOK 1024
#define HDIM 2048
#define DDIM 2048
#define NE 8

typedef unsigned int uint;
typedef unsigned short ushort;

typedef _Float16 f16x8 __attribute__((ext_vector_type(8)));
typedef float f32x4 __attribute__((ext_vector_type(4)));

typedef __attribute__((address_space(1))) const void v_g;
typedef __attribute__((address_space(3))) void v_l;

__device__ __forceinline__ ushort f2h(float f) {
  _Float16 h = (_Float16)f;           // v_cvt_f16_f32, RTNE
  return *(ushort*)&h;
}

// e2m1 nibble * 2^(sc-127) -> fp16 bits (exact; subnormals handled; <2^-24 -> 0)
__device__ __forceinline__ uint dqh(uint nib, int sc) {
  uint m = nib & 7u;
  int e = (int)(m >> 1);
  int e16 = sc - 113 + e;                       // fp16 biased exponent
  uint mant = ((m & 1u) && m >= 2u) ? 0x200u : 0u;
  uint bits;
  if (m == 0u || e16 <= -10) bits = 0u;
  else if (e16 >= 1) bits = ((uint)e16 << 10) | mant;
  else bits = (0x400u | mant) >> (1 - e16);     // subnormal (exact for these values)
  return bits | ((nib & 8u) << 12);
}
__device__ __forceinline__ uint dq2h(uint b, int sc) {
  return dqh(b & 15u, sc) | (dqh((b >> 4) & 15u, sc) << 16);
}

// one scale-block dequant: 16 int32 (packed nibbles) -> 32 fp16
__device__ __forceinline__ void dq_block(
    const int* __restrict__ qb, const int* __restrict__ qs,
    ushort* __restrict__ dst, size_t bi)
{
  int sc = qs[bi];
  const int4* bp = (const int4*)(qb + bi * 16);
  int4 q0 = bp[0], q1 = bp[1], q2 = bp[2], q3 = bp[3];
  uint w[16];
  w[0]=dq2h(q0.x,sc);  w[1]=dq2h(q0.y,sc);  w[2]=dq2h(q0.z,sc);  w[3]=dq2h(q0.w,sc);
  w[4]=dq2h(q1.x,sc);  w[5]=dq2h(q1.y,sc);  w[6]=dq2h(q1.z,sc);  w[7]=dq2h(q1.w,sc);
  w[8]=dq2h(q2.x,sc);  w[9]=dq2h(q2.y,sc);  w[10]=dq2h(q2.z,sc); w[11]=dq2h(q2.w,sc);
  w[12]=dq2h(q3.x,sc); w[13]=dq2h(q3.y,sc); w[14]=dq2h(q3.z,sc); w[15]=dq2h(q3.w,sc);
  uint4* o = (uint4*)(dst + bi * 32);
  o[0] = make_uint4(w[0], w[1], w[2], w[3]);
  o[1] = make_uint4(w[4], w[5], w[6], w[7]);
  o[2] = make_uint4(w[8], w[9], w[10], w[11]);
  o[3] = make_uint4(w[12], w[13], w[14], w[15]);
}

// Pipeline sync primitives (counted vmcnt across raw barriers, T3+T4)
__device__ __forceinline__ void waitv4() {
  asm volatile("s_waitcnt vmcnt(4)" ::: "memory");
  __builtin_amdgcn_sched_barrier(0);
}
__device__ __forceinline__ void waitv0() {
  asm volatile("s_waitcnt vmcnt(0)" ::: "memory");
  __builtin_amdgcn_sched_barrier(0);
}
__device__ __forceinline__ void barrier_raw() {
  asm volatile("" ::: "memory");
  __builtin_amdgcn_s_barrier();
  asm volatile("" ::: "memory");
}

// --- router body (RMSNorm + f32 logits + top-4 softmax) ----------------------
__device__ __forceinline__ void router_body(
    int t, const float* __restrict__ x, const float* __restrict__ nw,
    const float* __restrict__ rw, const float* __restrict__ rb,
    ushort* __restrict__ tbuf, float* __restrict__ scores)
{
  const int tid = threadIdx.x;
  const float4* xr = (const float4*)(x + (size_t)t * HDIM);
  float4 v0 = xr[tid * 2], v1 = xr[tid * 2 + 1];
  float ss = v0.x*v0.x + v0.y*v0.y + v0.z*v0.z + v0.w*v0.w
           + v1.x*v1.x + v1.y*v1.y + v1.z*v1.z + v1.w*v1.w;
  __shared__ float red[256];
  red[tid] = ss;
  __syncthreads();
  for (int s = 128; s > 0; s >>= 1) {
    if (tid < s) red[tid] += red[tid + s];
    __syncthreads();
  }
  const float rstd = rsqrtf(red[0] * (1.0f / HDIM) + 1e-5f);
  float xv[8] = {v0.x, v0.y, v0.z, v0.w, v1.x, v1.y, v1.z, v1.w};
  float lp[NE];
#pragma unroll
  for (int e = 0; e < NE; ++e) lp[e] = 0.f;
  union { ushort us[8]; uint4 v; } pkh;
  const int h0 = tid * 8;
#pragma unroll
  for (int j = 0; j < 8; ++j) {
    int h = h0 + j;
    float tn = xv[j] * rstd * nw[h];
    pkh.us[j] = f2h(tn);
#pragma unroll
    for (int e = 0; e < NE; ++e) lp[e] += tn * rw[h * NE + e];
  }
  *(uint4*)(tbuf + (size_t)t * HDIM + h0) = pkh.v;
#pragma unroll
  for (int e = 0; e < NE; ++e)
#pragma unroll
    for (int off = 32; off > 0; off >>= 1) lp[e] += __shfl_down(lp[e], off);
  __shared__ float wred[4][NE];
  if ((tid & 63) == 0) {
#pragma unroll
    for (int e = 0; e < NE; ++e) wred[tid >> 6][e] = lp[e];
  }
  __syncthreads();
  if (tid == 0) {
    float lg[NE];
#pragma unroll
    for (int e = 0; e < NE; ++e)
      lg[e] = wred[0][e] + wred[1][e] + wred[2][e] + wred[3][e] + rb[e];
    bool used[NE] = {false, false, false, false, false, false, false, false};
    float tv[4]; int ti[4];
    for (int s = 0; s < 4; ++s) {          // ties: lowest index first (strict >)
      float best = -3.4e38f; int bi = 0;
      for (int e = 0; e < NE; ++e)
        if (!used[e] && lg[e] > best) { best = lg[e]; bi = e; }
      used[bi] = true; tv[s] = best; ti[s] = bi;
    }
    float den = 0.f, ev[4];
    for (int s = 0; s < 4; ++s) { ev[s] = expf(tv[s] - tv[0]); den += ev[s]; }
    float so[NE] = {0, 0, 0, 0, 0, 0, 0, 0};
    for (int s = 0; s < 4; ++s) so[ti[s]] = ev[s] / den;
#pragma unroll
    for (int e = 0; e < NE; ++e) scores[t * NE + e] = so[e];
  }
}

__global__ __launch_bounds__(256) void router_kernel(
    const float* __restrict__ x, const float* __restrict__ nw,
    const float* __restrict__ rw, const float* __restrict__ rb,
    ushort* __restrict__ tbuf, float* __restrict__ scores)
{
  router_body(blockIdx.x, x, nw, rw, rb, tbuf, scores);
}

// ---- prep: gate_up dequant (blocks 0..NGUB-1) + router (rest) ---------------
#define NGUB (NE * 4096 * 64 / 256)        // 8192 blocks, gu weights only
__global__ __launch_bounds__(256) void prep_kernel(
    const float* __restrict__ x, const float* __restrict__ nw,
    const float* __restrict__ rw, const float* __restrict__ rb,
    const int* __restrict__ gub, const int* __restrict__ gus,
    ushort* __restrict__ tbuf, float* __restrict__ scores,
    ushort* __restrict__ wgu)
{
  if (blockIdx.x >= NGUB) {
    router_body(blockIdx.x - NGUB, x, nw, rw, rb, tbuf, scores);
    return;
  }
  size_t bi = (size_t)blockIdx.x * 256 + threadIdx.x;
  dq_block(gub, gus, wgu, bi);
}

// -- per-expert token compaction + inverse slot map (deterministic scan) -------
__global__ __launch_bounds__(256) void scan_kernel(
    const float* __restrict__ scores, int* __restrict__ cnts,
    int* __restrict__ idx, int* __restrict__ slotmap)
{
  const int e = blockIdx.x, tid = threadIdx.x;
  int loc[4], c = 0;
#pragma unroll
  for (int j = 0; j < 4; ++j) {
    int t = tid * 4 + j;
    loc[j] = (scores[t * NE + e] != 0.f) ? 1 : 0;
    c += loc[j];
  }
  __shared__ int sc[256];
  sc[tid] = c;
  __syncthreads();
  for (int off = 1; off < 256; off <<= 1) {
    int v = (tid >= off) ? sc[tid - off] : 0;
    __syncthreads();
    sc[tid] += v;
    __syncthreads();
  }
  int base = sc[tid] - c;
#pragma unroll
  for (int j = 0; j < 4; ++j)
    if (loc[j]) {
      int t = tid * 4 + j;
      idx[e * T_TOK + base] = t;
      slotmap[t * NE + e] = base;
      base++;
    }
  if (tid == 255) cnts[e] = sc[255];
}

// ---- pipelined fp16 GEMM: 128x128 tile, BK=32, 2-deep counted-vmcnt (T3+T4) --
// MODE 0: gate_up+GLU -> mid; z>=NE blocks instead dequant dn weights (fused).
// MODE 1: down + scatter atomics to out (fallback path).
// MODE 2: down, split-K x2 (z = 2e+kh) -> fp16 plane midD[kh][e][slot][h].
template<int MODE>
__global__ __launch_bounds__(256) void mx_gemm_p(
    const ushort* __restrict__ Abase,
    const ushort* __restrict__ Bw,
    const float* __restrict__ bias,
    const float* __restrict__ scores,
    const int* __restrict__ cnts,
    const int* __restrict__ tokidx,
    ushort* __restrict__ midH,
    float* __restrict__ outp,
    const int* __restrict__ dnb,
    const int* __restrict__ dns,
    ushort* __restrict__ wdn)
{
  constexpr int NTOT = (MODE == 0) ? 2 * DDIM : HDIM;
  constexpr int K    = (MODE == 0) ? HDIM : DDIM;
  constexpr int KSPAN = (MODE == 2) ? K / 2 : K;     // K range per block
  constexpr int NKT  = KSPAN / 32;
  const int nt = blockIdx.x, mt = blockIdx.y;
  const int e  = (MODE == 2) ? (blockIdx.z >> 1) : blockIdx.z;
  const int kh = (MODE == 2) ? (blockIdx.z & 1) : 0;
  const int koff = kh * KSPAN;                        // 0 unless MODE 2
  if constexpr (MODE == 0) {
    if (e >= NE) {                 // fused dn-weight dequant block
      size_t bi = ((size_t)(e - NE) * 256 + mt * 32 + nt) * 256 + threadIdx.x;
      dq_block(dnb, dns, wdn, bi);
      return;
    }
  }
  const int cnt = cnts[e];
  const int m0 = mt * 128, n0 = nt * 128;
  if (m0 >= cnt) return;
  const ushort* A = Abase + (MODE == 0 ? (size_t)0 : (size_t)e * T_TOK * DDIM);

  __shared__ __align__(16) ushort As[2][128 * 32];   // 2 x 8 KB
  __shared__ __align__(16) ushort Bs[2][128 * 32];   // 2 x 8 KB
  __shared__ int tok_s[128];

  const int tid = threadIdx.x;
  const int lane = tid & 63;
  const int wv = tid >> 6;
  const int wm = wv >> 1, wn = wv & 1;
  const int fr = lane & 15, kg = lane >> 4;

  if (tid < 128) {
    int sl = m0 + tid;
    tok_s[tid] = (sl < cnt) ? tokidx[e * T_TOK + sl] : 0;
  }
  __syncthreads();

  int arow[2];
#pragma unroll
  for (int j = 0; j < 2; ++j) {
    int row = (tid + 256 * j) >> 2;
    arow[j] = (MODE == 0) ? tok_s[row] : (m0 + row);
  }

  f32x4 acc[4][4];
#pragma unroll
  for (int i = 0; i < 4; ++i)
#pragma unroll
    for (int j = 0; j < 4; ++j) acc[i][j] = f32x4{0.f, 0.f, 0.f, 0.f};

  // stage one K-tile (4 global_load_lds per thread: 2 A + 2 B), swizzled source
  auto do_stage = [&](int buf, int kt) {
#pragma unroll
    for (int j = 0; j < 2; ++j) {
      int cidx = tid + 256 * j;
      int row = cidx >> 2, ck = cidx & 3;
      int gck = ck ^ ((row >> 1) & 3);
      size_t go = (size_t)arow[j] * K + koff + kt * 32 + gck * 8;
      __builtin_amdgcn_global_load_lds((v_g*)(A + go),
          (v_l*)((char*)&As[buf][0] + cidx * 16), 16, 0, 0);
    }
#pragma unroll
    for (int j = 0; j < 2; ++j) {
      int cidx = tid + 256 * j;
      int row = cidx >> 2, ck = cidx & 3;
      int gck = ck ^ ((row >> 1) & 3);
      const ushort* g = Bw + ((size_t)e * NTOT + n0 + row) * K + koff + kt * 32 + gck * 8;
      __builtin_amdgcn_global_load_lds((v_g*)g,
          (v_l*)((char*)&Bs[buf][0] + cidx * 16), 16, 0, 0);
    }
  };

  auto do_compute = [&](int buf) {
    f16x8 aF[4], bF[4];
#pragma unroll
    for (int mi = 0; mi < 4; ++mi) {
      int r = wm * 64 + mi * 16 + fr;
      int ck = kg ^ ((r >> 1) & 3);
      aF[mi] = *(const f16x8*)(&As[buf][r * 32 + ck * 8]);
    }
#pragma unroll
    for (int ni = 0; ni < 4; ++ni) {
      int r = wn * 64 + ni * 16 + fr;
      int ck = kg ^ ((r >> 1) & 3);
      bF[ni] = *(const f16x8*)(&Bs[buf][r * 32 + ck * 8]);
    }
#pragma unroll
    for (int mi = 0; mi < 4; ++mi)
#pragma unroll
      for (int ni = 0; ni < 4; ++ni)
        acc[mi][ni] = __builtin_amdgcn_mfma_f32_16x16x32_f16(aF[mi], bF[ni], acc[mi][ni], 0, 0, 0);
  };

  // prologue: 2-deep prefetch
  do_stage(0, 0);
  do_stage(1, 1);
  waitv4();                         // tile0's 4 loads landed
  barrier_raw();                    // all waves' tile0 loads landed
#pragma unroll 2
  for (int kt = 0; kt < NKT; ++kt) {
    do_compute(kt & 1);             // tile kt
    if (kt == NKT - 1) break;
    barrier_raw();                  // all waves done READING buf kt&1
    if (kt + 2 < NKT) {
      do_stage(kt & 1, kt + 2);     // overwrite freed buffer; 8 outstanding
      waitv4();                     // tile kt+1's loads landed
    } else {
      waitv0();                     // tail drain
    }
    barrier_raw();                  // all waves have tile kt+1 ready
  }

  const int c = lane & 15, rg = lane >> 4;
  const int sbase = m0 + wm * 64, nbase = n0 + wn * 64;
  if constexpr (MODE == 0) {
#pragma unroll
    for (int mi = 0; mi < 4; ++mi)
#pragma unroll
      for (int ni = 0; ni < 4; ++ni) {
        int n = nbase + ni * 16 + c;
        float bv = bias[(size_t)e * NTOT + n];
#pragma unroll
        for (int r = 0; r < 4; ++r) {
          int slot = sbase + mi * 16 + rg * 4 + r;
          float val = acc[mi][ni][r] + bv;
          float other = __shfl_xor(val, 1);
          if (!(c & 1) && slot < cnt) {
            int tok = tok_s[slot - m0];
            float g = fminf(val, 7.0f);
            float u = fminf(fmaxf(other, -7.0f), 7.0f);
            float glu = g / (1.0f + expf(-1.702f * g));
            float mv = (u + 1.0f) * glu;
            float s = scores[tok * NE + e];
            midH[((size_t)e * T_TOK + slot) * DDIM + ((uint)n >> 1)] = f2h(mv * s);
          }
        }
      }
  } else if constexpr (MODE == 1) {
#pragma unroll
    for (int mi = 0; mi < 4; ++mi)
#pragma unroll
      for (int ni = 0; ni < 4; ++ni) {
        int n = nbase + ni * 16 + c;
        float dbv = bias[(size_t)e * NTOT + n];
#pragma unroll
        for (int r = 0; r < 4; ++r) {
          int slot = sbase + mi * 16 + rg * 4 + r;
          if (slot < cnt) {
            int tok = tok_s[slot - m0];
            float s = scores[tok * NE + e];
            atomicAdd(outp + (size_t)tok * HDIM + n, acc[mi][ni][r] + s * dbv);
          }
        }
      }
  } else {   // MODE 2: compacted fp16 plane store (bias/score in gather)
    ushort* plane = midH + (size_t)kh * NE * T_TOK * HDIM;
#pragma unroll
    for (int mi = 0; mi < 4; ++mi)
#pragma unroll
      for (int ni = 0; ni < 4; ++ni) {
        int n = nbase + ni * 16 + c;
#pragma unroll
        for (int r = 0; r < 4; ++r) {
          int slot = sbase + mi * 16 + rg * 4 + r;
          if (slot < cnt)
            plane[((size_t)e * T_TOK + slot) * HDIM + n] = f2h(acc[mi][ni][r]);
        }
      }
  }
}

// -- gather: out[t] = x[t] + sum_e (midD0 + midD1 + s*dn_bias), fixed e-order --
__global__ __launch_bounds__(256) void gather_kernel(
    const float* __restrict__ x, const ushort* __restrict__ midD,
    const float* __restrict__ dnbias, const float* __restrict__ scores,
    const int* __restrict__ slotmap, float* __restrict__ outp)
{
  const int t = blockIdx.x, tid = threadIdx.x;
  const int h0 = tid * 8;
  const float4* xr = (const float4*)(x + (size_t)t * HDIM + h0);
  float4 a0 = xr[0], a1 = xr[1];
  const ushort* midD1 = midD + (size_t)NE * T_TOK * HDIM;
  float sc[NE]; int sl[NE];
#pragma unroll
  for (int e = 0; e < NE; ++e) sc[e] = scores[t * NE + e];
#pragma unroll
  for (int e = 0; e < NE; ++e) sl[e] = slotmap[t * NE + e];
#pragma unroll
  for (int e = 0; e < NE; ++e) {
    if (sc[e] != 0.f) {
      size_t off = ((size_t)e * T_TOK + sl[e]) * HDIM + h0;
      const f16x8 m8 = *(const f16x8*)(midD + off);
      const f16x8 p8 = *(const f16x8*)(midD1 + off);
      const float4* br = (const float4*)(dnbias + (size_t)e * HDIM + h0);
      float4 b0 = br[0], b1 = br[1];
      float s = sc[e];
      a0.x += (float)m8[0] + (float)p8[0] + s * b0.x;
      a0.y += (float)m8[1] + (float)p8[1] + s * b0.y;
      a0.z += (float)m8[2] + (float)p8[2] + s * b0.z;
      a0.w += (float)m8[3] + (float)p8[3] + s * b0.w;
      a1.x += (float)m8[4] + (float)p8[4] + s * b1.x;
      a1.y += (float)m8[5] + (float)p8[5] + s * b1.y;
      a1.z += (float)m8[6] + (float)p8[6] + s * b1.z;
      a1.w += (float)m8[7] + (float)p8[7] + s * b1.w;
    }
  }
  float4* orow = (float4*)(outp + (size_t)t * HDIM + h0);
  orow[0] = a0;
  orow[1] = a1;
}

// ---- fallback kernels (inline fp16 dequant, simple 1-phase; ws-too-small) ----
__global__ __launch_bounds__(256) void gu_gemm_q(
    const ushort* __restrict__ At,
    const int* __restrict__ qblocks,
    const int* __restrict__ qscales,
    const float* __restrict__ bias,
    const float* __restrict__ scores,
    const int* __restrict__ cnts,
    const int* __restrict__ tokidx,
    ushort* __restrict__ midH)
{
  constexpr int NTOT = 2 * DDIM;
  constexpr int K = HDIM;
  const int nt = blockIdx.x, mt = blockIdx.y, e = blockIdx.z;
  const int cnt = cnts[e];
  const int m0 = mt * 128, n0 = nt * 128;
  if (m0 >= cnt) return;

  __shared__ __align__(16) ushort As[128 * 64];
  __shared__ __align__(16) ushort Bs[128 * 64];
  __shared__ int tok_s[128];

  const int tid = threadIdx.x;
  const int lane = tid & 63;
  const int wv = tid >> 6;
  const int wm = wv >> 1, wn = wv & 1;
  const int fr = lane & 15, kg = lane >> 4;

  if (tid < 128) {
    int sl = m0 + tid;
    tok_s[tid] = (sl < cnt) ? tokidx[e * T_TOK + sl] : 0;
  }
  __syncthreads();
  int arow[4];
#pragma unroll
  for (int j = 0; j < 4; ++j) arow[j] = tok_s[(tid + 256 * j) >> 3];

  f32x4 acc[4][4];
#pragma unroll
  for (int i = 0; i < 4; ++i)
#pragma unroll
    for (int j = 0; j < 4; ++j) acc[i][j] = f32x4{0.f, 0.f, 0.f, 0.f};

  for (int kt = 0; kt < K / 64; ++kt) {
#pragma unroll
    for (int j = 0; j < 4; ++j) {
      int cidx = tid + 256 * j;
      int row = cidx >> 3, ck = cidx & 7;
      int sck = ck ^ (row & 7);
      size_t go = (size_t)arow[j] * K + kt * 64 + sck * 8;
      __builtin_amdgcn_global_load_lds((v_g*)(At + go), (v_l*)((char*)As + cidx * 16), 16, 0, 0);
    }
    {
      const int brow = tid >> 1, bblk = tid & 1;
      int kb = kt * 2 + bblk;
      size_t bi = ((size_t)e * NTOT + n0 + brow) * (K / 32) + kb;
      int sc = qscales[bi];
      const int4* bp = (const int4*)(qblocks + bi * 16);
      int4 q0 = bp[0], q1 = bp[1], q2 = bp[2], q3 = bp[3];
      uint w[16];
      w[0]=dq2h(q0.x,sc);  w[1]=dq2h(q0.y,sc);  w[2]=dq2h(q0.z,sc);  w[3]=dq2h(q0.w,sc);
      w[4]=dq2h(q1.x,sc);  w[5]=dq2h(q1.y,sc);  w[6]=dq2h(q1.z,sc);  w[7]=dq2h(q1.w,sc);
      w[8]=dq2h(q2.x,sc);  w[9]=dq2h(q2.y,sc);  w[10]=dq2h(q2.z,sc); w[11]=dq2h(q2.w,sc);
      w[12]=dq2h(q3.x,sc); w[13]=dq2h(q3.y,sc); w[14]=dq2h(q3.z,sc); w[15]=dq2h(q3.w,sc);
#pragma unroll
      for (int q = 0; q < 4; ++q) {
        int ck = bblk * 4 + q;
        int sk = ck ^ (brow & 7);
        *(uint4*)((char*)Bs + brow * 128 + sk * 16) =
            make_uint4(w[4*q], w[4*q+1], w[4*q+2], w[4*q+3]);
      }
    }
    __syncthreads();
#pragma unroll
    for (int kh = 0; kh < 2; ++kh) {
      f16x8 aF[4], bF[4];
#pragma unroll
      for (int mi = 0; mi < 4; ++mi) {
        int r = wm * 64 + mi * 16 + fr;
        int ck = (kh * 4 + kg) ^ (r & 7);
        aF[mi] = *(const f16x8*)((const char*)As + r * 128 + ck * 16);
      }
#pragma unroll
      for (int ni = 0; ni < 4; ++ni) {
        int r = wn * 64 + ni * 16 + fr;
        int ck = (kh * 4 + kg) ^ (r & 7);
        bF[ni] = *(const f16x8*)((const char*)Bs + r * 128 + ck * 16);
      }
#pragma unroll
      for (int mi = 0; mi < 4; ++mi)
#pragma unroll
        for (int ni = 0; ni < 4; ++ni)
          acc[mi][ni] = __builtin_amdgcn_mfma_f32_16x16x32_f16(aF[mi], bF[ni], acc[mi][ni], 0, 0, 0);
    }
    __syncthreads();
  }

  const int c = lane & 15, rg = lane >> 4;
  const int sbase = m0 + wm * 64, nbase = n0 + wn * 64;
#pragma unroll
  for (int mi = 0; mi < 4; ++mi)
#pragma unroll
    for (int ni = 0; ni < 4; ++ni) {
      int n = nbase + ni * 16 + c;
      float bv = bias[(size_t)e * NTOT + n];
#pragma unroll
      for (int r = 0; r < 4; ++r) {
        int slot = sbase + mi * 16 + rg * 4 + r;
        float val = acc[mi][ni][r] + bv;
        float other = __shfl_xor(val, 1);
        if (!(c & 1) && slot < cnt) {
          int tok = tok_s[slot - m0];
          float g = fminf(val, 7.0f);
          float u = fminf(fmaxf(other, -7.0f), 7.0f);
          float glu = g / (1.0f + expf(-1.702f * g));
          float mv = (u + 1.0f) * glu;
          float s = scores[tok * NE + e];
          midH[((size_t)e * T_TOK + slot) * DDIM + ((uint)n >> 1)] = f2h(mv * s);
        }
      }
    }
}

__global__ __launch_bounds__(256) void dn_gemm_q(
    const ushort* __restrict__ Abase,
    const int* __restrict__ qblocks,
    const int* __restrict__ qscales,
    const float* __restrict__ bias,
    const float* __restrict__ scores,
    const int* __restrict__ cnts,
    const int* __restrict__ tokidx,
    float* __restrict__ outp)
{
  constexpr int NTOT = HDIM;
  constexpr int K    = DDIM;
  const int nt = blockIdx.x, mt = blockIdx.y, e = blockIdx.z;
  const int cnt = cnts[e];
  const int m0 = mt * 128, n0 = nt * 128;
  if (m0 >= cnt) return;
  const ushort* A = Abase + (size_t)e * T_TOK * DDIM;

  __shared__ __align__(16) ushort As[128 * 64];
  __shared__ __align__(16) ushort Bs[128 * 64];
  __shared__ int tok_s[128];

  const int tid = threadIdx.x;
  const int lane = tid & 63;
  const int wv = tid >> 6;
  const int wm = wv >> 1, wn = wv & 1;
  const int fr = lane & 15, kg = lane >> 4;

  if (tid < 128) {
    int sl = m0 + tid;
    tok_s[tid] = (sl < cnt) ? tokidx[e * T_TOK + sl] : 0;
  }
  __syncthreads();

  f32x4 acc[4][4];
#pragma unroll
  for (int i = 0; i < 4; ++i)
#pragma unroll
    for (int j = 0; j < 4; ++j) acc[i][j] = f32x4{0.f, 0.f, 0.f, 0.f};

  for (int kt = 0; kt < K / 64; ++kt) {
#pragma unroll
    for (int j = 0; j < 4; ++j) {
      int cidx = tid + 256 * j;
      int row = cidx >> 3, ck = cidx & 7;
      int sck = ck ^ (row & 7);
      size_t go = (size_t)(m0 + row) * K + kt * 64 + sck * 8;
      __builtin_amdgcn_global_load_lds((v_g*)(A + go), (v_l*)((char*)As + cidx * 16), 16, 0, 0);
    }
    {
      const int brow = tid >> 1, bblk = tid & 1;
      int kb = kt * 2 + bblk;
      size_t bi = ((size_t)e * NTOT + n0 + brow) * (K / 32) + kb;
      int sc = qscales[bi];
      const int4* bp = (const int4*)(qblocks + bi * 16);
      int4 q0 = bp[0], q1 = bp[1], q2 = bp[2], q3 = bp[3];
      uint w[16];
      w[0]=dq2h(q0.x,sc);  w[1]=dq2h(q0.y,sc);  w[2]=dq2h(q0.z,sc);  w[3]=dq2h(q0.w,sc);
      w[4]=dq2h(q1.x,sc);  w[5]=dq2h(q1.y,sc);  w[6]=dq2h(q1.z,sc);  w[7]=dq2h(q1.w,sc);
      w[8]=dq2h(q2.x,sc);  w[9]=dq2h(q2.y,sc);  w[10]=dq2h(q2.z,sc); w[11]=dq2h(q2.w,sc);
      w[12]=dq2h(q3.x,sc); w[13]=dq2h(q3.y,sc); w[14]=dq2h(q3.z,sc); w[15]=dq2h(q3.w,sc);
#pragma unroll
      for (int q = 0; q < 4; ++q) {
        int ck = bblk * 4 + q;
        int sk = ck ^ (brow & 7);
        *(uint4*)((char*)Bs + brow * 128 + sk * 16) =
            make_uint4(w[4*q], w[4*q+1], w[4*q+2], w[4*q+3]);
      }
    }
    __syncthreads();
#pragma unroll
    for (int kh = 0; kh < 2; ++kh) {
      f16x8 aF[4], bF[4];
#pragma unroll
      for (int mi = 0; mi < 4; ++mi) {
        int r = wm * 64 + mi * 16 + fr;
        int ck = (kh * 4 + kg) ^ (r & 7);
        aF[mi] = *(const f16x8*)((const char*)As + r * 128 + ck * 16);
      }
#pragma unroll
      for (int ni = 0; ni < 4; ++ni) {
        int r = wn * 64 + ni * 16 + fr;
        int ck = (kh * 4 + kg) ^ (r & 7);
        bF[ni] = *(const f16x8*)((const char*)Bs + r * 128 + ck * 16);
      }
#pragma unroll
      for (int mi = 0; mi < 4; ++mi)
#pragma unroll
        for (int ni = 0; ni < 4; ++ni)
          acc[mi][ni] = __builtin_amdgcn_mfma_f32_16x16x32_f16(aF[mi], bF[ni], acc[mi][ni], 0, 0, 0);
    }
    __syncthreads();
  }

  const int c = lane & 15, rg = lane >> 4;
  const int sbase = m0 + wm * 64, nbase = n0 + wn * 64;
#pragma unroll
  for (int mi = 0; mi < 4; ++mi)
#pragma unroll
    for (int ni = 0; ni < 4; ++ni) {
      int n = nbase + ni * 16 + c;
      float dbv = bias[(size_t)e * NTOT + n];
#pragma unroll
      for (int r = 0; r < 4; ++r) {
        int slot = sbase + mi * 16 + rg * 4 + r;
        if (slot < cnt) {
          int tok = tok_s[slot - m0];
          float s = scores[tok * NE + e];
          atomicAdd(outp + (size_t)tok * HDIM + n, acc[mi][ni][r] + s * dbv);
        }
      }
    }
}

extern "C" void kernel_launch(void* const* d_in, const int* in_sizes, int n_in,
                              void* d_out, int out_size, void* d_ws, size_t ws_size,
                              hipStream_t stream)
{
  const float* x      = (const float*)d_in[0];
  const float* nw     = (const float*)d_in[1];
  const float* rw     = (const float*)d_in[2];
  const float* rb     = (const float*)d_in[3];
  const int*   gus    = (const int*)d_in[4];
  const int*   gub    = (const int*)d_in[5];
  const float* gubias = (const float*)d_in[6];
  const int*   dns    = (const int*)d_in[7];
  const int*   dnb    = (const int*)d_in[8];
  const float* dnbias = (const float*)d_in[9];

  char* ws = (char*)d_ws;
  const size_t SZ_WGU  = (size_t)NE * 4096 * 2048 * 2;   // 134 MB
  const size_t SZ_WDN  = (size_t)NE * 2048 * 2048 * 2;   //  67 MB
  const size_t SZ_T    = (size_t)T_TOK * HDIM * 2;       //   4 MB
  const size_t SZ_MID  = (size_t)NE * T_TOK * DDIM * 2;  //  33.5 MB
  const size_t SZ_MIDD = (size_t)2 * NE * T_TOK * HDIM * 2; // 67 MB (2 fp16 planes)
  const size_t SZ_SC   = (size_t)T_TOK * NE * 4;
  const size_t SZ_IDX  = (size_t)NE * T_TOK * 4;
  const size_t SZ_SLOT = (size_t)T_TOK * NE * 4;
  const size_t SZ_CNT  = 128;

  const size_t need_mid = SZ_WGU + SZ_WDN + SZ_T + SZ_MID + SZ_SC + SZ_IDX + SZ_SLOT + SZ_CNT;
  const size_t need_big = need_mid + SZ_MIDD;
  const bool predeq = ws_size >= need_mid;
  const bool bigws  = ws_size >= need_big;

  ushort* wgu = (ushort*)ws;
  ushort* wdn = (ushort*)(ws + SZ_WGU);
  char* base2 = predeq ? (ws + SZ_WGU + SZ_WDN) : ws;
  ushort* tbuf   = (ushort*)base2;
  ushort* midHp  = (ushort*)(base2 + SZ_T);
  float*  scores = (float*)(base2 + SZ_T + SZ_MID);
  int*    cnts   = (int*)(base2 + SZ_T + SZ_MID + SZ_SC);
  int*    tokidx = (int*)(base2 + SZ_T + SZ_MID + SZ_SC + SZ_CNT);
  int*    slotmap= (int*)(base2 + SZ_T + SZ_MID + SZ_SC + SZ_CNT + SZ_IDX);
  ushort* midD   = (ushort*)(base2 + SZ_T + SZ_MID + SZ_SC + SZ_CNT + SZ_IDX + SZ_SLOT);
  float*  outp   = (float*)d_out;

  if (predeq) {
    prep_kernel<<<NGUB + T_TOK, 256, 0, stream>>>(
        x, nw, rw, rb, gub, gus, tbuf, scores, wgu);
    scan_kernel<<<NE, 256, 0, stream>>>(scores, cnts, tokidx, slotmap);
    // gate_up GEMM + fused dn-weight dequant (z in [NE, NE+16))
    mx_gemm_p<0><<<dim3(32, 8, NE + 16), 256, 0, stream>>>(
        tbuf, wgu, gubias, scores, cnts, tokidx, midHp, nullptr, dnb, dns, wdn);
    if (bigws) {
      // down GEMM, split-K x2 -> two fp16 planes of midD
      mx_gemm_p<2><<<dim3(16, 8, NE * 2), 256, 0, stream>>>(
          midHp, wdn, dnbias, scores, cnts, tokidx, midD, nullptr, nullptr, nullptr, nullptr);
      gather_kernel<<<T_TOK, 256, 0, stream>>>(
          x, midD, dnbias, scores, slotmap, outp);
    } else {
      hipMemcpyAsync(d_out, (void*)x, (size_t)T_TOK * HDIM * 4,
                     hipMemcpyDeviceToDevice, stream);
      mx_gemm_p<1><<<dim3(16, 8, NE), 256, 0, stream>>>(
          midHp, wdn, dnbias, scores, cnts, tokidx, nullptr, outp, nullptr, nullptr, nullptr);
    }
  } else {
    hipMemcpyAsync(d_out, (void*)x, (size_t)T_TOK * HDIM * 4,
                   hipMemcpyDeviceToDevice, stream);
    router_kernel<<<T_TOK, 256, 0, stream>>>(x, nw, rw, rb, tbuf, scores);
    scan_kernel<<<NE, 256, 0, stream>>>(scores, cnts, tokidx, slotmap);
    gu_gemm_q<<<dim3(32, 8, NE), 256, 0, stream>>>(
        tbuf, gub, gus, gubias, scores, cnts, tokidx, midHp);
    dn_gemm_q<<<dim3(16, 8, NE), 256, 0, stream>>>(
        midHp, dnb, dns, dnbias, scores, cnts, tokidx, outp);
  }
}